// Round 3
// baseline (1888.624 us; speedup 1.0000x reference)
//
#include <hip/hip_runtime.h>
#include <hip/hip_bf16.h>
#include <math.h>

typedef __hip_bfloat16 bf16;
typedef unsigned short ushort16_t;
typedef unsigned int uint32;
typedef __attribute__((ext_vector_type(8))) short short8;
typedef __attribute__((ext_vector_type(4))) float floatx4;

#define BB 8
#define NN 2048
#define KK 20

// ---- workspace layout (float offsets) ----
#define O_XMAN  0                        // [8][19][2048]  rows 0..2 = x (fp32), rows 3..18 = lafe out
#define O_XC1   311296                   // [8][83][2048]
#define O_XC2   1671168                  // [8][512][2048] rows 0..255=x_mlp (and U2 before mlp), 256..511=xp2
                                         // reused: knn scratch (hilo/xx), then U2 fp32 [b][2048][256]
#define O_IDX2  10059776                 // int [8][2048][20]
#define O_IDX3  10387456                 // int [8][2048][20] (also temp home for lafe knn idx)
#define O_MLPW  10715136                 // [256][20] padded
#define O_MLPSC 10720256
#define O_MLPSH 10720512
#define O_W1P   10720768                 // [64][64] padded
#define O_BN1SC 10724864
#define O_BN1SH 10724928
#define O_P1SC  10724992
#define O_P1SH  10725056
#define O_P1W   10725120                 // [64][64]
#define O_P1B   10729216
#define O_W2P   10729280                 // B2f fp32 [256][84] (B = Wce + Wdiff)
#define O_BN2SC 10794816
#define O_BN2SH 10795072
#define O_P2SC  10795328
#define O_P2SH  10795584
#define O_P2W   10795840                 // (spare)
#define O_P2B   10861376
#define O_W3P   10861632                 // [512][512]
#define O_BN3SC 11123776
#define O_BN3SH 11124288
#define O_LA    11124800                 // w1[48] b1[16] w2[48] b2[16] w3[16] b3[1]
#define O_FLAG  11124960                 // int: 1 if inputs are fp32, 0 if bf16
#define O_W2B16 11125760                 // ushort A2b [256][96] bf16 (A = Wnb - Wdiff)
#define O_P2W16 11162624                 // ushort [256][256] bf16 p2w

// knn scratch inside XC2 region (consumed before uv2/edge2/mlp write XC2):
//  hilo: ushort [8][2048][KP<=256] = 4.19M ush = 2,097,152 floats
//  xx:   float  [8][2048]          = 16,384 floats
#define O_HILO  O_XC2
#define O_XXQ   (O_XC2 + 2097152)

__device__ __forceinline__ float ldin(const void* p, int i, int f32) {
    return f32 ? ((const float*)p)[i]
               : __bfloat162float(((const bf16*)p)[i]);
}

__device__ __forceinline__ ushort16_t f2bf(float v) {
    union { bf16 h; ushort16_t u; } x; x.h = __float2bfloat16(v); return x.u;
}

__device__ __forceinline__ float bfbits2f(ushort16_t u) {
    union { uint32 i; float f; } c; c.i = ((uint32)u) << 16; return c.f;
}

__device__ __forceinline__ void st4bf(ushort16_t* p, float a, float b, float c, float d) {
    uint2 v;
    v.x = (uint32)f2bf(a) | ((uint32)f2bf(b) << 16);
    v.y = (uint32)f2bf(c) | ((uint32)f2bf(d) << 16);
    *(uint2*)p = v;
}

// ============ detect: are inputs fp32 or bf16? ============
__global__ void detect_kernel(const void* x, int* flag) {
    if (threadIdx.x == 0 && blockIdx.x == 0) {
        const unsigned short* u = (const unsigned short*)x;
        int bad = 0;
        for (int i = 0; i < 64; ++i) {
            int e = (u[i] >> 7) & 0xFF;
            if (e >= 0x86) bad++;
        }
        *flag = (bad > 0) ? 1 : 0;
    }
}

// ================= prep =================
__global__ void prep_kernel(
    const void* la_w1, const void* la_b1, const void* la_w2, const void* la_b2,
    const void* la_w3, const void* la_b3,
    const void* mlp_w, const void* mlp_b, const void* mlp_bn,
    const void* w1, const void* bn1, const void* w2, const void* bn2,
    const void* w3, const void* bn3,
    const void* p1_bn, const void* p1_w, const void* p1_b,
    const void* p2_bn, const void* p2_w, const void* p2_b,
    float* ws)
{
    const int f32 = ((const int*)ws)[O_FLAG];
    int gid = blockIdx.x * blockDim.x + threadIdx.x;
    int gsz = gridDim.x * blockDim.x;

    for (int i = gid; i < 256*20; i += gsz) {
        int o = i / 20, c = i - o*20;
        ws[O_MLPW + i] = (c < 19) ? ldin(mlp_w, o*19 + c, f32) : 0.f;
    }
    for (int c = gid; c < 256; c += gsz) {
        float g = ldin(mlp_bn, c, f32), be = ldin(mlp_bn, 256+c, f32);
        float m = ldin(mlp_bn, 512+c, f32), vv = ldin(mlp_bn, 768+c, f32);
        float s = g / sqrtf(vv + 1e-5f);
        ws[O_MLPSC + c] = s;
        ws[O_MLPSH + c] = be + (ldin(mlp_b, c, f32) - m) * s;
    }
    for (int i = gid; i < 64*64; i += gsz) {
        int o = i >> 6, c = i & 63;
        ws[O_W1P + i] = (c < 57) ? ldin(w1, o*57 + c, f32) : 0.f;
    }
    for (int c = gid; c < 64; c += gsz) {
        float g = ldin(bn1, c, f32), be = ldin(bn1, 64+c, f32);
        float m = ldin(bn1, 128+c, f32), vv = ldin(bn1, 192+c, f32);
        float s = g / sqrtf(vv + 1e-5f);
        ws[O_BN1SC + c] = s; ws[O_BN1SH + c] = be - m*s;
        float g2 = ldin(p1_bn, c, f32), be2 = ldin(p1_bn, 64+c, f32);
        float m2 = ldin(p1_bn, 128+c, f32), vv2 = ldin(p1_bn, 192+c, f32);
        float s2 = g2 / sqrtf(vv2 + 1e-5f);
        ws[O_P1SC + c] = s2; ws[O_P1SH + c] = be2 - m2*s2;
        ws[O_P1B + c] = ldin(p1_b, c, f32);
    }
    for (int i = gid; i < 64*64; i += gsz) ws[O_P1W + i] = ldin(p1_w, i, f32);
    for (int c = gid; c < 256; c += gsz) {
        float g = ldin(bn2, c, f32), be = ldin(bn2, 256+c, f32);
        float m = ldin(bn2, 512+c, f32), vv = ldin(bn2, 768+c, f32);
        float s = g / sqrtf(vv + 1e-5f);
        ws[O_BN2SC + c] = s; ws[O_BN2SH + c] = be - m*s;
        float g2 = ldin(p2_bn, c, f32), be2 = ldin(p2_bn, 256+c, f32);
        float m2 = ldin(p2_bn, 512+c, f32), vv2 = ldin(p2_bn, 768+c, f32);
        float s2 = g2 / sqrtf(vv2 + 1e-5f);
        ws[O_P2SC + c] = s2; ws[O_P2SH + c] = be2 - m2*s2;
        ws[O_P2B + c] = ldin(p2_b, c, f32);
    }
    for (int i = gid; i < 512*512; i += gsz) ws[O_W3P + i] = ldin(w3, i, f32);
    for (int c = gid; c < 512; c += gsz) {
        float g = ldin(bn3, c, f32), be = ldin(bn3, 512+c, f32);
        float m = ldin(bn3, 1024+c, f32), vv = ldin(bn3, 1536+c, f32);
        float s = g / sqrtf(vv + 1e-5f);
        ws[O_BN3SC + c] = s; ws[O_BN3SH + c] = be - m*s;
    }
    for (int i = gid; i < 48; i += gsz) ws[O_LA + i]       = ldin(la_w1, i, f32);
    for (int i = gid; i < 16; i += gsz) ws[O_LA + 48 + i]  = ldin(la_b1, i, f32);
    for (int i = gid; i < 48; i += gsz) ws[O_LA + 64 + i]  = ldin(la_w2, i, f32);
    for (int i = gid; i < 16; i += gsz) ws[O_LA + 112 + i] = ldin(la_b2, i, f32);
    for (int i = gid; i < 16; i += gsz) ws[O_LA + 128 + i] = ldin(la_w3, i, f32);
    if (gid == 0) ws[O_LA + 144] = ldin(la_b3, 0, f32);

    // edge2 decomposition: A = Wnb - Wdiff (bf16, [256][96] padded), B = Wce + Wdiff (fp32, [256][84])
    ushort16_t* a2b = (ushort16_t*)(ws + O_W2B16);
    for (int i = gid; i < 256*96; i += gsz) {
        int row = i / 96, c = i - row*96;
        float v = (c < 83) ? (ldin(w2, row*249 + c, f32) - ldin(w2, row*249 + 166 + c, f32)) : 0.f;
        a2b[i] = f2bf(v);
    }
    float* b2f = ws + O_W2P;
    for (int i = gid; i < 256*84; i += gsz) {
        int row = i / 84, c = i - row*84;
        b2f[i] = (c < 83) ? (ldin(w2, row*249 + 83 + c, f32) + ldin(w2, row*249 + 166 + c, f32)) : 0.f;
    }
    ushort16_t* pwb = (ushort16_t*)(ws + O_P2W16);
    for (int i = gid; i < 256*256; i += gsz) pwb[i] = f2bf(ldin(p2_w, i, f32));
}

// ================= xconv: x -> fp32 into XMAN rows 0..2 =================
__global__ __launch_bounds__(256) void xconv_kernel(const void* x, float* ws) {
    const int f32 = ((const int*)ws)[O_FLAG];
    int gid = blockIdx.x*256 + threadIdx.x;     // 0 .. 8*3*2048-1
    int b = gid / (3*NN), r = gid - b*3*NN;
    ws[O_XMAN + b*19*NN + r] = ldin(x, gid, f32);
}

// ====== 3-way bf16 split precompute: feat fp32 [b][CS][NN] -> hilo [b][NN][KP] ======
template<int C, int CS, int KP>
__global__ void hilo_kernel(const float* feat, ushort16_t* out) {
    int gsz = gridDim.x * blockDim.x;
    int gid0 = blockIdx.x * blockDim.x + threadIdx.x;
    for (int gid = gid0; gid < BB*C*NN; gid += gsz) {
        int b = gid / (C*NN);
        int rem = gid - b*C*NN;
        int c = rem >> 11, n = rem & (NN-1);
        float v = feat[((size_t)b*CS + c)*NN + n];
        ushort16_t h = f2bf(v);
        float r1 = v - bfbits2f(h);
        ushort16_t m = f2bf(r1);
        ushort16_t l = f2bf(r1 - bfbits2f(m));
        size_t base = ((size_t)b*NN + n)*KP + 3*c;
        out[base] = h; out[base+1] = m; out[base+2] = l;
    }
    constexpr int PAD = KP - 3*C;
    for (int gid = gid0; gid < BB*NN*PAD; gid += gsz) {
        int row = gid / PAD, p = gid - row*PAD;
        out[(size_t)row*KP + 3*C + p] = 0;
    }
}

// ====== exact fp32 squared norms ======
template<int C, int CS>
__global__ __launch_bounds__(256) void xx_kernel(const float* feat, float* xxg) {
    int gid = blockIdx.x*256 + threadIdx.x;      // BB*NN total
    int b = gid >> 11, n = gid & (NN-1);
    const float* fb = feat + (size_t)b*CS*NN;
    float s = 0.f;
    #pragma unroll
    for (int c = 0; c < C; ++c) { float v = fb[c*NN + n]; s += v*v; }
    xxg[gid] = s;
}

// ====== fused knn: MFMA distance tile (16 pts x 2048 cands) in LDS, then
//        wave-parallel 20x max-extraction per point row. ======
template<int C, int CS, int KP>
__global__ __launch_bounds__(512, 2) void knn_fused_kernel(
    const float* feat, const ushort16_t* hilo, const float* xxg, int* idxout)
{
    constexpr int KT = KP / 32;
    constexpr int ST = 2057;                 // odd stride -> conflict-free LDS
    __shared__ float Dt[16 * ST];            // 131,648 B
    int tid = threadIdx.x;
    int b  = blockIdx.x >> 7;                // 8 batches x 128 point-groups
    int n0 = (blockIdx.x & 127) << 4;        // 16 points per block
    int lane = tid & 63, wv = tid >> 6;      // 8 waves
    int quad = lane >> 4, l15 = lane & 15;
    const float* fb = feat + (size_t)b * CS * NN;

    // ---- point-side B fragments (point = n0 + l15; same for all waves) ----
    short8 Bh[KT], Bm[KT], Bl[KT];
    #pragma unroll
    for (int kt = 0; kt < KT; ++kt) {
        #pragma unroll
        for (int e = 0; e < 8; ++e) {
            int kp = kt*32 + quad*8 + e;
            int c = kp / 3;
            float v = (c < C) ? fb[(size_t)c*NN + n0 + l15] : 0.f;
            ushort16_t h = f2bf(v);
            float r1 = v - bfbits2f(h);
            ushort16_t m = f2bf(r1);
            ushort16_t l = f2bf(r1 - bfbits2f(m));
            Bh[kt][e] = (short)h; Bm[kt][e] = (short)m; Bl[kt][e] = (short)l;
        }
    }

    const ushort16_t* hb = hilo + (size_t)b * NN * KP;
    const float* xxb = xxg + b * NN;

    // ---- distance phase: wave wv covers candidate tiles wv*4 .. wv*4+3 ----
    #pragma unroll
    for (int i = 0; i < 4; ++i) {
        int base = (wv*4 + i) * 64;
        floatx4 acc[4];
        #pragma unroll
        for (int st = 0; st < 4; ++st) {
            acc[st] = (floatx4){0.f,0.f,0.f,0.f};
            #pragma unroll
            for (int kt = 0; kt < KT; ++kt) {
                short8 a = *(const short8*)&hb[(size_t)(base + st*16 + l15)*KP + kt*32 + quad*8];
                acc[st] = __builtin_amdgcn_mfma_f32_16x16x32_bf16(a, Bh[kt], acc[st], 0, 0, 0);
                acc[st] = __builtin_amdgcn_mfma_f32_16x16x32_bf16(a, Bm[kt], acc[st], 0, 0, 0);
                acc[st] = __builtin_amdgcn_mfma_f32_16x16x32_bf16(a, Bl[kt], acc[st], 0, 0, 0);
            }
        }
        #pragma unroll
        for (int st = 0; st < 4; ++st) {
            #pragma unroll
            for (int r = 0; r < 4; ++r) {
                int cand = base + st*16 + quad*4 + r;
                Dt[l15*ST + cand] = 2.f*acc[st][r] - xxb[cand];
            }
        }
    }
    __syncthreads();

    // ---- selection phase: wave wv handles rows wv*2, wv*2+1 (interleaved ILP) ----
    int r0 = wv*2, r1 = wv*2 + 1;
    float v0[32], v1[32];
    #pragma unroll
    for (int j = 0; j < 32; ++j) {
        v0[j] = Dt[r0*ST + j*64 + lane];
        v1[j] = Dt[r1*ST + j*64 + lane];
    }
    float lv0 = v0[0], lv1 = v1[0];
    int lj0 = 0, lj1 = 0;
    #pragma unroll
    for (int j = 1; j < 32; ++j) {
        bool t0 = v0[j] > lv0; lv0 = t0 ? v0[j] : lv0; lj0 = t0 ? j : lj0;
        bool t1 = v1[j] > lv1; lv1 = t1 ? v1[j] : lv1; lj1 = t1 ? j : lj1;
    }
    int myg0 = 0, myg1 = 0;
    #pragma unroll 1
    for (int it = 0; it < KK; ++it) {
        float bv0 = lv0, bv1 = lv1;
        int bg0 = (lj0 << 6) | lane, bg1 = (lj1 << 6) | lane;
        #pragma unroll
        for (int s = 1; s < 64; s <<= 1) {
            float ov0 = __shfl_xor(bv0, s); int og0 = __shfl_xor(bg0, s);
            float ov1 = __shfl_xor(bv1, s); int og1 = __shfl_xor(bg1, s);
            bool t0 = (ov0 > bv0) || (ov0 == bv0 && og0 < bg0);
            bool t1 = (ov1 > bv1) || (ov1 == bv1 && og1 < bg1);
            bv0 = t0 ? ov0 : bv0; bg0 = t0 ? og0 : bg0;
            bv1 = t1 ? ov1 : bv1; bg1 = t1 ? og1 : bg1;
        }
        if (it == lane) { myg0 = bg0; myg1 = bg1; }
        bool s0 = (lane == (bg0 & 63)); int wj0 = bg0 >> 6;
        bool s1 = (lane == (bg1 & 63)); int wj1 = bg1 >> 6;
        #pragma unroll
        for (int j = 0; j < 32; ++j) {
            v0[j] = (s0 && j == wj0) ? -3.0e38f : v0[j];
            v1[j] = (s1 && j == wj1) ? -3.0e38f : v1[j];
        }
        lv0 = v0[0]; lj0 = 0; lv1 = v1[0]; lj1 = 0;
        #pragma unroll
        for (int j = 1; j < 32; ++j) {
            bool t0 = v0[j] > lv0; lv0 = t0 ? v0[j] : lv0; lj0 = t0 ? j : lj0;
            bool t1 = v1[j] > lv1; lv1 = t1 ? v1[j] : lv1; lj1 = t1 ? j : lj1;
        }
    }
    if (lane < KK) {
        idxout[((size_t)(b*NN + n0 + r0))*KK + lane] = myg0;
        idxout[((size_t)(b*NN + n0 + r1))*KK + lane] = myg1;
    }
}

// ================= lafe attention (post-knn) =================
__global__ __launch_bounds__(256, 1) void lafe_att_kernel(float* ws, const int* idx) {
    __shared__ float xs0[NN], xs1[NN], xs2[NN];
    int tid = threadIdx.x;
    int b = blockIdx.x >> 3;
    int n = ((blockIdx.x & 7) << 8) + tid;
    float* xm = ws + O_XMAN + b*19*NN;
    for (int i = tid; i < NN; i += 256) {
        xs0[i] = xm[i]; xs1[i] = xm[NN + i]; xs2[i] = xm[2*NN + i];
    }
    __syncthreads();
    float a0 = xs0[n], a1 = xs1[n], a2 = xs2[n];
    int ti[KK];
    #pragma unroll
    for (int k = 0; k < KK; ++k) ti[k] = idx[(b*NN + n)*KK + k] & (NN-1);
    const float* wl = ws + O_LA;
    float sa = wl[144];
    #pragma unroll
    for (int o = 0; o < 16; ++o) {
        float nf = wl[o*3+0]*a0 + wl[o*3+1]*a1 + wl[o*3+2]*a2 + wl[48+o];
        sa += wl[128+o]*nf;
    }
    float lg[KK]; float mx = -3.0e38f;
    #pragma unroll
    for (int k = 0; k < KK; ++k) {
        int m = ti[k];
        float d0 = a0 - xs0[m], d1 = a1 - xs1[m], d2 = a2 - xs2[m];
        float na = wl[144];
        #pragma unroll
        for (int o = 0; o < 16; ++o) {
            float ef = wl[64+o*3+0]*d0 + wl[64+o*3+1]*d1 + wl[64+o*3+2]*d2 + wl[112+o];
            na += wl[128+o]*ef;
        }
        float t = sa + na;
        t = t > 0.f ? t : 0.01f*t;
        lg[k] = t; mx = fmaxf(mx, t);
    }
    float ssum = 0.f;
    #pragma unroll
    for (int k = 0; k < KK; ++k) { lg[k] = expf(lg[k] - mx); ssum += lg[k]; }
    float vals[16];
    #pragma unroll
    for (int o = 0; o < 16; ++o) vals[o] = 0.f;
    #pragma unroll
    for (int k = 0; k < KK; ++k) {
        float coef = lg[k] / ssum;
        int m = ti[k];
        float d0 = a0 - xs0[m], d1 = a1 - xs1[m], d2 = a2 - xs2[m];
        #pragma unroll
        for (int o = 0; o < 16; ++o) {
            float ef = wl[64+o*3+0]*d0 + wl[64+o*3+1]*d1 + wl[64+o*3+2]*d2 + wl[112+o];
            vals[o] += coef * ef;
        }
    }
    #pragma unroll
    for (int o = 0; o < 16; ++o) {
        float v = vals[o];
        xm[(3+o)*NN + n] = v > 0.f ? v : expm1f(v);
    }
}

// ================= mlp =================
__global__ void mlp_kernel(float* ws) {
    __shared__ __align__(16) float xv[20];
    int tid = threadIdx.x;
    int b = blockIdx.x >> 11, n = blockIdx.x & 2047;
    if (tid < 20) xv[tid] = (tid < 19) ? ws[O_XMAN + b*19*NN + tid*NN + n] : 0.f;
    __syncthreads();
    const float* mw = ws + O_MLPW;
    float acc = 0.f;
    #pragma unroll
    for (int c4 = 0; c4 < 5; ++c4) {
        float4 w = *(const float4*)&mw[tid*20 + c4*4];
        float4 g = *(const float4*)&xv[c4*4];
        acc += w.x*g.x + w.y*g.y + w.z*g.z + w.w*g.w;
    }
    float v = acc * ws[O_MLPSC + tid] + ws[O_MLPSH + tid];
    ws[O_XC2 + b*512*NN + tid*NN + n] = fmaxf(v, 0.f);
}

// ================= edge1 (fp32) =================
__global__ void edge1_kernel(float* ws, const int* idx) {
    __shared__ __align__(16) float g1T[KK*64];
    __shared__ __align__(16) float h1L[64*21];
    __shared__ __align__(16) float hrT[KK*64];
    __shared__ __align__(16) float attL[64*21];
    __shared__ float xcL[19];
    __shared__ int idxL[KK];
    int tid = threadIdx.x;
    int b = blockIdx.x >> 11, n = blockIdx.x & 2047;
    const float* xb = ws + O_XMAN + b*19*NN;
    if (tid < KK) idxL[tid] = idx[(b*NN + n)*KK + tid] & (NN-1);
    if (tid < 19) xcL[tid] = xb[tid*NN + n];
    __syncthreads();
    for (int i = tid; i < KK*64; i += 64) {
        int k = i >> 6, c = i & 63;
        int j = idxL[k];
        float v = 0.f;
        if (c < 19) v = xb[c*NN + j];
        else if (c < 38) v = xcL[c-19];
        else if (c < 57) v = xcL[c-38] - xb[(c-38)*NN + j];
        g1T[i] = v;
    }
    __syncthreads();
    int ro = tid & 15, kb = (tid >> 4) * 5;
    const float* w1p = ws + O_W1P;
    float acc[4][5];
    #pragma unroll
    for (int j = 0; j < 4; ++j)
        #pragma unroll
        for (int kk = 0; kk < 5; ++kk) acc[j][kk] = 0.f;
    for (int c4 = 0; c4 < 16; ++c4) {
        float4 gv[5], wv[4];
        #pragma unroll
        for (int kk = 0; kk < 5; ++kk) gv[kk] = *(const float4*)&g1T[(kb+kk)*64 + c4*4];
        #pragma unroll
        for (int j = 0; j < 4; ++j) wv[j] = *(const float4*)&w1p[(ro + 16*j)*64 + c4*4];
        #pragma unroll
        for (int j = 0; j < 4; ++j)
            #pragma unroll
            for (int kk = 0; kk < 5; ++kk)
                acc[j][kk] += wv[j].x*gv[kk].x + wv[j].y*gv[kk].y + wv[j].z*gv[kk].z + wv[j].w*gv[kk].w;
    }
    #pragma unroll
    for (int j = 0; j < 4; ++j) {
        int r = ro + 16*j;
        float s1 = ws[O_BN1SC + r], h1s = ws[O_BN1SH + r];
        float ps = ws[O_P1SC + r], ph = ws[O_P1SH + r];
        #pragma unroll
        for (int kk = 0; kk < 5; ++kk) {
            float v = acc[j][kk]*s1 + h1s;
            v = v > 0.f ? v : 0.2f*v;
            h1L[r*21 + kb + kk] = v;
            float hv = v*ps + ph;
            hrT[(kb+kk)*64 + r] = hv > 0.f ? hv : 0.f;
        }
    }
    __syncthreads();
    const float* p1w = ws + O_P1W;
    float ac2[4][5];
    #pragma unroll
    for (int j = 0; j < 4; ++j)
        #pragma unroll
        for (int kk = 0; kk < 5; ++kk) ac2[j][kk] = 0.f;
    for (int c4 = 0; c4 < 16; ++c4) {
        float4 gv[5], wv[4];
        #pragma unroll
        for (int kk = 0; kk < 5; ++kk) gv[kk] = *(const float4*)&hrT[(kb+kk)*64 + c4*4];
        #pragma unroll
        for (int j = 0; j < 4; ++j) wv[j] = *(const float4*)&p1w[(ro + 16*j)*64 + c4*4];
        #pragma unroll
        for (int j = 0; j < 4; ++j)
            #pragma unroll
            for (int kk = 0; kk < 5; ++kk)
                ac2[j][kk] += wv[j].x*gv[kk].x + wv[j].y*gv[kk].y + wv[j].z*gv[kk].z + wv[j].w*gv[kk].w;
    }
    #pragma unroll
    for (int j = 0; j < 4; ++j) {
        int r = ro + 16*j;
        float pb = ws[O_P1B + r];
        #pragma unroll
        for (int kk = 0; kk < 5; ++kk) attL[r*21 + kb + kk] = ac2[j][kk] + pb;
    }
    __syncthreads();
    {
        int o = tid;
        float av[KK]; float mx = -3.0e38f;
        #pragma unroll
        for (int k = 0; k < KK; ++k) { av[k] = attL[o*21 + k]; mx = fmaxf(mx, av[k]); }
        float ssum = 0.f;
        #pragma unroll
        for (int k = 0; k < KK; ++k) { av[k] = expf(av[k] - mx); ssum += av[k]; }
        float outv = 0.f;
        #pragma unroll
        for (int k = 0; k < KK; ++k) outv += h1L[o*21 + k] * (av[k]/ssum);
        float* xc1 = ws + O_XC1 + b*83*NN;
        xc1[(19+o)*NN + n] = outv;
        if (tid < 19) xc1[tid*NN + n] = xcL[tid];
    }
}

// ====== uv2: U2[b][n][r] = sum_c A2[r][c] * xc1[b][c][n], fp32 point-major ======
__global__ __launch_bounds__(256, 2) void uv2_kernel(float* ws) {
    __shared__ ushort16_t xt[64*104];       // [point][chan] bf16, 13,312 B
    int tid = threadIdx.x;
    int b = blockIdx.x >> 5;
    int pn0 = (blockIdx.x & 31) << 6;       // 64 points per block
    const float* xc1 = ws + O_XC1 + (size_t)b*83*NN;
    for (int i = tid; i < 96*64; i += 256) {
        int c = i >> 6, j = i & 63;
        xt[j*104 + c] = (c < 83) ? f2bf(xc1[c*NN + pn0 + j]) : (ushort16_t)0;
    }
    __syncthreads();
    int lane = tid & 63, wv = tid >> 6;
    int quad = lane >> 4, l15 = lane & 15;
    const ushort16_t* a2b = (const ushort16_t*)(ws + O_W2B16);
    floatx4 acc[4][4];
    #pragma unroll
    for (int rt = 0; rt < 4; ++rt)
        #pragma unroll
        for (int nt = 0; nt < 4; ++nt) acc[rt][nt] = (floatx4){0.f,0.f,0.f,0.f};
    #pragma unroll
    for (int kt = 0; kt < 3; ++kt) {
        int c0 = kt*32 + quad*8;
        short8 bfr[4], a[4];
        #pragma unroll
        for (int nt = 0; nt < 4; ++nt)
            bfr[nt] = *(const short8*)&xt[(nt*16 + l15)*104 + c0];
        #pragma unroll
        for (int rt = 0; rt < 4; ++rt)
            a[rt] = *(const short8*)&a2b[(wv*64 + rt*16 + l15)*96 + c0];
        #pragma unroll
        for (int rt = 0; rt < 4; ++rt)
            #pragma unroll
            for (int nt = 0; nt < 4; ++nt)
                acc[rt][nt] = __builtin_amdgcn_mfma_f32_16x16x32_bf16(a[rt], bfr[nt], acc[rt][nt], 0, 0, 0);
    }
    float* U2 = ws + O_XC2 + (size_t)b*512*NN;
    #pragma unroll
    for (int rt = 0; rt < 4; ++rt)
        #pragma unroll
        for (int nt = 0; nt < 4; ++nt) {
            int n = pn0 + nt*16 + l15;
            int r = wv*64 + rt*16 + quad*4;
            *(float4*)&U2[(size_t)n*256 + r] =
                make_float4(acc[rt][nt][0], acc[rt][nt][1], acc[rt][nt][2], acc[rt][nt][3]);
        }
}

// ================= edge2: hr build + att GEMM + softmax + weighted sum =================
__global__ __launch_bounds__(256, 1) void edge2_kernel(float* ws, const int* idx) {
    __shared__ __align__(16) ushort16_t hrb[80*264];   // 42,240 B
    __shared__ __align__(16) float attL[256*84];       // 86,016 B
    __shared__ float vL[4*256];                        // 4,096 B
    __shared__ float scal[5*256];                      // 5,120 B
    __shared__ int idxL[80];

    int tid = threadIdx.x;
    int b  = blockIdx.x >> 9;
    int n0 = (blockIdx.x & 511) << 2;

    scal[tid]        = ws[O_BN2SC + tid];
    scal[256 + tid]  = ws[O_BN2SH + tid];
    scal[512 + tid]  = ws[O_P2SC + tid];
    scal[768 + tid]  = ws[O_P2SH + tid];
    scal[1024 + tid] = ws[O_P2B + tid];
    if (tid < 80) idxL[tid] = idx[(b*NN + n0 + tid/20)*KK + (tid%20)] & (NN-1);

    // V contribution (exact fp32): vL[p][row] = sum_c B2f[row][c] * xc1[c][n0+p]
    {
        const float* xc1 = ws + O_XC1 + (size_t)b*83*NN;
        const float* b2f = ws + O_W2P;
        float a0 = 0.f, a1 = 0.f, a2 = 0.f, a3 = 0.f;
        #pragma unroll 4
        for (int c = 0; c < 83; ++c) {
            float w = b2f[tid*84 + c];
            const float* xr = &xc1[c*NN + n0];
            a0 += w * xr[0]; a1 += w * xr[1]; a2 += w * xr[2]; a3 += w * xr[3];
        }
        vL[tid] = a0; vL[256 + tid] = a1; vL[512 + tid] = a2; vL[768 + tid] = a3;
    }
    __syncthreads();

    // P1: build hr tile [col][row] bf16 from U2 (coalesced) + vL
    const float* U2 = ws + O_XC2 + (size_t)b*512*NN;
    #pragma unroll 4
    for (int col = 0; col < 80; ++col) {
        int p = (col*205) >> 12;
        int j = idxL[col];
        float u = U2[(size_t)j*256 + tid];
        float h2 = (u + vL[p*256 + tid]) * scal[tid] + scal[256 + tid];
        h2 = h2 > 0.f ? h2 : 0.2f*h2;
        float hv = h2*scal[512 + tid] + scal[768 + tid];
        hrb[col*264 + tid] = f2bf(fmaxf(hv, 0.f));
    }
    __syncthreads();

    // P2: att GEMM (p2w [256x256] bf16 x hr [256 x 80])
    int lane = tid & 63, wv = tid >> 6;
    int quad = lane >> 4, l15 = lane & 15;
    const ushort16_t* p2wb = (const ushort16_t*)(ws + O_P2W16);
    floatx4 acc2[4][5];
    #pragma unroll
    for (int mt = 0; mt < 4; ++mt)
        #pragma unroll
        for (int nt = 0; nt < 5; ++nt) acc2[mt][nt] = (floatx4){0.f,0.f,0.f,0.f};
    for (int kt = 0; kt < 8; ++kt) {
        int c0 = kt*32 + quad*8;
        short8 a[4], bb5[5];
        #pragma unroll
        for (int mt = 0; mt < 4; ++mt)
            a[mt] = *(const short8*)&p2wb[(wv*64 + mt*16 + l15)*256 + c0];
        #pragma unroll
        for (int nt = 0; nt < 5; ++nt)
            bb5[nt] = *(const short8*)&hrb[(nt*16 + l15)*264 + c0];
        #pragma unroll
        for (int mt = 0; mt < 4; ++mt)
            #pragma unroll
            for (int nt = 0; nt < 5; ++nt)
                acc2[mt][nt] = __builtin_amdgcn_mfma_f32_16x16x32_bf16(a[mt], bb5[nt], acc2[mt][nt], 0, 0, 0);
    }
    #pragma unroll
    for (int mt = 0; mt < 4; ++mt) {
        int k0 = wv*64 + mt*16 + quad*4;
        #pragma unroll
        for (int nt = 0; nt < 5; ++nt) {
            int col = nt*16 + l15;
            #pragma unroll
            for (int r = 0; r < 4; ++r)
                attL[(k0 + r)*84 + col] = acc2[mt][nt][r] + scal[1024 + k0 + r];
        }
    }
    __syncthreads();

    // P3: softmax over k + weighted sum of recomputed h2 -> xout
    float* xout = ws + O_XC2 + (size_t)b*512*NN;
    #pragma unroll
    for (int q = 0; q < 4; ++q) {
        int pr = tid + 256*q;
        int row = pr >> 2, p = pr & 3;
        float av[KK]; float mx = -3.0e38f;
        #pragma unroll
        for (int k = 0; k < KK; ++k) { av[k] = attL[row*84 + p*20 + k]; mx = fmaxf(mx, av[k]); }
        float ssum = 0.f;
        #pragma unroll
        for (int k = 0; k < KK; ++k) { av[k] = expf(av[k] - mx); ssum += av[k]; }
        float inv = 1.f / ssum;
        float vpr = vL[p*256 + row];
        float sc = scal[row], sh = scal[256 + row];
        float sacc = 0.f;
        #pragma unroll
        for (int k = 0; k < KK; ++k) {
            int j = idxL[p*20 + k];
            float u = U2[(size_t)j*256 + row];
            float h2 = (u + vpr)*sc + sh;
            h2 = h2 > 0.f ? h2 : 0.2f*h2;
            sacc += av[k] * inv * h2;
        }
        xout[(size_t)(256 + row)*NN + n0 + p] = sacc;
    }
}

// ================= final: out = lrelu(bn3(w3 @ x_c2)) -> fp32 =================
__global__ void final_kernel(const float* ws, float* out) {
    __shared__ __align__(16) float tileF[512*16];
    int tid = threadIdx.x;
    int b = blockIdx.x >> 7;
    int n0 = (blockIdx.x & 127) << 4;
    const float* xc2 = ws + O_XC2 + b*512*NN;
    for (int i = tid; i < 512*16; i += 256) {
        int c = i >> 4, nn = i & 15;
        tileF[i] = xc2[c*NN + n0 + nn];
    }
    __syncthreads();
    const float* w3p = ws + O_W3P;
    int r0 = tid*2, r1 = r0 + 1;
    float acc0[16], acc1[16];
    #pragma unroll
    for (int q = 0; q < 16; ++q) { acc0[q] = 0.f; acc1[q] = 0.f; }
    #pragma unroll 4
    for (int c = 0; c < 512; ++c) {
        float w0 = w3p[r0*512 + c], w1v = w3p[r1*512 + c];
        const float4* tr = (const float4*)&tileF[c*16];
        #pragma unroll
        for (int q = 0; q < 4; ++q) {
            float4 t = tr[q];
            acc0[q*4+0] += w0*t.x;  acc0[q*4+1] += w0*t.y;  acc0[q*4+2] += w0*t.z;  acc0[q*4+3] += w0*t.w;
            acc1[q*4+0] += w1v*t.x; acc1[q*4+1] += w1v*t.y; acc1[q*4+2] += w1v*t.z; acc1[q*4+3] += w1v*t.w;
        }
    }
    float s0 = ws[O_BN3SC + r0], q0 = ws[O_BN3SH + r0];
    float s1 = ws[O_BN3SC + r1], q1 = ws[O_BN3SH + r1];
    float* ob = out + b*512*NN;
    #pragma unroll
    for (int nn = 0; nn < 16; ++nn) {
        float v = acc0[nn]*s0 + q0; v = v > 0.f ? v : 0.2f*v;
        ob[r0*NN + n0 + nn] = v;
        float u = acc1[nn]*s1 + q1; u = u > 0.f ? u : 0.2f*u;
        ob[r1*NN + n0 + nn] = u;
    }
}

extern "C" void kernel_launch(void* const* d_in, const int* in_sizes, int n_in,
                              void* d_out, int out_size, void* d_ws, size_t ws_size,
                              hipStream_t stream) {
    float* ws = (float*)d_ws;
    float* out = (float*)d_out;
    ushort16_t* hilo = (ushort16_t*)(ws + O_HILO);
    float* xxq = ws + O_XXQ;

    detect_kernel<<<1, 64, 0, stream>>>(d_in[0], (int*)ws + O_FLAG);
    prep_kernel<<<64, 256, 0, stream>>>(d_in[1], d_in[2], d_in[3], d_in[4], d_in[5], d_in[6],
                                        d_in[7], d_in[8], d_in[9], d_in[10], d_in[11], d_in[12],
                                        d_in[13], d_in[14], d_in[15], d_in[16], d_in[17], d_in[18],
                                        d_in[19], d_in[20], d_in[21], ws);
    // lafe = xconv + knn3 (fused MFMA+select) + attention
    xconv_kernel<<<192, 256, 0, stream>>>(d_in[0], ws);
    hilo_kernel<3, 19, 32><<<256, 256, 0, stream>>>(ws + O_XMAN, hilo);
    xx_kernel<3, 19><<<64, 256, 0, stream>>>(ws + O_XMAN, xxq);
    knn_fused_kernel<3, 19, 32><<<1024, 512, 0, stream>>>(ws + O_XMAN, hilo, xxq, (int*)(ws + O_IDX3));
    lafe_att_kernel<<<64, 256, 0, stream>>>(ws, (const int*)(ws + O_IDX3));
    // knn on x_manet (C=19)
    hilo_kernel<19, 19, 64><<<1024, 256, 0, stream>>>(ws + O_XMAN, hilo);
    xx_kernel<19, 19><<<64, 256, 0, stream>>>(ws + O_XMAN, xxq);
    knn_fused_kernel<19, 19, 64><<<1024, 512, 0, stream>>>(ws + O_XMAN, hilo, xxq, (int*)(ws + O_IDX2));
    edge1_kernel<<<BB*NN, 64, 0, stream>>>(ws, (const int*)(ws + O_IDX2));
    // knn on x_c1 (C=83)
    hilo_kernel<83, 83, 256><<<2048, 256, 0, stream>>>(ws + O_XC1, hilo);
    xx_kernel<83, 83><<<64, 256, 0, stream>>>(ws + O_XC1, xxq);
    knn_fused_kernel<83, 83, 256><<<1024, 512, 0, stream>>>(ws + O_XC1, hilo, xxq, (int*)(ws + O_IDX3));
    // edge2 via A/B decomposition: U2 = A @ xc1 (MFMA), V computed in-block
    uv2_kernel<<<256, 256, 0, stream>>>(ws);
    edge2_kernel<<<BB*512, 256, 0, stream>>>(ws, (const int*)(ws + O_IDX3));
    mlp_kernel<<<BB*NN, 256, 0, stream>>>(ws);
    final_kernel<<<BB*(NN/16), 256, 0, stream>>>(ws, out);
}

// Round 4
// 1754.252 us; speedup vs baseline: 1.0766x; 1.0766x over previous
//
#include <hip/hip_runtime.h>
#include <hip/hip_bf16.h>
#include <math.h>

typedef __hip_bfloat16 bf16;
typedef unsigned short ushort16_t;
typedef unsigned int uint32;
typedef __attribute__((ext_vector_type(8))) short short8;
typedef __attribute__((ext_vector_type(4))) float floatx4;

#define BB 8
#define NN 2048
#define KK 20

// ---- workspace layout (float offsets) ----
#define O_XMAN  0                        // [8][19][2048]  rows 0..2 = x (fp32), rows 3..18 = lafe out
#define O_XC1   311296                   // [8][83][2048]
#define O_XC2   1671168                  // [8][512][2048]:
                                         //   pre-mlp: [b] rows 0..255 region = U2 fp32 [2048][256]
                                         //            [b] rows 256..511 region = XP2 fp32 [2048][256] (point-major xp2)
                                         //   post-mlp: rows 0..255 = x_mlp [c][n]
                                         //   also reused earlier: knn scratch (hilo/xx)
#define O_IDX2  10059776                 // int [8][2048][20]
#define O_IDX3  10387456                 // int [8][2048][20] (also temp home for lafe knn idx)
#define O_MLPW  10715136                 // [256][20] padded
#define O_MLPSC 10720256
#define O_MLPSH 10720512
#define O_W1P   10720768                 // [64][64] padded
#define O_BN1SC 10724864
#define O_BN1SH 10724928
#define O_P1SC  10724992
#define O_P1SH  10725056
#define O_P1W   10725120                 // [64][64]
#define O_P1B   10729216
#define O_W2P   10729280                 // b2fT fp32 [84][256] (B = Wce + Wdiff, transposed)
#define O_BN2SC 10794816
#define O_BN2SH 10795072
#define O_P2SC  10795328
#define O_P2SH  10795584
#define O_P2W   10795840                 // (spare)
#define O_P2B   10861376
#define O_W3P   10861632                 // [512][512]
#define O_BN3SC 11123776
#define O_BN3SH 11124288
#define O_LA    11124800                 // w1[48] b1[16] w2[48] b2[16] w3[16] b3[1]
#define O_FLAG  11124960                 // int: 1 if inputs are fp32, 0 if bf16
#define O_W2B16 11125760                 // ushort A2b [256][96] bf16 (A = Wnb - Wdiff)
#define O_P2W16 11162624                 // ushort [256][256] bf16 p2w

// knn scratch inside XC2 region (consumed before uv2/edge2/mlp write XC2):
#define O_HILO  O_XC2
#define O_XXQ   (O_XC2 + 2097152)

__device__ __forceinline__ float ldin(const void* p, int i, int f32) {
    return f32 ? ((const float*)p)[i]
               : __bfloat162float(((const bf16*)p)[i]);
}

__device__ __forceinline__ ushort16_t f2bf(float v) {
    union { bf16 h; ushort16_t u; } x; x.h = __float2bfloat16(v); return x.u;
}

__device__ __forceinline__ float bfbits2f(ushort16_t u) {
    union { uint32 i; float f; } c; c.i = ((uint32)u) << 16; return c.f;
}

// ============ detect: are inputs fp32 or bf16? ============
__global__ void detect_kernel(const void* x, int* flag) {
    if (threadIdx.x == 0 && blockIdx.x == 0) {
        const unsigned short* u = (const unsigned short*)x;
        int bad = 0;
        for (int i = 0; i < 64; ++i) {
            int e = (u[i] >> 7) & 0xFF;
            if (e >= 0x86) bad++;
        }
        *flag = (bad > 0) ? 1 : 0;
    }
}

// ================= prep =================
__global__ void prep_kernel(
    const void* la_w1, const void* la_b1, const void* la_w2, const void* la_b2,
    const void* la_w3, const void* la_b3,
    const void* mlp_w, const void* mlp_b, const void* mlp_bn,
    const void* w1, const void* bn1, const void* w2, const void* bn2,
    const void* w3, const void* bn3,
    const void* p1_bn, const void* p1_w, const void* p1_b,
    const void* p2_bn, const void* p2_w, const void* p2_b,
    float* ws)
{
    const int f32 = ((const int*)ws)[O_FLAG];
    int gid = blockIdx.x * blockDim.x + threadIdx.x;
    int gsz = gridDim.x * blockDim.x;

    for (int i = gid; i < 256*20; i += gsz) {
        int o = i / 20, c = i - o*20;
        ws[O_MLPW + i] = (c < 19) ? ldin(mlp_w, o*19 + c, f32) : 0.f;
    }
    for (int c = gid; c < 256; c += gsz) {
        float g = ldin(mlp_bn, c, f32), be = ldin(mlp_bn, 256+c, f32);
        float m = ldin(mlp_bn, 512+c, f32), vv = ldin(mlp_bn, 768+c, f32);
        float s = g / sqrtf(vv + 1e-5f);
        ws[O_MLPSC + c] = s;
        ws[O_MLPSH + c] = be + (ldin(mlp_b, c, f32) - m) * s;
    }
    for (int i = gid; i < 64*64; i += gsz) {
        int o = i >> 6, c = i & 63;
        ws[O_W1P + i] = (c < 57) ? ldin(w1, o*57 + c, f32) : 0.f;
    }
    for (int c = gid; c < 64; c += gsz) {
        float g = ldin(bn1, c, f32), be = ldin(bn1, 64+c, f32);
        float m = ldin(bn1, 128+c, f32), vv = ldin(bn1, 192+c, f32);
        float s = g / sqrtf(vv + 1e-5f);
        ws[O_BN1SC + c] = s; ws[O_BN1SH + c] = be - m*s;
        float g2 = ldin(p1_bn, c, f32), be2 = ldin(p1_bn, 64+c, f32);
        float m2 = ldin(p1_bn, 128+c, f32), vv2 = ldin(p1_bn, 192+c, f32);
        float s2 = g2 / sqrtf(vv2 + 1e-5f);
        ws[O_P1SC + c] = s2; ws[O_P1SH + c] = be2 - m2*s2;
        ws[O_P1B + c] = ldin(p1_b, c, f32);
    }
    for (int i = gid; i < 64*64; i += gsz) ws[O_P1W + i] = ldin(p1_w, i, f32);
    for (int c = gid; c < 256; c += gsz) {
        float g = ldin(bn2, c, f32), be = ldin(bn2, 256+c, f32);
        float m = ldin(bn2, 512+c, f32), vv = ldin(bn2, 768+c, f32);
        float s = g / sqrtf(vv + 1e-5f);
        ws[O_BN2SC + c] = s; ws[O_BN2SH + c] = be - m*s;
        float g2 = ldin(p2_bn, c, f32), be2 = ldin(p2_bn, 256+c, f32);
        float m2 = ldin(p2_bn, 512+c, f32), vv2 = ldin(p2_bn, 768+c, f32);
        float s2 = g2 / sqrtf(vv2 + 1e-5f);
        ws[O_P2SC + c] = s2; ws[O_P2SH + c] = be2 - m2*s2;
        ws[O_P2B + c] = ldin(p2_b, c, f32);
    }
    for (int i = gid; i < 512*512; i += gsz) ws[O_W3P + i] = ldin(w3, i, f32);
    for (int c = gid; c < 512; c += gsz) {
        float g = ldin(bn3, c, f32), be = ldin(bn3, 512+c, f32);
        float m = ldin(bn3, 1024+c, f32), vv = ldin(bn3, 1536+c, f32);
        float s = g / sqrtf(vv + 1e-5f);
        ws[O_BN3SC + c] = s; ws[O_BN3SH + c] = be - m*s;
    }
    for (int i = gid; i < 48; i += gsz) ws[O_LA + i]       = ldin(la_w1, i, f32);
    for (int i = gid; i < 16; i += gsz) ws[O_LA + 48 + i]  = ldin(la_b1, i, f32);
    for (int i = gid; i < 48; i += gsz) ws[O_LA + 64 + i]  = ldin(la_w2, i, f32);
    for (int i = gid; i < 16; i += gsz) ws[O_LA + 112 + i] = ldin(la_b2, i, f32);
    for (int i = gid; i < 16; i += gsz) ws[O_LA + 128 + i] = ldin(la_w3, i, f32);
    if (gid == 0) ws[O_LA + 144] = ldin(la_b3, 0, f32);

    // edge2 decomposition: A = Wnb - Wdiff (bf16, [256][96] padded),
    //                      B^T = (Wce + Wdiff)^T (fp32, [84][256] column-major for coalesced V)
    ushort16_t* a2b = (ushort16_t*)(ws + O_W2B16);
    for (int i = gid; i < 256*96; i += gsz) {
        int row = i / 96, c = i - row*96;
        float v = (c < 83) ? (ldin(w2, row*249 + c, f32) - ldin(w2, row*249 + 166 + c, f32)) : 0.f;
        a2b[i] = f2bf(v);
    }
    float* b2fT = ws + O_W2P;
    for (int i = gid; i < 84*256; i += gsz) {
        int c = i >> 8, row = i & 255;
        b2fT[i] = (c < 83) ? (ldin(w2, row*249 + 83 + c, f32) + ldin(w2, row*249 + 166 + c, f32)) : 0.f;
    }
    ushort16_t* pwb = (ushort16_t*)(ws + O_P2W16);
    for (int i = gid; i < 256*256; i += gsz) pwb[i] = f2bf(ldin(p2_w, i, f32));
}

// ================= xconv: x -> fp32 into XMAN rows 0..2 =================
__global__ __launch_bounds__(256) void xconv_kernel(const void* x, float* ws) {
    const int f32 = ((const int*)ws)[O_FLAG];
    int gid = blockIdx.x*256 + threadIdx.x;     // 0 .. 8*3*2048-1
    int b = gid / (3*NN), r = gid - b*3*NN;
    ws[O_XMAN + b*19*NN + r] = ldin(x, gid, f32);
}

// ====== 3-way bf16 split precompute (batch locked to XCD via blockIdx&7) ======
template<int C, int CS, int KP>
__global__ void hilo_kernel(const float* feat, ushort16_t* out) {
    int b  = blockIdx.x & 7;
    int lb = blockIdx.x >> 3;
    int nb = gridDim.x >> 3;
    const float* fb = feat + (size_t)b*CS*NN;
    ushort16_t* ob = out + (size_t)b*NN*KP;
    for (int i = lb*blockDim.x + threadIdx.x; i < C*NN; i += nb*blockDim.x) {
        int c = i >> 11, n = i & (NN-1);
        float v = fb[(size_t)c*NN + n];
        ushort16_t h = f2bf(v);
        float r1 = v - bfbits2f(h);
        ushort16_t m = f2bf(r1);
        ushort16_t l = f2bf(r1 - bfbits2f(m));
        size_t base = (size_t)n*KP + 3*c;
        ob[base] = h; ob[base+1] = m; ob[base+2] = l;
    }
    constexpr int PAD = KP - 3*C;
    for (int i = lb*blockDim.x + threadIdx.x; i < NN*PAD; i += nb*blockDim.x) {
        int n = i / PAD, p = i - n*PAD;
        ob[(size_t)n*KP + 3*C + p] = 0;
    }
}

// ====== exact fp32 squared norms ======
template<int C, int CS>
__global__ __launch_bounds__(256) void xx_kernel(const float* feat, float* xxg) {
    int gid = blockIdx.x*256 + threadIdx.x;      // BB*NN total
    int b = gid >> 11, n = gid & (NN-1);
    const float* fb = feat + (size_t)b*CS*NN;
    float s = 0.f;
    #pragma unroll
    for (int c = 0; c < C; ++c) { float v = fb[c*NN + n]; s += v*v; }
    xxg[gid] = s;
}

// ====== fused knn: MFMA distance tile (16 pts x 2048 cands) in LDS, then
//        wave-parallel 20x max-extraction per point row. batch = blockIdx&7 ======
template<int C, int CS, int KP>
__global__ __launch_bounds__(512, 2) void knn_fused_kernel(
    const float* feat, const ushort16_t* hilo, const float* xxg, int* idxout)
{
    constexpr int KT = KP / 32;
    constexpr int ST = 2057;                 // odd stride -> conflict-free LDS
    __shared__ float Dt[16 * ST];            // 131,648 B
    int tid = threadIdx.x;
    int b  = blockIdx.x & 7;                 // batch -> XCD lock
    int n0 = (blockIdx.x >> 3) << 4;         // 16 points per block (128 groups/batch)
    int lane = tid & 63, wv = tid >> 6;      // 8 waves
    int quad = lane >> 4, l15 = lane & 15;
    const float* fb = feat + (size_t)b * CS * NN;

    // ---- point-side B fragments (point = n0 + l15; same for all waves) ----
    short8 Bh[KT], Bm[KT], Bl[KT];
    #pragma unroll
    for (int kt = 0; kt < KT; ++kt) {
        #pragma unroll
        for (int e = 0; e < 8; ++e) {
            int kp = kt*32 + quad*8 + e;
            int c = kp / 3;
            float v = (c < C) ? fb[(size_t)c*NN + n0 + l15] : 0.f;
            ushort16_t h = f2bf(v);
            float r1 = v - bfbits2f(h);
            ushort16_t m = f2bf(r1);
            ushort16_t l = f2bf(r1 - bfbits2f(m));
            Bh[kt][e] = (short)h; Bm[kt][e] = (short)m; Bl[kt][e] = (short)l;
        }
    }

    const ushort16_t* hb = hilo + (size_t)b * NN * KP;
    const float* xxb = xxg + b * NN;

    // ---- distance phase: wave wv covers candidate tiles wv*4 .. wv*4+3 ----
    #pragma unroll
    for (int i = 0; i < 4; ++i) {
        int base = (wv*4 + i) * 64;
        floatx4 acc[4];
        #pragma unroll
        for (int st = 0; st < 4; ++st) {
            acc[st] = (floatx4){0.f,0.f,0.f,0.f};
            #pragma unroll
            for (int kt = 0; kt < KT; ++kt) {
                short8 a = *(const short8*)&hb[(size_t)(base + st*16 + l15)*KP + kt*32 + quad*8];
                acc[st] = __builtin_amdgcn_mfma_f32_16x16x32_bf16(a, Bh[kt], acc[st], 0, 0, 0);
                acc[st] = __builtin_amdgcn_mfma_f32_16x16x32_bf16(a, Bm[kt], acc[st], 0, 0, 0);
                acc[st] = __builtin_amdgcn_mfma_f32_16x16x32_bf16(a, Bl[kt], acc[st], 0, 0, 0);
            }
        }
        #pragma unroll
        for (int st = 0; st < 4; ++st) {
            #pragma unroll
            for (int r = 0; r < 4; ++r) {
                int cand = base + st*16 + quad*4 + r;
                Dt[l15*ST + cand] = 2.f*acc[st][r] - xxb[cand];
            }
        }
    }
    __syncthreads();

    // ---- selection phase: wave wv handles rows wv*2, wv*2+1 (interleaved ILP) ----
    int r0 = wv*2, r1 = wv*2 + 1;
    float v0[32], v1[32];
    #pragma unroll
    for (int j = 0; j < 32; ++j) {
        v0[j] = Dt[r0*ST + j*64 + lane];
        v1[j] = Dt[r1*ST + j*64 + lane];
    }
    float lv0 = v0[0], lv1 = v1[0];
    int lj0 = 0, lj1 = 0;
    #pragma unroll
    for (int j = 1; j < 32; ++j) {
        bool t0 = v0[j] > lv0; lv0 = t0 ? v0[j] : lv0; lj0 = t0 ? j : lj0;
        bool t1 = v1[j] > lv1; lv1 = t1 ? v1[j] : lv1; lj1 = t1 ? j : lj1;
    }
    int myg0 = 0, myg1 = 0;
    #pragma unroll 1
    for (int it = 0; it < KK; ++it) {
        float bv0 = lv0, bv1 = lv1;
        int bg0 = (lj0 << 6) | lane, bg1 = (lj1 << 6) | lane;
        #pragma unroll
        for (int s = 1; s < 64; s <<= 1) {
            float ov0 = __shfl_xor(bv0, s); int og0 = __shfl_xor(bg0, s);
            float ov1 = __shfl_xor(bv1, s); int og1 = __shfl_xor(bg1, s);
            bool t0 = (ov0 > bv0) || (ov0 == bv0 && og0 < bg0);
            bool t1 = (ov1 > bv1) || (ov1 == bv1 && og1 < bg1);
            bv0 = t0 ? ov0 : bv0; bg0 = t0 ? og0 : bg0;
            bv1 = t1 ? ov1 : bv1; bg1 = t1 ? og1 : bg1;
        }
        if (it == lane) { myg0 = bg0; myg1 = bg1; }
        bool s0 = (lane == (bg0 & 63)); int wj0 = bg0 >> 6;
        bool s1 = (lane == (bg1 & 63)); int wj1 = bg1 >> 6;
        #pragma unroll
        for (int j = 0; j < 32; ++j) {
            v0[j] = (s0 && j == wj0) ? -3.0e38f : v0[j];
            v1[j] = (s1 && j == wj1) ? -3.0e38f : v1[j];
        }
        lv0 = v0[0]; lj0 = 0; lv1 = v1[0]; lj1 = 0;
        #pragma unroll
        for (int j = 1; j < 32; ++j) {
            bool t0 = v0[j] > lv0; lv0 = t0 ? v0[j] : lv0; lj0 = t0 ? j : lj0;
            bool t1 = v1[j] > lv1; lv1 = t1 ? v1[j] : lv1; lj1 = t1 ? j : lj1;
        }
    }
    if (lane < KK) {
        idxout[((size_t)(b*NN + n0 + r0))*KK + lane] = myg0;
        idxout[((size_t)(b*NN + n0 + r1))*KK + lane] = myg1;
    }
}

// ================= lafe attention (post-knn) =================
__global__ __launch_bounds__(256, 1) void lafe_att_kernel(float* ws, const int* idx) {
    __shared__ float xs0[NN], xs1[NN], xs2[NN];
    int tid = threadIdx.x;
    int b = blockIdx.x >> 3;
    int n = ((blockIdx.x & 7) << 8) + tid;
    float* xm = ws + O_XMAN + b*19*NN;
    for (int i = tid; i < NN; i += 256) {
        xs0[i] = xm[i]; xs1[i] = xm[NN + i]; xs2[i] = xm[2*NN + i];
    }
    __syncthreads();
    float a0 = xs0[n], a1 = xs1[n], a2 = xs2[n];
    int ti[KK];
    #pragma unroll
    for (int k = 0; k < KK; ++k) ti[k] = idx[(b*NN + n)*KK + k] & (NN-1);
    const float* wl = ws + O_LA;
    float sa = wl[144];
    #pragma unroll
    for (int o = 0; o < 16; ++o) {
        float nf = wl[o*3+0]*a0 + wl[o*3+1]*a1 + wl[o*3+2]*a2 + wl[48+o];
        sa += wl[128+o]*nf;
    }
    float lg[KK]; float mx = -3.0e38f;
    #pragma unroll
    for (int k = 0; k < KK; ++k) {
        int m = ti[k];
        float d0 = a0 - xs0[m], d1 = a1 - xs1[m], d2 = a2 - xs2[m];
        float na = wl[144];
        #pragma unroll
        for (int o = 0; o < 16; ++o) {
            float ef = wl[64+o*3+0]*d0 + wl[64+o*3+1]*d1 + wl[64+o*3+2]*d2 + wl[112+o];
            na += wl[128+o]*ef;
        }
        float t = sa + na;
        t = t > 0.f ? t : 0.01f*t;
        lg[k] = t; mx = fmaxf(mx, t);
    }
    float ssum = 0.f;
    #pragma unroll
    for (int k = 0; k < KK; ++k) { lg[k] = expf(lg[k] - mx); ssum += lg[k]; }
    float vals[16];
    #pragma unroll
    for (int o = 0; o < 16; ++o) vals[o] = 0.f;
    #pragma unroll
    for (int k = 0; k < KK; ++k) {
        float coef = lg[k] / ssum;
        int m = ti[k];
        float d0 = a0 - xs0[m], d1 = a1 - xs1[m], d2 = a2 - xs2[m];
        #pragma unroll
        for (int o = 0; o < 16; ++o) {
            float ef = wl[64+o*3+0]*d0 + wl[64+o*3+1]*d1 + wl[64+o*3+2]*d2 + wl[112+o];
            vals[o] += coef * ef;
        }
    }
    #pragma unroll
    for (int o = 0; o < 16; ++o) {
        float v = vals[o];
        xm[(3+o)*NN + n] = v > 0.f ? v : expm1f(v);
    }
}

// ================= mlp (batch = blockIdx&7) =================
__global__ void mlp_kernel(float* ws) {
    __shared__ __align__(16) float xv[20];
    int tid = threadIdx.x;
    int b = blockIdx.x & 7, n = blockIdx.x >> 3;
    if (tid < 20) xv[tid] = (tid < 19) ? ws[O_XMAN + b*19*NN + tid*NN + n] : 0.f;
    __syncthreads();
    const float* mw = ws + O_MLPW;
    float acc = 0.f;
    #pragma unroll
    for (int c4 = 0; c4 < 5; ++c4) {
        float4 w = *(const float4*)&mw[tid*20 + c4*4];
        float4 g = *(const float4*)&xv[c4*4];
        acc += w.x*g.x + w.y*g.y + w.z*g.z + w.w*g.w;
    }
    float v = acc * ws[O_MLPSC + tid] + ws[O_MLPSH + tid];
    ws[O_XC2 + b*512*NN + tid*NN + n] = fmaxf(v, 0.f);
}

// ================= edge1 (fp32) =================
__global__ void edge1_kernel(float* ws, const int* idx) {
    __shared__ __align__(16) float g1T[KK*64];
    __shared__ __align__(16) float h1L[64*21];
    __shared__ __align__(16) float hrT[KK*64];
    __shared__ __align__(16) float attL[64*21];
    __shared__ float xcL[19];
    __shared__ int idxL[KK];
    int tid = threadIdx.x;
    int b = blockIdx.x >> 11, n = blockIdx.x & 2047;
    const float* xb = ws + O_XMAN + b*19*NN;
    if (tid < KK) idxL[tid] = idx[(b*NN + n)*KK + tid] & (NN-1);
    if (tid < 19) xcL[tid] = xb[tid*NN + n];
    __syncthreads();
    for (int i = tid; i < KK*64; i += 64) {
        int k = i >> 6, c = i & 63;
        int j = idxL[k];
        float v = 0.f;
        if (c < 19) v = xb[c*NN + j];
        else if (c < 38) v = xcL[c-19];
        else if (c < 57) v = xcL[c-38] - xb[(c-38)*NN + j];
        g1T[i] = v;
    }
    __syncthreads();
    int ro = tid & 15, kb = (tid >> 4) * 5;
    const float* w1p = ws + O_W1P;
    float acc[4][5];
    #pragma unroll
    for (int j = 0; j < 4; ++j)
        #pragma unroll
        for (int kk = 0; kk < 5; ++kk) acc[j][kk] = 0.f;
    for (int c4 = 0; c4 < 16; ++c4) {
        float4 gv[5], wv[4];
        #pragma unroll
        for (int kk = 0; kk < 5; ++kk) gv[kk] = *(const float4*)&g1T[(kb+kk)*64 + c4*4];
        #pragma unroll
        for (int j = 0; j < 4; ++j) wv[j] = *(const float4*)&w1p[(ro + 16*j)*64 + c4*4];
        #pragma unroll
        for (int j = 0; j < 4; ++j)
            #pragma unroll
            for (int kk = 0; kk < 5; ++kk)
                acc[j][kk] += wv[j].x*gv[kk].x + wv[j].y*gv[kk].y + wv[j].z*gv[kk].z + wv[j].w*gv[kk].w;
    }
    #pragma unroll
    for (int j = 0; j < 4; ++j) {
        int r = ro + 16*j;
        float s1 = ws[O_BN1SC + r], h1s = ws[O_BN1SH + r];
        float ps = ws[O_P1SC + r], ph = ws[O_P1SH + r];
        #pragma unroll
        for (int kk = 0; kk < 5; ++kk) {
            float v = acc[j][kk]*s1 + h1s;
            v = v > 0.f ? v : 0.2f*v;
            h1L[r*21 + kb + kk] = v;
            float hv = v*ps + ph;
            hrT[(kb+kk)*64 + r] = hv > 0.f ? hv : 0.f;
        }
    }
    __syncthreads();
    const float* p1w = ws + O_P1W;
    float ac2[4][5];
    #pragma unroll
    for (int j = 0; j < 4; ++j)
        #pragma unroll
        for (int kk = 0; kk < 5; ++kk) ac2[j][kk] = 0.f;
    for (int c4 = 0; c4 < 16; ++c4) {
        float4 gv[5], wv[4];
        #pragma unroll
        for (int kk = 0; kk < 5; ++kk) gv[kk] = *(const float4*)&hrT[(kb+kk)*64 + c4*4];
        #pragma unroll
        for (int j = 0; j < 4; ++j) wv[j] = *(const float4*)&p1w[(ro + 16*j)*64 + c4*4];
        #pragma unroll
        for (int j = 0; j < 4; ++j)
            #pragma unroll
            for (int kk = 0; kk < 5; ++kk)
                ac2[j][kk] += wv[j].x*gv[kk].x + wv[j].y*gv[kk].y + wv[j].z*gv[kk].z + wv[j].w*gv[kk].w;
    }
    #pragma unroll
    for (int j = 0; j < 4; ++j) {
        int r = ro + 16*j;
        float pb = ws[O_P1B + r];
        #pragma unroll
        for (int kk = 0; kk < 5; ++kk) attL[r*21 + kb + kk] = ac2[j][kk] + pb;
    }
    __syncthreads();
    {
        int o = tid;
        float av[KK]; float mx = -3.0e38f;
        #pragma unroll
        for (int k = 0; k < KK; ++k) { av[k] = attL[o*21 + k]; mx = fmaxf(mx, av[k]); }
        float ssum = 0.f;
        #pragma unroll
        for (int k = 0; k < KK; ++k) { av[k] = expf(av[k] - mx); ssum += av[k]; }
        float outv = 0.f;
        #pragma unroll
        for (int k = 0; k < KK; ++k) outv += h1L[o*21 + k] * (av[k]/ssum);
        float* xc1 = ws + O_XC1 + b*83*NN;
        xc1[(19+o)*NN + n] = outv;
        if (tid < 19) xc1[tid*NN + n] = xcL[tid];
    }
}

// ====== uv2: U2[b][n][r] = sum_c A2[r][c] * xc1[b][c][n] (batch = blockIdx&7) ======
__global__ __launch_bounds__(256, 2) void uv2_kernel(float* ws) {
    __shared__ ushort16_t xt[64*104];       // [point][chan] bf16, 13,312 B
    int tid = threadIdx.x;
    int b = blockIdx.x & 7;
    int pn0 = (blockIdx.x >> 3) << 6;       // 64 points per block (32 groups/batch)
    const float* xc1 = ws + O_XC1 + (size_t)b*83*NN;
    for (int i = tid; i < 96*64; i += 256) {
        int c = i >> 6, j = i & 63;
        xt[j*104 + c] = (c < 83) ? f2bf(xc1[c*NN + pn0 + j]) : (ushort16_t)0;
    }
    __syncthreads();
    int lane = tid & 63, wv = tid >> 6;
    int quad = lane >> 4, l15 = lane & 15;
    const ushort16_t* a2b = (const ushort16_t*)(ws + O_W2B16);
    floatx4 acc[4][4];
    #pragma unroll
    for (int rt = 0; rt < 4; ++rt)
        #pragma unroll
        for (int nt = 0; nt < 4; ++nt) acc[rt][nt] = (floatx4){0.f,0.f,0.f,0.f};
    #pragma unroll
    for (int kt = 0; kt < 3; ++kt) {
        int c0 = kt*32 + quad*8;
        short8 bfr[4], a[4];
        #pragma unroll
        for (int nt = 0; nt < 4; ++nt)
            bfr[nt] = *(const short8*)&xt[(nt*16 + l15)*104 + c0];
        #pragma unroll
        for (int rt = 0; rt < 4; ++rt)
            a[rt] = *(const short8*)&a2b[(wv*64 + rt*16 + l15)*96 + c0];
        #pragma unroll
        for (int rt = 0; rt < 4; ++rt)
            #pragma unroll
            for (int nt = 0; nt < 4; ++nt)
                acc[rt][nt] = __builtin_amdgcn_mfma_f32_16x16x32_bf16(a[rt], bfr[nt], acc[rt][nt], 0, 0, 0);
    }
    float* U2 = ws + O_XC2 + (size_t)b*512*NN;
    #pragma unroll
    for (int rt = 0; rt < 4; ++rt)
        #pragma unroll
        for (int nt = 0; nt < 4; ++nt) {
            int n = pn0 + nt*16 + l15;
            int r = wv*64 + rt*16 + quad*4;
            *(float4*)&U2[(size_t)n*256 + r] =
                make_float4(acc[rt][nt][0], acc[rt][nt][1], acc[rt][nt][2], acc[rt][nt][3]);
        }
}

// ================= edge2: 2 points/block, batch->XCD locked =================
__global__ __launch_bounds__(256, 2) void edge2_kernel(float* ws, const int* idx) {
    __shared__ __align__(16) ushort16_t hrb[48*264];   // 25,344 B (cols 40..47 pad, never read out)
    __shared__ __align__(16) float attL[256*41];       // 41,984 B
    __shared__ float vL[2*256];                        // 2,048 B
    __shared__ float scal[5*256];                      // 5,120 B
    __shared__ float xcL[2*84];
    __shared__ int idxL[40];

    int tid = threadIdx.x;
    int b  = blockIdx.x & 7;                // batch -> XCD lock (U2[b] L2-resident)
    int n0 = (blockIdx.x >> 3) << 1;        // 2 points per block, 1024 groups/batch

    scal[tid]        = ws[O_BN2SC + tid];
    scal[256 + tid]  = ws[O_BN2SH + tid];
    scal[512 + tid]  = ws[O_P2SC + tid];
    scal[768 + tid]  = ws[O_P2SH + tid];
    scal[1024 + tid] = ws[O_P2B + tid];
    if (tid < 40) idxL[tid] = idx[(b*NN + n0 + tid/20)*KK + (tid%20)] & (NN-1);
    if (tid < 166) {
        int p = tid / 83, c = tid - p*83;
        xcL[p*84 + c] = ws[O_XC1 + (size_t)b*83*NN + c*NN + n0 + p];
    }
    __syncthreads();

    // V (exact fp32): vL[p][row] = sum_c b2fT[c][row] * xc1[c][n0+p]  (coalesced weight reads)
    {
        const float* b2fT = ws + O_W2P;
        float a0 = 0.f, a1 = 0.f;
        #pragma unroll 4
        for (int c = 0; c < 83; ++c) {
            float w = b2fT[c*256 + tid];
            a0 += w * xcL[c];
            a1 += w * xcL[84 + c];
        }
        vL[tid] = a0; vL[256 + tid] = a1;
    }
    __syncthreads();

    // P1: hr tile [col][row] bf16 from U2 gather (L2-hit) + vL
    const float* U2 = ws + O_XC2 + (size_t)b*512*NN;
    #pragma unroll 10
    for (int col = 0; col < 40; ++col) {
        int p = col >= 20;
        int j = idxL[col];
        float u = U2[(size_t)j*256 + tid];
        float h2 = (u + vL[p*256 + tid]) * scal[tid] + scal[256 + tid];
        h2 = h2 > 0.f ? h2 : 0.2f*h2;
        float hv = h2*scal[512 + tid] + scal[768 + tid];
        hrb[col*264 + tid] = f2bf(fmaxf(hv, 0.f));
    }
    __syncthreads();

    // P2: att GEMM (p2w [256x256] bf16 x hr [256 x 48(40 used)])
    int lane = tid & 63, wv = tid >> 6;
    int quad = lane >> 4, l15 = lane & 15;
    const ushort16_t* p2wb = (const ushort16_t*)(ws + O_P2W16);
    floatx4 acc2[4][3];
    #pragma unroll
    for (int mt = 0; mt < 4; ++mt)
        #pragma unroll
        for (int nt = 0; nt < 3; ++nt) acc2[mt][nt] = (floatx4){0.f,0.f,0.f,0.f};
    for (int kt = 0; kt < 8; ++kt) {
        int c0 = kt*32 + quad*8;
        short8 a[4], bb3[3];
        #pragma unroll
        for (int mt = 0; mt < 4; ++mt)
            a[mt] = *(const short8*)&p2wb[(wv*64 + mt*16 + l15)*256 + c0];
        #pragma unroll
        for (int nt = 0; nt < 3; ++nt)
            bb3[nt] = *(const short8*)&hrb[(nt*16 + l15)*264 + c0];
        #pragma unroll
        for (int mt = 0; mt < 4; ++mt)
            #pragma unroll
            for (int nt = 0; nt < 3; ++nt)
                acc2[mt][nt] = __builtin_amdgcn_mfma_f32_16x16x32_bf16(a[mt], bb3[nt], acc2[mt][nt], 0, 0, 0);
    }
    #pragma unroll
    for (int mt = 0; mt < 4; ++mt) {
        int k0 = wv*64 + mt*16 + quad*4;
        #pragma unroll
        for (int nt = 0; nt < 3; ++nt) {
            int col = nt*16 + l15;
            if (col < 40) {
                #pragma unroll
                for (int r = 0; r < 4; ++r)
                    attL[(k0 + r)*41 + col] = acc2[mt][nt][r] + scal[1024 + k0 + r];
            }
        }
    }
    __syncthreads();

    // P3: per-row softmax over k + weighted sum of recomputed h2 -> XP2 (point-major, coalesced)
    float* xp2 = ws + O_XC2 + (size_t)b*512*NN + (size_t)256*NN;
    float sc = scal[tid], sh = scal[256 + tid];
    #pragma unroll
    for (int p = 0; p < 2; ++p) {
        float av[KK]; float mx = -3.0e38f;
        #pragma unroll
        for (int k = 0; k < KK; ++k) { av[k] = attL[tid*41 + p*20 + k]; mx = fmaxf(mx, av[k]); }
        float ssum = 0.f;
        #pragma unroll
        for (int k = 0; k < KK; ++k) { av[k] = expf(av[k] - mx); ssum += av[k]; }
        float inv = 1.f / ssum;
        float vpr = vL[p*256 + tid];
        float sacc = 0.f;
        #pragma unroll
        for (int k = 0; k < KK; ++k) {
            int j = idxL[p*20 + k];
            float u = U2[(size_t)j*256 + tid];
            float h2 = (u + vpr)*sc + sh;
            h2 = h2 > 0.f ? h2 : 0.2f*h2;
            sacc += av[k] * inv * h2;
        }
        xp2[(size_t)(n0 + p)*256 + tid] = sacc;
    }
}

// ================= final: out = lrelu(bn3(w3 @ x_c2)) -> fp32 =================
// x_c2 rows 0..255 from x_mlp [c][n]; rows 256..511 from XP2 [n][r] (point-major)
__global__ void final_kernel(const float* ws, float* out) {
    __shared__ __align__(16) float tileF[512*20];
    int tid = threadIdx.x;
    int b = blockIdx.x & 7;
    int n0 = (blockIdx.x >> 3) << 4;
    const float* xc2 = ws + O_XC2 + (size_t)b*512*NN;
    for (int i = tid; i < 256*16; i += 256) {
        int c = i >> 4, nn = i & 15;
        tileF[c*20 + nn] = xc2[c*NN + n0 + nn];
    }
    const float* xp2 = xc2 + (size_t)256*NN;
    #pragma unroll
    for (int it = 0; it < 16; ++it) {
        tileF[(256 + tid)*20 + it] = xp2[(size_t)(n0 + it)*256 + tid];
    }
    __syncthreads();
    const float* w3p = ws + O_W3P;
    int r0 = tid*2, r1 = r0 + 1;
    float acc0[16], acc1[16];
    #pragma unroll
    for (int q = 0; q < 16; ++q) { acc0[q] = 0.f; acc1[q] = 0.f; }
    #pragma unroll 4
    for (int c = 0; c < 512; ++c) {
        float w0 = w3p[r0*512 + c], w1v = w3p[r1*512 + c];
        const float4* tr = (const float4*)&tileF[c*20];
        #pragma unroll
        for (int q = 0; q < 4; ++q) {
            float4 t = tr[q];
            acc0[q*4+0] += w0*t.x;  acc0[q*4+1] += w0*t.y;  acc0[q*4+2] += w0*t.z;  acc0[q*4+3] += w0*t.w;
            acc1[q*4+0] += w1v*t.x; acc1[q*4+1] += w1v*t.y; acc1[q*4+2] += w1v*t.z; acc1[q*4+3] += w1v*t.w;
        }
    }
    float s0 = ws[O_BN3SC + r0], q0 = ws[O_BN3SH + r0];
    float s1 = ws[O_BN3SC + r1], q1 = ws[O_BN3SH + r1];
    float* ob = out + (size_t)b*512*NN;
    #pragma unroll
    for (int nn = 0; nn < 16; ++nn) {
        float v = acc0[nn]*s0 + q0; v = v > 0.f ? v : 0.2f*v;
        ob[r0*NN + n0 + nn] = v;
        float u = acc1[nn]*s1 + q1; u = u > 0.f ? u : 0.2f*u;
        ob[r1*NN + n0 + nn] = u;
    }
}

extern "C" void kernel_launch(void* const* d_in, const int* in_sizes, int n_in,
                              void* d_out, int out_size, void* d_ws, size_t ws_size,
                              hipStream_t stream) {
    float* ws = (float*)d_ws;
    float* out = (float*)d_out;
    ushort16_t* hilo = (ushort16_t*)(ws + O_HILO);
    float* xxq = ws + O_XXQ;

    detect_kernel<<<1, 64, 0, stream>>>(d_in[0], (int*)ws + O_FLAG);
    prep_kernel<<<64, 256, 0, stream>>>(d_in[1], d_in[2], d_in[3], d_in[4], d_in[5], d_in[6],
                                        d_in[7], d_in[8], d_in[9], d_in[10], d_in[11], d_in[12],
                                        d_in[13], d_in[14], d_in[15], d_in[16], d_in[17], d_in[18],
                                        d_in[19], d_in[20], d_in[21], ws);
    // lafe = xconv + knn3 (fused MFMA+select) + attention
    xconv_kernel<<<192, 256, 0, stream>>>(d_in[0], ws);
    hilo_kernel<3, 19, 32><<<256, 256, 0, stream>>>(ws + O_XMAN, hilo);
    xx_kernel<3, 19><<<64, 256, 0, stream>>>(ws + O_XMAN, xxq);
    knn_fused_kernel<3, 19, 32><<<1024, 512, 0, stream>>>(ws + O_XMAN, hilo, xxq, (int*)(ws + O_IDX3));
    lafe_att_kernel<<<64, 256, 0, stream>>>(ws, (const int*)(ws + O_IDX3));
    // knn on x_manet (C=19)
    hilo_kernel<19, 19, 64><<<1024, 256, 0, stream>>>(ws + O_XMAN, hilo);
    xx_kernel<19, 19><<<64, 256, 0, stream>>>(ws + O_XMAN, xxq);
    knn_fused_kernel<19, 19, 64><<<1024, 512, 0, stream>>>(ws + O_XMAN, hilo, xxq, (int*)(ws + O_IDX2));
    edge1_kernel<<<BB*NN, 64, 0, stream>>>(ws, (const int*)(ws + O_IDX2));
    // knn on x_c1 (C=83)
    hilo_kernel<83, 83, 256><<<2048, 256, 0, stream>>>(ws + O_XC1, hilo);
    xx_kernel<83, 83><<<64, 256, 0, stream>>>(ws + O_XC1, xxq);
    knn_fused_kernel<83, 83, 256><<<1024, 512, 0, stream>>>(ws + O_XC1, hilo, xxq, (int*)(ws + O_IDX3));
    // edge2 via A/B decomposition: U2 = A @ xc1 (MFMA, batch-locked), then fused gather kernel
    uv2_kernel<<<256, 256, 0, stream>>>(ws);
    edge2_kernel<<<BB*1024, 256, 0, stream>>>(ws, (const int*)(ws + O_IDX3));
    mlp_kernel<<<BB*NN, 256, 0, stream>>>(ws);
    final_kernel<<<BB*(NN/16), 256, 0, stream>>>(ws, out);
}

// Round 5
// 1483.090 us; speedup vs baseline: 1.2734x; 1.1828x over previous
//
#include <hip/hip_runtime.h>
#include <hip/hip_bf16.h>
#include <math.h>

typedef __hip_bfloat16 bf16;
typedef unsigned short ushort16_t;
typedef unsigned int uint32;
typedef __attribute__((ext_vector_type(8))) short short8;
typedef __attribute__((ext_vector_type(4))) float floatx4;

#define BB 8
#define NN 2048
#define KK 20

// ---- workspace layout (float offsets) ----
#define O_XMAN  0                        // [8][19][2048]  rows 0..2 = x (fp32), rows 3..18 = lafe out
#define O_XC1   311296                   // [8][83][2048]
#define O_XC2   1671168                  // [8][512][2048]:
                                         //   pre-mlp: [b] rows 0..255 region = U2 fp32 [2048][256]
                                         //            [b] rows 256..511 region = XP2 fp32 [2048][256] (point-major xp2)
                                         //   post-mlp: rows 0..255 = x_mlp [c][n]
                                         //   also reused earlier: knn scratch (hilo/xx)
#define O_IDX2  10059776                 // int [8][2048][20]
#define O_IDX3  10387456                 // int [8][2048][20] (also temp home for lafe knn idx)
#define O_MLPW  10715136                 // [256][20] padded
#define O_MLPSC 10720256
#define O_MLPSH 10720512
#define O_W1P   10720768                 // [64][64] padded
#define O_BN1SC 10724864
#define O_BN1SH 10724928
#define O_P1SC  10724992
#define O_P1SH  10725056
#define O_P1W   10725120                 // [64][64]
#define O_P1B   10729216
#define O_W2P   10729280                 // b2fT fp32 [84][256] (B = Wce + Wdiff, transposed)
#define O_BN2SC 10794816
#define O_BN2SH 10795072
#define O_P2SC  10795328
#define O_P2SH  10795584
#define O_P2W   10795840                 // (spare)
#define O_P2B   10861376
#define O_W3P   10861632                 // [512][512]
#define O_BN3SC 11123776
#define O_BN3SH 11124288
#define O_LA    11124800                 // w1[48] b1[16] w2[48] b2[16] w3[16] b3[1]
#define O_FLAG  11124960                 // int: 1 if inputs are fp32, 0 if bf16
#define O_W2B16 11125760                 // ushort A2b [256][96] bf16 (A = Wnb - Wdiff)
#define O_P2W16 11162624                 // ushort [256][256] bf16 p2w

// knn scratch inside XC2 region (consumed before uv2/edge2/mlp write XC2):
#define O_HILO  O_XC2
#define O_XXQ   (O_XC2 + 2097152)

__device__ __forceinline__ float ldin(const void* p, int i, int f32) {
    return f32 ? ((const float*)p)[i]
               : __bfloat162float(((const bf16*)p)[i]);
}

__device__ __forceinline__ ushort16_t f2bf(float v) {
    union { bf16 h; ushort16_t u; } x; x.h = __float2bfloat16(v); return x.u;
}

__device__ __forceinline__ float bfbits2f(ushort16_t u) {
    union { uint32 i; float f; } c; c.i = ((uint32)u) << 16; return c.f;
}

// ============ detect: are inputs fp32 or bf16? ============
__global__ void detect_kernel(const void* x, int* flag) {
    if (threadIdx.x == 0 && blockIdx.x == 0) {
        const unsigned short* u = (const unsigned short*)x;
        int bad = 0;
        for (int i = 0; i < 64; ++i) {
            int e = (u[i] >> 7) & 0xFF;
            if (e >= 0x86) bad++;
        }
        *flag = (bad > 0) ? 1 : 0;
    }
}

// ================= prep =================
__global__ void prep_kernel(
    const void* la_w1, const void* la_b1, const void* la_w2, const void* la_b2,
    const void* la_w3, const void* la_b3,
    const void* mlp_w, const void* mlp_b, const void* mlp_bn,
    const void* w1, const void* bn1, const void* w2, const void* bn2,
    const void* w3, const void* bn3,
    const void* p1_bn, const void* p1_w, const void* p1_b,
    const void* p2_bn, const void* p2_w, const void* p2_b,
    float* ws)
{
    const int f32 = ((const int*)ws)[O_FLAG];
    int gid = blockIdx.x * blockDim.x + threadIdx.x;
    int gsz = gridDim.x * blockDim.x;

    for (int i = gid; i < 256*20; i += gsz) {
        int o = i / 20, c = i - o*20;
        ws[O_MLPW + i] = (c < 19) ? ldin(mlp_w, o*19 + c, f32) : 0.f;
    }
    for (int c = gid; c < 256; c += gsz) {
        float g = ldin(mlp_bn, c, f32), be = ldin(mlp_bn, 256+c, f32);
        float m = ldin(mlp_bn, 512+c, f32), vv = ldin(mlp_bn, 768+c, f32);
        float s = g / sqrtf(vv + 1e-5f);
        ws[O_MLPSC + c] = s;
        ws[O_MLPSH + c] = be + (ldin(mlp_b, c, f32) - m) * s;
    }
    for (int i = gid; i < 64*64; i += gsz) {
        int o = i >> 6, c = i & 63;
        ws[O_W1P + i] = (c < 57) ? ldin(w1, o*57 + c, f32) : 0.f;
    }
    for (int c = gid; c < 64; c += gsz) {
        float g = ldin(bn1, c, f32), be = ldin(bn1, 64+c, f32);
        float m = ldin(bn1, 128+c, f32), vv = ldin(bn1, 192+c, f32);
        float s = g / sqrtf(vv + 1e-5f);
        ws[O_BN1SC + c] = s; ws[O_BN1SH + c] = be - m*s;
        float g2 = ldin(p1_bn, c, f32), be2 = ldin(p1_bn, 64+c, f32);
        float m2 = ldin(p1_bn, 128+c, f32), vv2 = ldin(p1_bn, 192+c, f32);
        float s2 = g2 / sqrtf(vv2 + 1e-5f);
        ws[O_P1SC + c] = s2; ws[O_P1SH + c] = be2 - m2*s2;
        ws[O_P1B + c] = ldin(p1_b, c, f32);
    }
    for (int i = gid; i < 64*64; i += gsz) ws[O_P1W + i] = ldin(p1_w, i, f32);
    for (int c = gid; c < 256; c += gsz) {
        float g = ldin(bn2, c, f32), be = ldin(bn2, 256+c, f32);
        float m = ldin(bn2, 512+c, f32), vv = ldin(bn2, 768+c, f32);
        float s = g / sqrtf(vv + 1e-5f);
        ws[O_BN2SC + c] = s; ws[O_BN2SH + c] = be - m*s;
        float g2 = ldin(p2_bn, c, f32), be2 = ldin(p2_bn, 256+c, f32);
        float m2 = ldin(p2_bn, 512+c, f32), vv2 = ldin(p2_bn, 768+c, f32);
        float s2 = g2 / sqrtf(vv2 + 1e-5f);
        ws[O_P2SC + c] = s2; ws[O_P2SH + c] = be2 - m2*s2;
        ws[O_P2B + c] = ldin(p2_b, c, f32);
    }
    for (int i = gid; i < 512*512; i += gsz) ws[O_W3P + i] = ldin(w3, i, f32);
    for (int c = gid; c < 512; c += gsz) {
        float g = ldin(bn3, c, f32), be = ldin(bn3, 512+c, f32);
        float m = ldin(bn3, 1024+c, f32), vv = ldin(bn3, 1536+c, f32);
        float s = g / sqrtf(vv + 1e-5f);
        ws[O_BN3SC + c] = s; ws[O_BN3SH + c] = be - m*s;
    }
    for (int i = gid; i < 48; i += gsz) ws[O_LA + i]       = ldin(la_w1, i, f32);
    for (int i = gid; i < 16; i += gsz) ws[O_LA + 48 + i]  = ldin(la_b1, i, f32);
    for (int i = gid; i < 48; i += gsz) ws[O_LA + 64 + i]  = ldin(la_w2, i, f32);
    for (int i = gid; i < 16; i += gsz) ws[O_LA + 112 + i] = ldin(la_b2, i, f32);
    for (int i = gid; i < 16; i += gsz) ws[O_LA + 128 + i] = ldin(la_w3, i, f32);
    if (gid == 0) ws[O_LA + 144] = ldin(la_b3, 0, f32);

    // edge2 decomposition: A = Wnb - Wdiff (bf16, [256][96] padded),
    //                      B^T = (Wce + Wdiff)^T (fp32, [84][256] column-major for coalesced V)
    ushort16_t* a2b = (ushort16_t*)(ws + O_W2B16);
    for (int i = gid; i < 256*96; i += gsz) {
        int row = i / 96, c = i - row*96;
        float v = (c < 83) ? (ldin(w2, row*249 + c, f32) - ldin(w2, row*249 + 166 + c, f32)) : 0.f;
        a2b[i] = f2bf(v);
    }
    float* b2fT = ws + O_W2P;
    for (int i = gid; i < 84*256; i += gsz) {
        int c = i >> 8, row = i & 255;
        b2fT[i] = (c < 83) ? (ldin(w2, row*249 + 83 + c, f32) + ldin(w2, row*249 + 166 + c, f32)) : 0.f;
    }
    ushort16_t* pwb = (ushort16_t*)(ws + O_P2W16);
    for (int i = gid; i < 256*256; i += gsz) pwb[i] = f2bf(ldin(p2_w, i, f32));
}

// ================= xconv: x -> fp32 into XMAN rows 0..2 =================
__global__ __launch_bounds__(256) void xconv_kernel(const void* x, float* ws) {
    const int f32 = ((const int*)ws)[O_FLAG];
    int gid = blockIdx.x*256 + threadIdx.x;     // 0 .. 8*3*2048-1
    int b = gid / (3*NN), r = gid - b*3*NN;
    ws[O_XMAN + b*19*NN + r] = ldin(x, gid, f32);
}

// ====== 3-way bf16 split precompute (batch locked to XCD via blockIdx&7) ======
template<int C, int CS, int KP>
__global__ void hilo_kernel(const float* feat, ushort16_t* out) {
    int b  = blockIdx.x & 7;
    int lb = blockIdx.x >> 3;
    int nb = gridDim.x >> 3;
    const float* fb = feat + (size_t)b*CS*NN;
    ushort16_t* ob = out + (size_t)b*NN*KP;
    for (int i = lb*blockDim.x + threadIdx.x; i < C*NN; i += nb*blockDim.x) {
        int c = i >> 11, n = i & (NN-1);
        float v = fb[(size_t)c*NN + n];
        ushort16_t h = f2bf(v);
        float r1 = v - bfbits2f(h);
        ushort16_t m = f2bf(r1);
        ushort16_t l = f2bf(r1 - bfbits2f(m));
        size_t base = (size_t)n*KP + 3*c;
        ob[base] = h; ob[base+1] = m; ob[base+2] = l;
    }
    constexpr int PAD = KP - 3*C;
    for (int i = lb*blockDim.x + threadIdx.x; i < NN*PAD; i += nb*blockDim.x) {
        int n = i / PAD, p = i - n*PAD;
        ob[(size_t)n*KP + 3*C + p] = 0;
    }
}

// ====== exact fp32 squared norms ======
template<int C, int CS>
__global__ __launch_bounds__(256) void xx_kernel(const float* feat, float* xxg) {
    int gid = blockIdx.x*256 + threadIdx.x;      // BB*NN total
    int b = gid >> 11, n = gid & (NN-1);
    const float* fb = feat + (size_t)b*CS*NN;
    float s = 0.f;
    #pragma unroll
    for (int c = 0; c < C; ++c) { float v = fb[c*NN + n]; s += v*v; }
    xxg[gid] = s;
}

// ====== fused knn: MFMA distance tile (16 pts x 2048 cands) in LDS, then
//        per-lane lazy top-3 + u64-butterfly 20x extraction. batch = blockIdx&7 ======
// key = (ordered_u32(d) << 32) | (2047 - cand): larger value wins, tie -> smaller cand.
template<int C, int CS, int KP>
__global__ __launch_bounds__(512, 2) void knn_fused_kernel(
    const float* feat, const ushort16_t* hilo, const float* xxg, int* idxout)
{
    constexpr int KT = KP / 32;
    constexpr int ST = 2057;                 // odd stride -> conflict-free LDS
    __shared__ float Dt[16 * ST];            // 131,648 B
    int tid = threadIdx.x;
    int b  = blockIdx.x & 7;                 // batch -> XCD lock
    int n0 = (blockIdx.x >> 3) << 4;         // 16 points per block (128 groups/batch)
    int lane = tid & 63, wv = tid >> 6;      // 8 waves
    int quad = lane >> 4, l15 = lane & 15;
    const float* fb = feat + (size_t)b * CS * NN;

    // ---- point-side B fragments (point = n0 + l15; same for all waves) ----
    short8 Bh[KT], Bm[KT], Bl[KT];
    #pragma unroll
    for (int kt = 0; kt < KT; ++kt) {
        #pragma unroll
        for (int e = 0; e < 8; ++e) {
            int kp = kt*32 + quad*8 + e;
            int c = kp / 3;
            float v = (c < C) ? fb[(size_t)c*NN + n0 + l15] : 0.f;
            ushort16_t h = f2bf(v);
            float r1 = v - bfbits2f(h);
            ushort16_t m = f2bf(r1);
            ushort16_t l = f2bf(r1 - bfbits2f(m));
            Bh[kt][e] = (short)h; Bm[kt][e] = (short)m; Bl[kt][e] = (short)l;
        }
    }

    const ushort16_t* hb = hilo + (size_t)b * NN * KP;
    const float* xxb = xxg + b * NN;

    // ---- distance phase: wave wv covers candidate tiles wv*4 .. wv*4+3 ----
    #pragma unroll
    for (int i = 0; i < 4; ++i) {
        int base = (wv*4 + i) * 64;
        floatx4 acc[4];
        #pragma unroll
        for (int st = 0; st < 4; ++st) {
            acc[st] = (floatx4){0.f,0.f,0.f,0.f};
            #pragma unroll
            for (int kt = 0; kt < KT; ++kt) {
                short8 a = *(const short8*)&hb[(size_t)(base + st*16 + l15)*KP + kt*32 + quad*8];
                acc[st] = __builtin_amdgcn_mfma_f32_16x16x32_bf16(a, Bh[kt], acc[st], 0, 0, 0);
                acc[st] = __builtin_amdgcn_mfma_f32_16x16x32_bf16(a, Bm[kt], acc[st], 0, 0, 0);
                acc[st] = __builtin_amdgcn_mfma_f32_16x16x32_bf16(a, Bl[kt], acc[st], 0, 0, 0);
            }
        }
        #pragma unroll
        for (int st = 0; st < 4; ++st) {
            #pragma unroll
            for (int r = 0; r < 4; ++r) {
                int cand = base + st*16 + quad*4 + r;
                Dt[l15*ST + cand] = 2.f*acc[st][r] - xxb[cand];
            }
        }
    }
    __syncthreads();

    // ---- selection: wave wv owns rows wv*2, wv*2+1 (interleaved for ILP) ----
    int r0 = wv*2, r1 = wv*2 + 1;
    unsigned int basei = 2047u - (unsigned int)lane;
    unsigned int a0[32], a1[32];
    unsigned int dead0 = 0, dead1 = 0;
    unsigned long long p0 = 0, p1 = 0, p2 = 0;   // row0 lane-local sorted top-3
    unsigned long long q0 = 0, q1 = 0, q2 = 0;   // row1
    #pragma unroll
    for (int j = 0; j < 32; ++j) {
        unsigned int u0 = __float_as_uint(Dt[r0*ST + j*64 + lane]);
        unsigned int u1 = __float_as_uint(Dt[r1*ST + j*64 + lane]);
        unsigned int o0 = u0 ^ (unsigned int)(((int)u0 >> 31) | 0x80000000);
        unsigned int o1 = u1 ^ (unsigned int)(((int)u1 >> 31) | 0x80000000);
        a0[j] = o0; a1[j] = o1;
        unsigned long long k0 = ((unsigned long long)o0 << 32) | (basei - j*64);
        unsigned long long k1 = ((unsigned long long)o1 << 32) | (basei - j*64);
        bool g00 = k0 > p0, g01 = k0 > p1, g02 = k0 > p2;
        p2 = g01 ? p1 : (g02 ? k0 : p2);
        p1 = g00 ? p0 : (g01 ? k0 : p1);
        p0 = g00 ? k0 : p0;
        bool g10 = k1 > q0, g11 = k1 > q1, g12 = k1 > q2;
        q2 = g11 ? q1 : (g12 ? k1 : q2);
        q1 = g10 ? q0 : (g11 ? k1 : q1);
        q0 = g10 ? k1 : q0;
    }
    int myg0 = 0, myg1 = 0;
    #pragma unroll 1
    for (int it = 0; it < KK; ++it) {
        unsigned long long b0 = p0, b1 = q0;
        #pragma unroll
        for (int sh = 1; sh < 64; sh <<= 1) {
            unsigned long long o0 = __shfl_xor(b0, sh);
            unsigned long long o1 = __shfl_xor(b1, sh);
            b0 = (o0 > b0) ? o0 : b0;
            b1 = (o1 > b1) ? o1 : b1;
        }
        if (lane == it) {
            myg0 = (int)(2047u - (unsigned int)b0);
            myg1 = (int)(2047u - (unsigned int)b1);
        }
        if (p0 == b0) {                      // exactly one lane owns the winner
            dead0 |= 1u << ((int)(basei - (unsigned int)b0) >> 6);
            p0 = p1; p1 = p2; p2 = 0;
        }
        if (q0 == b1) {
            dead1 |= 1u << ((int)(basei - (unsigned int)b1) >> 6);
            q0 = q1; q1 = q2; q2 = 0;
        }
        if (__any((p0 == 0ull) | (q0 == 0ull))) {   // rare: lane popped 3x since build
            if (p0 == 0ull) {
                unsigned long long t0 = 0, t1 = 0, t2 = 0;
                #pragma unroll
                for (int j = 0; j < 32; ++j) {
                    unsigned long long k = ((dead0 >> j) & 1u) ? 0ull
                        : (((unsigned long long)a0[j] << 32) | (basei - j*64));
                    bool g0 = k > t0, g1 = k > t1, g2 = k > t2;
                    t2 = g1 ? t1 : (g2 ? k : t2);
                    t1 = g0 ? t0 : (g1 ? k : t1);
                    t0 = g0 ? k : t0;
                }
                p0 = t0; p1 = t1; p2 = t2;
            }
            if (q0 == 0ull) {
                unsigned long long t0 = 0, t1 = 0, t2 = 0;
                #pragma unroll
                for (int j = 0; j < 32; ++j) {
                    unsigned long long k = ((dead1 >> j) & 1u) ? 0ull
                        : (((unsigned long long)a1[j] << 32) | (basei - j*64));
                    bool g0 = k > t0, g1 = k > t1, g2 = k > t2;
                    t2 = g1 ? t1 : (g2 ? k : t2);
                    t1 = g0 ? t0 : (g1 ? k : t1);
                    t0 = g0 ? k : t0;
                }
                q0 = t0; q1 = t1; q2 = t2;
            }
        }
    }
    if (lane < KK) {
        idxout[((size_t)(b*NN + n0 + r0))*KK + lane] = myg0;
        idxout[((size_t)(b*NN + n0 + r1))*KK + lane] = myg1;
    }
}

// ================= lafe attention (post-knn) =================
__global__ __launch_bounds__(256, 1) void lafe_att_kernel(float* ws, const int* idx) {
    __shared__ float xs0[NN], xs1[NN], xs2[NN];
    int tid = threadIdx.x;
    int b = blockIdx.x >> 3;
    int n = ((blockIdx.x & 7) << 8) + tid;
    float* xm = ws + O_XMAN + b*19*NN;
    for (int i = tid; i < NN; i += 256) {
        xs0[i] = xm[i]; xs1[i] = xm[NN + i]; xs2[i] = xm[2*NN + i];
    }
    __syncthreads();
    float a0 = xs0[n], a1 = xs1[n], a2 = xs2[n];
    int ti[KK];
    #pragma unroll
    for (int k = 0; k < KK; ++k) ti[k] = idx[(b*NN + n)*KK + k] & (NN-1);
    const float* wl = ws + O_LA;
    float sa = wl[144];
    #pragma unroll
    for (int o = 0; o < 16; ++o) {
        float nf = wl[o*3+0]*a0 + wl[o*3+1]*a1 + wl[o*3+2]*a2 + wl[48+o];
        sa += wl[128+o]*nf;
    }
    float lg[KK]; float mx = -3.0e38f;
    #pragma unroll
    for (int k = 0; k < KK; ++k) {
        int m = ti[k];
        float d0 = a0 - xs0[m], d1 = a1 - xs1[m], d2 = a2 - xs2[m];
        float na = wl[144];
        #pragma unroll
        for (int o = 0; o < 16; ++o) {
            float ef = wl[64+o*3+0]*d0 + wl[64+o*3+1]*d1 + wl[64+o*3+2]*d2 + wl[112+o];
            na += wl[128+o]*ef;
        }
        float t = sa + na;
        t = t > 0.f ? t : 0.01f*t;
        lg[k] = t; mx = fmaxf(mx, t);
    }
    float ssum = 0.f;
    #pragma unroll
    for (int k = 0; k < KK; ++k) { lg[k] = expf(lg[k] - mx); ssum += lg[k]; }
    float vals[16];
    #pragma unroll
    for (int o = 0; o < 16; ++o) vals[o] = 0.f;
    #pragma unroll
    for (int k = 0; k < KK; ++k) {
        float coef = lg[k] / ssum;
        int m = ti[k];
        float d0 = a0 - xs0[m], d1 = a1 - xs1[m], d2 = a2 - xs2[m];
        #pragma unroll
        for (int o = 0; o < 16; ++o) {
            float ef = wl[64+o*3+0]*d0 + wl[64+o*3+1]*d1 + wl[64+o*3+2]*d2 + wl[112+o];
            vals[o] += coef * ef;
        }
    }
    #pragma unroll
    for (int o = 0; o < 16; ++o) {
        float v = vals[o];
        xm[(3+o)*NN + n] = v > 0.f ? v : expm1f(v);
    }
}

// ================= mlp (batch = blockIdx&7) =================
__global__ void mlp_kernel(float* ws) {
    __shared__ __align__(16) float xv[20];
    int tid = threadIdx.x;
    int b = blockIdx.x & 7, n = blockIdx.x >> 3;
    if (tid < 20) xv[tid] = (tid < 19) ? ws[O_XMAN + b*19*NN + tid*NN + n] : 0.f;
    __syncthreads();
    const float* mw = ws + O_MLPW;
    float acc = 0.f;
    #pragma unroll
    for (int c4 = 0; c4 < 5; ++c4) {
        float4 w = *(const float4*)&mw[tid*20 + c4*4];
        float4 g = *(const float4*)&xv[c4*4];
        acc += w.x*g.x + w.y*g.y + w.z*g.z + w.w*g.w;
    }
    float v = acc * ws[O_MLPSC + tid] + ws[O_MLPSH + tid];
    ws[O_XC2 + b*512*NN + tid*NN + n] = fmaxf(v, 0.f);
}

// ================= edge1 (fp32) =================
__global__ void edge1_kernel(float* ws, const int* idx) {
    __shared__ __align__(16) float g1T[KK*64];
    __shared__ __align__(16) float h1L[64*21];
    __shared__ __align__(16) float hrT[KK*64];
    __shared__ __align__(16) float attL[64*21];
    __shared__ float xcL[19];
    __shared__ int idxL[KK];
    int tid = threadIdx.x;
    int b = blockIdx.x >> 11, n = blockIdx.x & 2047;
    const float* xb = ws + O_XMAN + b*19*NN;
    if (tid < KK) idxL[tid] = idx[(b*NN + n)*KK + tid] & (NN-1);
    if (tid < 19) xcL[tid] = xb[tid*NN + n];
    __syncthreads();
    for (int i = tid; i < KK*64; i += 64) {
        int k = i >> 6, c = i & 63;
        int j = idxL[k];
        float v = 0.f;
        if (c < 19) v = xb[c*NN + j];
        else if (c < 38) v = xcL[c-19];
        else if (c < 57) v = xcL[c-38] - xb[(c-38)*NN + j];
        g1T[i] = v;
    }
    __syncthreads();
    int ro = tid & 15, kb = (tid >> 4) * 5;
    const float* w1p = ws + O_W1P;
    float acc[4][5];
    #pragma unroll
    for (int j = 0; j < 4; ++j)
        #pragma unroll
        for (int kk = 0; kk < 5; ++kk) acc[j][kk] = 0.f;
    for (int c4 = 0; c4 < 16; ++c4) {
        float4 gv[5], wv[4];
        #pragma unroll
        for (int kk = 0; kk < 5; ++kk) gv[kk] = *(const float4*)&g1T[(kb+kk)*64 + c4*4];
        #pragma unroll
        for (int j = 0; j < 4; ++j) wv[j] = *(const float4*)&w1p[(ro + 16*j)*64 + c4*4];
        #pragma unroll
        for (int j = 0; j < 4; ++j)
            #pragma unroll
            for (int kk = 0; kk < 5; ++kk)
                acc[j][kk] += wv[j].x*gv[kk].x + wv[j].y*gv[kk].y + wv[j].z*gv[kk].z + wv[j].w*gv[kk].w;
    }
    #pragma unroll
    for (int j = 0; j < 4; ++j) {
        int r = ro + 16*j;
        float s1 = ws[O_BN1SC + r], h1s = ws[O_BN1SH + r];
        float ps = ws[O_P1SC + r], ph = ws[O_P1SH + r];
        #pragma unroll
        for (int kk = 0; kk < 5; ++kk) {
            float v = acc[j][kk]*s1 + h1s;
            v = v > 0.f ? v : 0.2f*v;
            h1L[r*21 + kb + kk] = v;
            float hv = v*ps + ph;
            hrT[(kb+kk)*64 + r] = hv > 0.f ? hv : 0.f;
        }
    }
    __syncthreads();
    const float* p1w = ws + O_P1W;
    float ac2[4][5];
    #pragma unroll
    for (int j = 0; j < 4; ++j)
        #pragma unroll
        for (int kk = 0; kk < 5; ++kk) ac2[j][kk] = 0.f;
    for (int c4 = 0; c4 < 16; ++c4) {
        float4 gv[5], wv[4];
        #pragma unroll
        for (int kk = 0; kk < 5; ++kk) gv[kk] = *(const float4*)&hrT[(kb+kk)*64 + c4*4];
        #pragma unroll
        for (int j = 0; j < 4; ++j) wv[j] = *(const float4*)&p1w[(ro + 16*j)*64 + c4*4];
        #pragma unroll
        for (int j = 0; j < 4; ++j)
            #pragma unroll
            for (int kk = 0; kk < 5; ++kk)
                ac2[j][kk] += wv[j].x*gv[kk].x + wv[j].y*gv[kk].y + wv[j].z*gv[kk].z + wv[j].w*gv[kk].w;
    }
    #pragma unroll
    for (int j = 0; j < 4; ++j) {
        int r = ro + 16*j;
        float pb = ws[O_P1B + r];
        #pragma unroll
        for (int kk = 0; kk < 5; ++kk) attL[r*21 + kb + kk] = ac2[j][kk] + pb;
    }
    __syncthreads();
    {
        int o = tid;
        float av[KK]; float mx = -3.0e38f;
        #pragma unroll
        for (int k = 0; k < KK; ++k) { av[k] = attL[o*21 + k]; mx = fmaxf(mx, av[k]); }
        float ssum = 0.f;
        #pragma unroll
        for (int k = 0; k < KK; ++k) { av[k] = expf(av[k] - mx); ssum += av[k]; }
        float outv = 0.f;
        #pragma unroll
        for (int k = 0; k < KK; ++k) outv += h1L[o*21 + k] * (av[k]/ssum);
        float* xc1 = ws + O_XC1 + b*83*NN;
        xc1[(19+o)*NN + n] = outv;
        if (tid < 19) xc1[tid*NN + n] = xcL[tid];
    }
}

// ====== uv2: U2[b][n][r] = sum_c A2[r][c] * xc1[b][c][n] (batch = blockIdx&7) ======
__global__ __launch_bounds__(256, 2) void uv2_kernel(float* ws) {
    __shared__ ushort16_t xt[64*104];       // [point][chan] bf16, 13,312 B
    int tid = threadIdx.x;
    int b = blockIdx.x & 7;
    int pn0 = (blockIdx.x >> 3) << 6;       // 64 points per block (32 groups/batch)
    const float* xc1 = ws + O_XC1 + (size_t)b*83*NN;
    for (int i = tid; i < 96*64; i += 256) {
        int c = i >> 6, j = i & 63;
        xt[j*104 + c] = (c < 83) ? f2bf(xc1[c*NN + pn0 + j]) : (ushort16_t)0;
    }
    __syncthreads();
    int lane = tid & 63, wv = tid >> 6;
    int quad = lane >> 4, l15 = lane & 15;
    const ushort16_t* a2b = (const ushort16_t*)(ws + O_W2B16);
    floatx4 acc[4][4];
    #pragma unroll
    for (int rt = 0; rt < 4; ++rt)
        #pragma unroll
        for (int nt = 0; nt < 4; ++nt) acc[rt][nt] = (floatx4){0.f,0.f,0.f,0.f};
    #pragma unroll
    for (int kt = 0; kt < 3; ++kt) {
        int c0 = kt*32 + quad*8;
        short8 bfr[4], a[4];
        #pragma unroll
        for (int nt = 0; nt < 4; ++nt)
            bfr[nt] = *(const short8*)&xt[(nt*16 + l15)*104 + c0];
        #pragma unroll
        for (int rt = 0; rt < 4; ++rt)
            a[rt] = *(const short8*)&a2b[(wv*64 + rt*16 + l15)*96 + c0];
        #pragma unroll
        for (int rt = 0; rt < 4; ++rt)
            #pragma unroll
            for (int nt = 0; nt < 4; ++nt)
                acc[rt][nt] = __builtin_amdgcn_mfma_f32_16x16x32_bf16(a[rt], bfr[nt], acc[rt][nt], 0, 0, 0);
    }
    float* U2 = ws + O_XC2 + (size_t)b*512*NN;
    #pragma unroll
    for (int rt = 0; rt < 4; ++rt)
        #pragma unroll
        for (int nt = 0; nt < 4; ++nt) {
            int n = pn0 + nt*16 + l15;
            int r = wv*64 + rt*16 + quad*4;
            *(float4*)&U2[(size_t)n*256 + r] =
                make_float4(acc[rt][nt][0], acc[rt][nt][1], acc[rt][nt][2], acc[rt][nt][3]);
        }
}

// ================= edge2: 2 points/block, batch->XCD locked =================
__global__ __launch_bounds__(256, 2) void edge2_kernel(float* ws, const int* idx) {
    __shared__ __align__(16) ushort16_t hrb[48*264];   // 25,344 B (cols 40..47 pad, never read out)
    __shared__ __align__(16) float attL[256*41];       // 41,984 B
    __shared__ float vL[2*256];                        // 2,048 B
    __shared__ float scal[5*256];                      // 5,120 B
    __shared__ float xcL[2*84];
    __shared__ int idxL[40];

    int tid = threadIdx.x;
    int b  = blockIdx.x & 7;                // batch -> XCD lock (U2[b] L2-resident)
    int n0 = (blockIdx.x >> 3) << 1;        // 2 points per block, 1024 groups/batch

    scal[tid]        = ws[O_BN2SC + tid];
    scal[256 + tid]  = ws[O_BN2SH + tid];
    scal[512 + tid]  = ws[O_P2SC + tid];
    scal[768 + tid]  = ws[O_P2SH + tid];
    scal[1024 + tid] = ws[O_P2B + tid];
    if (tid < 40) idxL[tid] = idx[(b*NN + n0 + tid/20)*KK + (tid%20)] & (NN-1);
    if (tid < 166) {
        int p = tid / 83, c = tid - p*83;
        xcL[p*84 + c] = ws[O_XC1 + (size_t)b*83*NN + c*NN + n0 + p];
    }
    __syncthreads();

    // V (exact fp32): vL[p][row] = sum_c b2fT[c][row] * xc1[c][n0+p]  (coalesced weight reads)
    {
        const float* b2fT = ws + O_W2P;
        float a0 = 0.f, a1 = 0.f;
        #pragma unroll 4
        for (int c = 0; c < 83; ++c) {
            float w = b2fT[c*256 + tid];
            a0 += w * xcL[c];
            a1 += w * xcL[84 + c];
        }
        vL[tid] = a0; vL[256 + tid] = a1;
    }
    __syncthreads();

    // P1: hr tile [col][row] bf16 from U2 gather (L2-hit) + vL
    const float* U2 = ws + O_XC2 + (size_t)b*512*NN;
    #pragma unroll 10
    for (int col = 0; col < 40; ++col) {
        int p = col >= 20;
        int j = idxL[col];
        float u = U2[(size_t)j*256 + tid];
        float h2 = (u + vL[p*256 + tid]) * scal[tid] + scal[256 + tid];
        h2 = h2 > 0.f ? h2 : 0.2f*h2;
        float hv = h2*scal[512 + tid] + scal[768 + tid];
        hrb[col*264 + tid] = f2bf(fmaxf(hv, 0.f));
    }
    __syncthreads();

    // P2: att GEMM (p2w [256x256] bf16 x hr [256 x 48(40 used)])
    int lane = tid & 63, wv = tid >> 6;
    int quad = lane >> 4, l15 = lane & 15;
    const ushort16_t* p2wb = (const ushort16_t*)(ws + O_P2W16);
    floatx4 acc2[4][3];
    #pragma unroll
    for (int mt = 0; mt < 4; ++mt)
        #pragma unroll
        for (int nt = 0; nt < 3; ++nt) acc2[mt][nt] = (floatx4){0.f,0.f,0.f,0.f};
    for (int kt = 0; kt < 8; ++kt) {
        int c0 = kt*32 + quad*8;
        short8 a[4], bb3[3];
        #pragma unroll
        for (int mt = 0; mt < 4; ++mt)
            a[mt] = *(const short8*)&p2wb[(wv*64 + mt*16 + l15)*256 + c0];
        #pragma unroll
        for (int nt = 0; nt < 3; ++nt)
            bb3[nt] = *(const short8*)&hrb[(nt*16 + l15)*264 + c0];
        #pragma unroll
        for (int mt = 0; mt < 4; ++mt)
            #pragma unroll
            for (int nt = 0; nt < 3; ++nt)
                acc2[mt][nt] = __builtin_amdgcn_mfma_f32_16x16x32_bf16(a[mt], bb3[nt], acc2[mt][nt], 0, 0, 0);
    }
    #pragma unroll
    for (int mt = 0; mt < 4; ++mt) {
        int k0 = wv*64 + mt*16 + quad*4;
        #pragma unroll
        for (int nt = 0; nt < 3; ++nt) {
            int col = nt*16 + l15;
            if (col < 40) {
                #pragma unroll
                for (int r = 0; r < 4; ++r)
                    attL[(k0 + r)*41 + col] = acc2[mt][nt][r] + scal[1024 + k0 + r];
            }
        }
    }
    __syncthreads();

    // P3: per-row softmax over k + weighted sum of recomputed h2 -> XP2 (point-major, coalesced)
    float* xp2 = ws + O_XC2 + (size_t)b*512*NN + (size_t)256*NN;
    float sc = scal[tid], sh = scal[256 + tid];
    #pragma unroll
    for (int p = 0; p < 2; ++p) {
        float av[KK]; float mx = -3.0e38f;
        #pragma unroll
        for (int k = 0; k < KK; ++k) { av[k] = attL[tid*41 + p*20 + k]; mx = fmaxf(mx, av[k]); }
        float ssum = 0.f;
        #pragma unroll
        for (int k = 0; k < KK; ++k) { av[k] = expf(av[k] - mx); ssum += av[k]; }
        float inv = 1.f / ssum;
        float vpr = vL[p*256 + tid];
        float sacc = 0.f;
        #pragma unroll
        for (int k = 0; k < KK; ++k) {
            int j = idxL[p*20 + k];
            float u = U2[(size_t)j*256 + tid];
            float h2 = (u + vpr)*sc + sh;
            h2 = h2 > 0.f ? h2 : 0.2f*h2;
            sacc += av[k] * inv * h2;
        }
        xp2[(size_t)(n0 + p)*256 + tid] = sacc;
    }
}

// ================= final: out = lrelu(bn3(w3 @ x_c2)) -> fp32 =================
// x_c2 rows 0..255 from x_mlp [c][n]; rows 256..511 from XP2 [n][r] (point-major)
__global__ void final_kernel(const float* ws, float* out) {
    __shared__ __align__(16) float tileF[512*20];
    int tid = threadIdx.x;
    int b = blockIdx.x & 7;
    int n0 = (blockIdx.x >> 3) << 4;
    const float* xc2 = ws + O_XC2 + (size_t)b*512*NN;
    for (int i = tid; i < 256*16; i += 256) {
        int c = i >> 4, nn = i & 15;
        tileF[c*20 + nn] = xc2[c*NN + n0 + nn];
    }
    const float* xp2 = xc2 + (size_t)256*NN;
    #pragma unroll
    for (int it = 0; it < 16; ++it) {
        tileF[(256 + tid)*20 + it] = xp2[(size_t)(n0 + it)*256 + tid];
    }
    __syncthreads();
    const float* w3p = ws + O_W3P;
    int r0 = tid*2, r1 = r0 + 1;
    float acc0[16], acc1[16];
    #pragma unroll
    for (int q = 0; q < 16; ++q) { acc0[q] = 0.f; acc1[q] = 0.f; }
    #pragma unroll 4
    for (int c = 0; c < 512; ++c) {
        float w0 = w3p[r0*512 + c], w1v = w3p[r1*512 + c];
        const float4* tr = (const float4*)&tileF[c*20];
        #pragma unroll
        for (int q = 0; q < 4; ++q) {
            float4 t = tr[q];
            acc0[q*4+0] += w0*t.x;  acc0[q*4+1] += w0*t.y;  acc0[q*4+2] += w0*t.z;  acc0[q*4+3] += w0*t.w;
            acc1[q*4+0] += w1v*t.x; acc1[q*4+1] += w1v*t.y; acc1[q*4+2] += w1v*t.z; acc1[q*4+3] += w1v*t.w;
        }
    }
    float s0 = ws[O_BN3SC + r0], q0 = ws[O_BN3SH + r0];
    float s1 = ws[O_BN3SC + r1], q1 = ws[O_BN3SH + r1];
    float* ob = out + (size_t)b*512*NN;
    #pragma unroll
    for (int nn = 0; nn < 16; ++nn) {
        float v = acc0[nn]*s0 + q0; v = v > 0.f ? v : 0.2f*v;
        ob[r0*NN + n0 + nn] = v;
        float u = acc1[nn]*s1 + q1; u = u > 0.f ? u : 0.2f*u;
        ob[r1*NN + n0 + nn] = u;
    }
}

extern "C" void kernel_launch(void* const* d_in, const int* in_sizes, int n_in,
                              void* d_out, int out_size, void* d_ws, size_t ws_size,
                              hipStream_t stream) {
    float* ws = (float*)d_ws;
    float* out = (float*)d_out;
    ushort16_t* hilo = (ushort16_t*)(ws + O_HILO);
    float* xxq = ws + O_XXQ;

    detect_kernel<<<1, 64, 0, stream>>>(d_in[0], (int*)ws + O_FLAG);
    prep_kernel<<<64, 256, 0, stream>>>(d_in[1], d_in[2], d_in[3], d_in[4], d_in[5], d_in[6],
                                        d_in[7], d_in[8], d_in[9], d_in[10], d_in[11], d_in[12],
                                        d_in[13], d_in[14], d_in[15], d_in[16], d_in[17], d_in[18],
                                        d_in[19], d_in[20], d_in[21], ws);
    // lafe = xconv + knn3 (fused MFMA+select) + attention
    xconv_kernel<<<192, 256, 0, stream>>>(d_in[0], ws);
    hilo_kernel<3, 19, 32><<<256, 256, 0, stream>>>(ws + O_XMAN, hilo);
    xx_kernel<3, 19><<<64, 256, 0, stream>>>(ws + O_XMAN, xxq);
    knn_fused_kernel<3, 19, 32><<<1024, 512, 0, stream>>>(ws + O_XMAN, hilo, xxq, (int*)(ws + O_IDX3));
    lafe_att_kernel<<<64, 256, 0, stream>>>(ws, (const int*)(ws + O_IDX3));
    // knn on x_manet (C=19)
    hilo_kernel<19, 19, 64><<<1024, 256, 0, stream>>>(ws + O_XMAN, hilo);
    xx_kernel<19, 19><<<64, 256, 0, stream>>>(ws + O_XMAN, xxq);
    knn_fused_kernel<19, 19, 64><<<1024, 512, 0, stream>>>(ws + O_XMAN, hilo, xxq, (int*)(ws + O_IDX2));
    edge1_kernel<<<BB*NN, 64, 0, stream>>>(ws, (const int*)(ws + O_IDX2));
    // knn on x_c1 (C=83)
    hilo_kernel<83, 83, 256><<<2048, 256, 0, stream>>>(ws + O_XC1, hilo);
    xx_kernel<83, 83><<<64, 256, 0, stream>>>(ws + O_XC1, xxq);
    knn_fused_kernel<83, 83, 256><<<1024, 512, 0, stream>>>(ws + O_XC1, hilo, xxq, (int*)(ws + O_IDX3));
    // edge2 via A/B decomposition: U2 = A @ xc1 (MFMA, batch-locked), then fused gather kernel
    uv2_kernel<<<256, 256, 0, stream>>>(ws);
    edge2_kernel<<<BB*1024, 256, 0, stream>>>(ws, (const int*)(ws + O_IDX3));
    mlp_kernel<<<BB*NN, 256, 0, stream>>>(ws);
    final_kernel<<<BB*(NN/16), 256, 0, stream>>>(ws, out);
}

// Round 6
// 1262.037 us; speedup vs baseline: 1.4965x; 1.1752x over previous
//
#include <hip/hip_runtime.h>
#include <hip/hip_bf16.h>
#include <math.h>

typedef __hip_bfloat16 bf16;
typedef unsigned short ushort16_t;
typedef unsigned int uint32;
typedef __attribute__((ext_vector_type(8))) short short8;
typedef __attribute__((ext_vector_type(4))) float floatx4;

#define BB 8
#define NN 2048
#define KK 20

// ---- workspace layout (float offsets) ----
#define O_XMAN  0                        // [8][19][2048]  rows 0..2 = x (fp32), rows 3..18 = lafe out
#define O_XC1   311296                   // [8][83][2048]
#define O_XC2   1671168                  // [8][512][2048]:
                                         //   pre-mlp: [b] rows 0..255 region = U2 fp32 [2048][256]
                                         //            [b] rows 256..511 region = XP2 fp32 [2048][256]
                                         //   post-mlp: rows 0..255 = x_mlp [c][n]
                                         //   reused earlier: knn scratch (hilo/xx) + UV1
#define O_IDX2  10059776                 // int [8][2048][20]
#define O_IDX3  10387456                 // int [8][2048][20] (also temp home for lafe knn idx)
#define O_MLPW  10715136                 // [256][20] padded
#define O_MLPSC 10720256
#define O_MLPSH 10720512
#define O_W1P   10720768                 // (spare)
#define O_BN1SC 10724864
#define O_BN1SH 10724928
#define O_P1SC  10724992
#define O_P1SH  10725056
#define O_P1W   10725120                 // (spare)
#define O_P1B   10729216                 // (spare; p1_b is softmax-invariant)
#define O_W2P   10729280                 // region reused: W1S16 + W1A3 (edge1 decomp weights)
#define O_BN2SC 10794816
#define O_BN2SH 10795072
#define O_P2SC  10795328
#define O_P2SH  10795584
#define O_P2W   10795840                 // b2fT fp32 [84][256] (edge2 B = Wce + Wdiff, transposed)
#define O_P2B   10861376
#define O_W3P   10861632                 // [512][512]
#define O_BN3SC 11123776
#define O_BN3SH 11124288
#define O_LA    11124800                 // w1[48] b1[16] w2[48] b2[16] w3[16] b3[1]
#define O_FLAG  11124960                 // int: 1 if inputs are fp32, 0 if bf16
#define O_W2B16 11125760                 // ushort A2b [256][96] bf16 (edge2 A = Wnb - Wdiff)
#define O_P2W16 11162624                 // ushort [256][256] bf16 p2w

// edge1 decomposition weights (inside old W2P spare at O_W2P? NO - that now holds b2fT).
// Use O_W1P/O_P1W/O_P1B spares region: O_W1P..O_BN1SC = 4096 floats, O_P1W..O_W2P = 4160 floats.
#define O_W1S16 O_W1P                    // ushort [128][64] = 4096 ush = 2048 floats (fits 4096)
#define O_W1A3  O_P1W                    // ushort [3][64][192] = 36864 ush = 18432 floats -> needs more!

// O_P1W region is only 10729280-10725120 = 4160 floats; W1A3 needs 18432. Put W1A3 after P2W16:
#undef O_W1A3
#define O_W1A3  11195392                 // ushort [3][64][192] = 18432 floats, ends 11213824

// knn scratch inside XC2 region (consumed before uv2/edge2/mlp write XC2):
#define O_HILO  O_XC2
#define O_XXQ   (O_XC2 + 2097152)
#define O_UV1   (O_XC2 + 2113536)        // fp32 [8][2048][128] = 2,097,152 floats (U1 rows 0..63, V1 64..127)

__device__ __forceinline__ float ldin(const void* p, int i, int f32) {
    return f32 ? ((const float*)p)[i]
               : __bfloat162float(((const bf16*)p)[i]);
}

__device__ __forceinline__ ushort16_t f2bf(float v) {
    union { bf16 h; ushort16_t u; } x; x.h = __float2bfloat16(v); return x.u;
}

__device__ __forceinline__ float bfbits2f(ushort16_t u) {
    union { uint32 i; float f; } c; c.i = ((uint32)u) << 16; return c.f;
}

// ============ detect: are inputs fp32 or bf16? ============
__global__ void detect_kernel(const void* x, int* flag) {
    if (threadIdx.x == 0 && blockIdx.x == 0) {
        const unsigned short* u = (const unsigned short*)x;
        int bad = 0;
        for (int i = 0; i < 64; ++i) {
            int e = (u[i] >> 7) & 0xFF;
            if (e >= 0x86) bad++;
        }
        *flag = (bad > 0) ? 1 : 0;
    }
}

// ================= prep =================
__global__ void prep_kernel(
    const void* la_w1, const void* la_b1, const void* la_w2, const void* la_b2,
    const void* la_w3, const void* la_b3,
    const void* mlp_w, const void* mlp_b, const void* mlp_bn,
    const void* w1, const void* bn1, const void* w2, const void* bn2,
    const void* w3, const void* bn3,
    const void* p1_bn, const void* p1_w, const void* p1_b,
    const void* p2_bn, const void* p2_w, const void* p2_b,
    float* ws)
{
    const int f32 = ((const int*)ws)[O_FLAG];
    int gid = blockIdx.x * blockDim.x + threadIdx.x;
    int gsz = gridDim.x * blockDim.x;

    for (int i = gid; i < 256*20; i += gsz) {
        int o = i / 20, c = i - o*20;
        ws[O_MLPW + i] = (c < 19) ? ldin(mlp_w, o*19 + c, f32) : 0.f;
    }
    for (int c = gid; c < 256; c += gsz) {
        float g = ldin(mlp_bn, c, f32), be = ldin(mlp_bn, 256+c, f32);
        float m = ldin(mlp_bn, 512+c, f32), vv = ldin(mlp_bn, 768+c, f32);
        float s = g / sqrtf(vv + 1e-5f);
        ws[O_MLPSC + c] = s;
        ws[O_MLPSH + c] = be + (ldin(mlp_b, c, f32) - m) * s;
    }
    for (int c = gid; c < 64; c += gsz) {
        float g = ldin(bn1, c, f32), be = ldin(bn1, 64+c, f32);
        float m = ldin(bn1, 128+c, f32), vv = ldin(bn1, 192+c, f32);
        float s = g / sqrtf(vv + 1e-5f);
        ws[O_BN1SC + c] = s; ws[O_BN1SH + c] = be - m*s;
        float g2 = ldin(p1_bn, c, f32), be2 = ldin(p1_bn, 64+c, f32);
        float m2 = ldin(p1_bn, 128+c, f32), vv2 = ldin(p1_bn, 192+c, f32);
        float s2 = g2 / sqrtf(vv2 + 1e-5f);
        ws[O_P1SC + c] = s2; ws[O_P1SH + c] = be2 - m2*s2;
    }
    for (int c = gid; c < 256; c += gsz) {
        float g = ldin(bn2, c, f32), be = ldin(bn2, 256+c, f32);
        float m = ldin(bn2, 512+c, f32), vv = ldin(bn2, 768+c, f32);
        float s = g / sqrtf(vv + 1e-5f);
        ws[O_BN2SC + c] = s; ws[O_BN2SH + c] = be - m*s;
        float g2 = ldin(p2_bn, c, f32), be2 = ldin(p2_bn, 256+c, f32);
        float m2 = ldin(p2_bn, 512+c, f32), vv2 = ldin(p2_bn, 768+c, f32);
        float s2 = g2 / sqrtf(vv2 + 1e-5f);
        ws[O_P2SC + c] = s2; ws[O_P2SH + c] = be2 - m2*s2;
        ws[O_P2B + c] = ldin(p2_b, c, f32);
    }
    for (int i = gid; i < 512*512; i += gsz) ws[O_W3P + i] = ldin(w3, i, f32);
    for (int c = gid; c < 512; c += gsz) {
        float g = ldin(bn3, c, f32), be = ldin(bn3, 512+c, f32);
        float m = ldin(bn3, 1024+c, f32), vv = ldin(bn3, 1536+c, f32);
        float s = g / sqrtf(vv + 1e-5f);
        ws[O_BN3SC + c] = s; ws[O_BN3SH + c] = be - m*s;
    }
    for (int i = gid; i < 48; i += gsz) ws[O_LA + i]       = ldin(la_w1, i, f32);
    for (int i = gid; i < 16; i += gsz) ws[O_LA + 48 + i]  = ldin(la_b1, i, f32);
    for (int i = gid; i < 48; i += gsz) ws[O_LA + 64 + i]  = ldin(la_w2, i, f32);
    for (int i = gid; i < 16; i += gsz) ws[O_LA + 112 + i] = ldin(la_b2, i, f32);
    for (int i = gid; i < 16; i += gsz) ws[O_LA + 128 + i] = ldin(la_w3, i, f32);
    if (gid == 0) ws[O_LA + 144] = ldin(la_b3, 0, f32);

    // ---- edge1 decomposition: W1split (3-split interleaved, K side) ----
    // rows 0..63: A1 = Wnb - Wdiff (neighbor-applied); rows 64..127: B1 = Wce + Wdiff (center).
    // w1s[row][3c+s] = split_s(W[row][c]); kp 57..63 zero.
    ushort16_t* w1s = (ushort16_t*)(ws + O_W1S16);
    for (int i = gid; i < 128*64; i += gsz) {
        int row = i >> 6, kp = i & 63;
        if (kp < 57) {
            int c = kp / 3, s = kp - c*3;
            int o = row & 63;
            float wnb = ldin(w1, o*57 + c, f32);
            float wce = ldin(w1, o*57 + 19 + c, f32);
            float wdf = ldin(w1, o*57 + 38 + c, f32);
            float v = (row < 64) ? (wnb - wdf) : (wce + wdf);
            ushort16_t h = f2bf(v); float r1 = v - bfbits2f(h);
            ushort16_t m = f2bf(r1); ushort16_t l = f2bf(r1 - bfbits2f(m));
            w1s[i] = (s==0) ? h : ((s==1) ? m : l);
        } else w1s[i] = 0;
    }
    // ---- edge1 att weights: w1a3[pass][o][kp] = split_pass(p1w[o][kp/3]), kp<192 ----
    ushort16_t* w1a3 = (ushort16_t*)(ws + O_W1A3);
    for (int i = gid; i < 3*64*192; i += gsz) {
        int t = i / (64*192), rem = i - t*64*192;
        int o = rem / 192, kp = rem - o*192;
        int c = kp / 3;
        float v = ldin(p1_w, o*64 + c, f32);
        ushort16_t h = f2bf(v); float r1 = v - bfbits2f(h);
        ushort16_t m = f2bf(r1); ushort16_t l = f2bf(r1 - bfbits2f(m));
        w1a3[i] = (t==0) ? h : ((t==1) ? m : l);
    }

    // edge2 decomposition: A = Wnb - Wdiff (bf16, [256][96] padded),
    //                      B^T = (Wce + Wdiff)^T (fp32, [84][256] column-major for coalesced V)
    ushort16_t* a2b = (ushort16_t*)(ws + O_W2B16);
    for (int i = gid; i < 256*96; i += gsz) {
        int row = i / 96, c = i - row*96;
        float v = (c < 83) ? (ldin(w2, row*249 + c, f32) - ldin(w2, row*249 + 166 + c, f32)) : 0.f;
        a2b[i] = f2bf(v);
    }
    float* b2fT = ws + O_P2W;
    for (int i = gid; i < 84*256; i += gsz) {
        int c = i >> 8, row = i & 255;
        b2fT[i] = (c < 83) ? (ldin(w2, row*249 + 83 + c, f32) + ldin(w2, row*249 + 166 + c, f32)) : 0.f;
    }
    ushort16_t* pwb = (ushort16_t*)(ws + O_P2W16);
    for (int i = gid; i < 256*256; i += gsz) pwb[i] = f2bf(ldin(p2_w, i, f32));
}

// ================= xconv: x -> fp32 into XMAN rows 0..2 =================
__global__ __launch_bounds__(256) void xconv_kernel(const void* x, float* ws) {
    const int f32 = ((const int*)ws)[O_FLAG];
    int gid = blockIdx.x*256 + threadIdx.x;     // 0 .. 8*3*2048-1
    int b = gid / (3*NN), r = gid - b*3*NN;
    ws[O_XMAN + b*19*NN + r] = ldin(x, gid, f32);
}

// ================= xc1copy: xman rows 0..18 -> xc1 rows 0..18 (coalesced) =====
__global__ __launch_bounds__(256) void xc1copy_kernel(float* ws) {
    int gid = blockIdx.x*256 + threadIdx.x;     // 8*19*2048 = 311296
    int b = gid / (19*NN), r = gid - b*19*NN;
    ws[O_XC1 + (size_t)b*83*NN + r] = ws[O_XMAN + gid];
}

// ====== 3-way bf16 split precompute (batch locked to XCD via blockIdx&7) ======
template<int C, int CS, int KP>
__global__ void hilo_kernel(const float* feat, ushort16_t* out) {
    int b  = blockIdx.x & 7;
    int lb = blockIdx.x >> 3;
    int nb = gridDim.x >> 3;
    const float* fb = feat + (size_t)b*CS*NN;
    ushort16_t* ob = out + (size_t)b*NN*KP;
    for (int i = lb*blockDim.x + threadIdx.x; i < C*NN; i += nb*blockDim.x) {
        int c = i >> 11, n = i & (NN-1);
        float v = fb[(size_t)c*NN + n];
        ushort16_t h = f2bf(v);
        float r1 = v - bfbits2f(h);
        ushort16_t m = f2bf(r1);
        ushort16_t l = f2bf(r1 - bfbits2f(m));
        size_t base = (size_t)n*KP + 3*c;
        ob[base] = h; ob[base+1] = m; ob[base+2] = l;
    }
    constexpr int PAD = KP - 3*C;
    for (int i = lb*blockDim.x + threadIdx.x; i < NN*PAD; i += nb*blockDim.x) {
        int n = i / PAD, p = i - n*PAD;
        ob[(size_t)n*KP + 3*C + p] = 0;
    }
}

// ====== exact fp32 squared norms ======
template<int C, int CS>
__global__ __launch_bounds__(256) void xx_kernel(const float* feat, float* xxg) {
    int gid = blockIdx.x*256 + threadIdx.x;      // BB*NN total
    int b = gid >> 11, n = gid & (NN-1);
    const float* fb = feat + (size_t)b*CS*NN;
    float s = 0.f;
    #pragma unroll
    for (int c = 0; c < C; ++c) { float v = fb[c*NN + n]; s += v*v; }
    xxg[gid] = s;
}

// ====== fused knn: MFMA distance tile + lazy top-3 u64-butterfly extraction ======
template<int C, int CS, int KP>
__global__ __launch_bounds__(512, 2) void knn_fused_kernel(
    const float* feat, const ushort16_t* hilo, const float* xxg, int* idxout)
{
    constexpr int KT = KP / 32;
    constexpr int ST = 2057;                 // odd stride -> conflict-free LDS
    __shared__ float Dt[16 * ST];            // 131,648 B
    int tid = threadIdx.x;
    int b  = blockIdx.x & 7;                 // batch -> XCD lock
    int n0 = (blockIdx.x >> 3) << 4;         // 16 points per block (128 groups/batch)
    int lane = tid & 63, wv = tid >> 6;      // 8 waves
    int quad = lane >> 4, l15 = lane & 15;
    const float* fb = feat + (size_t)b * CS * NN;

    short8 Bh[KT], Bm[KT], Bl[KT];
    #pragma unroll
    for (int kt = 0; kt < KT; ++kt) {
        #pragma unroll
        for (int e = 0; e < 8; ++e) {
            int kp = kt*32 + quad*8 + e;
            int c = kp / 3;
            float v = (c < C) ? fb[(size_t)c*NN + n0 + l15] : 0.f;
            ushort16_t h = f2bf(v);
            float r1 = v - bfbits2f(h);
            ushort16_t m = f2bf(r1);
            ushort16_t l = f2bf(r1 - bfbits2f(m));
            Bh[kt][e] = (short)h; Bm[kt][e] = (short)m; Bl[kt][e] = (short)l;
        }
    }

    const ushort16_t* hb = hilo + (size_t)b * NN * KP;
    const float* xxb = xxg + b * NN;

    #pragma unroll
    for (int i = 0; i < 4; ++i) {
        int base = (wv*4 + i) * 64;
        floatx4 acc[4];
        #pragma unroll
        for (int st = 0; st < 4; ++st) {
            acc[st] = (floatx4){0.f,0.f,0.f,0.f};
            #pragma unroll
            for (int kt = 0; kt < KT; ++kt) {
                short8 a = *(const short8*)&hb[(size_t)(base + st*16 + l15)*KP + kt*32 + quad*8];
                acc[st] = __builtin_amdgcn_mfma_f32_16x16x32_bf16(a, Bh[kt], acc[st], 0, 0, 0);
                acc[st] = __builtin_amdgcn_mfma_f32_16x16x32_bf16(a, Bm[kt], acc[st], 0, 0, 0);
                acc[st] = __builtin_amdgcn_mfma_f32_16x16x32_bf16(a, Bl[kt], acc[st], 0, 0, 0);
            }
        }
        #pragma unroll
        for (int st = 0; st < 4; ++st) {
            #pragma unroll
            for (int r = 0; r < 4; ++r) {
                int cand = base + st*16 + quad*4 + r;
                Dt[l15*ST + cand] = 2.f*acc[st][r] - xxb[cand];
            }
        }
    }
    __syncthreads();

    int r0 = wv*2, r1 = wv*2 + 1;
    unsigned int basei = 2047u - (unsigned int)lane;
    unsigned int a0[32], a1[32];
    unsigned int dead0 = 0, dead1 = 0;
    unsigned long long p0 = 0, p1 = 0, p2 = 0;
    unsigned long long q0 = 0, q1 = 0, q2 = 0;
    #pragma unroll
    for (int j = 0; j < 32; ++j) {
        unsigned int u0 = __float_as_uint(Dt[r0*ST + j*64 + lane]);
        unsigned int u1 = __float_as_uint(Dt[r1*ST + j*64 + lane]);
        unsigned int o0 = u0 ^ (unsigned int)(((int)u0 >> 31) | 0x80000000);
        unsigned int o1 = u1 ^ (unsigned int)(((int)u1 >> 31) | 0x80000000);
        a0[j] = o0; a1[j] = o1;
        unsigned long long k0 = ((unsigned long long)o0 << 32) | (basei - j*64);
        unsigned long long k1 = ((unsigned long long)o1 << 32) | (basei - j*64);
        bool g00 = k0 > p0, g01 = k0 > p1, g02 = k0 > p2;
        p2 = g01 ? p1 : (g02 ? k0 : p2);
        p1 = g00 ? p0 : (g01 ? k0 : p1);
        p0 = g00 ? k0 : p0;
        bool g10 = k1 > q0, g11 = k1 > q1, g12 = k1 > q2;
        q2 = g11 ? q1 : (g12 ? k1 : q2);
        q1 = g10 ? q0 : (g11 ? k1 : q1);
        q0 = g10 ? k1 : q0;
    }
    int myg0 = 0, myg1 = 0;
    #pragma unroll 1
    for (int it = 0; it < KK; ++it) {
        unsigned long long b0 = p0, b1 = q0;
        #pragma unroll
        for (int sh = 1; sh < 64; sh <<= 1) {
            unsigned long long o0 = __shfl_xor(b0, sh);
            unsigned long long o1 = __shfl_xor(b1, sh);
            b0 = (o0 > b0) ? o0 : b0;
            b1 = (o1 > b1) ? o1 : b1;
        }
        if (lane == it) {
            myg0 = (int)(2047u - (unsigned int)b0);
            myg1 = (int)(2047u - (unsigned int)b1);
        }
        if (p0 == b0) {
            dead0 |= 1u << ((int)(basei - (unsigned int)b0) >> 6);
            p0 = p1; p1 = p2; p2 = 0;
        }
        if (q0 == b1) {
            dead1 |= 1u << ((int)(basei - (unsigned int)b1) >> 6);
            q0 = q1; q1 = q2; q2 = 0;
        }
        if (__any((p0 == 0ull) | (q0 == 0ull))) {
            if (p0 == 0ull) {
                unsigned long long t0 = 0, t1 = 0, t2 = 0;
                #pragma unroll
                for (int j = 0; j < 32; ++j) {
                    unsigned long long k = ((dead0 >> j) & 1u) ? 0ull
                        : (((unsigned long long)a0[j] << 32) | (basei - j*64));
                    bool g0 = k > t0, g1 = k > t1, g2 = k > t2;
                    t2 = g1 ? t1 : (g2 ? k : t2);
                    t1 = g0 ? t0 : (g1 ? k : t1);
                    t0 = g0 ? k : t0;
                }
                p0 = t0; p1 = t1; p2 = t2;
            }
            if (q0 == 0ull) {
                unsigned long long t0 = 0, t1 = 0, t2 = 0;
                #pragma unroll
                for (int j = 0; j < 32; ++j) {
                    unsigned long long k = ((dead1 >> j) & 1u) ? 0ull
                        : (((unsigned long long)a1[j] << 32) | (basei - j*64));
                    bool g0 = k > t0, g1 = k > t1, g2 = k > t2;
                    t2 = g1 ? t1 : (g2 ? k : t2);
                    t1 = g0 ? t0 : (g1 ? k : t1);
                    t0 = g0 ? k : t0;
                }
                q0 = t0; q1 = t1; q2 = t2;
            }
        }
    }
    if (lane < KK) {
        idxout[((size_t)(b*NN + n0 + r0))*KK + lane] = myg0;
        idxout[((size_t)(b*NN + n0 + r1))*KK + lane] = myg1;
    }
}

// ================= lafe attention (post-knn) =================
__global__ __launch_bounds__(256, 1) void lafe_att_kernel(float* ws, const int* idx) {
    __shared__ float xs0[NN], xs1[NN], xs2[NN];
    int tid = threadIdx.x;
    int b = blockIdx.x >> 3;
    int n = ((blockIdx.x & 7) << 8) + tid;
    float* xm = ws + O_XMAN + b*19*NN;
    for (int i = tid; i < NN; i += 256) {
        xs0[i] = xm[i]; xs1[i] = xm[NN + i]; xs2[i] = xm[2*NN + i];
    }
    __syncthreads();
    float a0 = xs0[n], a1 = xs1[n], a2 = xs2[n];
    int ti[KK];
    #pragma unroll
    for (int k = 0; k < KK; ++k) ti[k] = idx[(b*NN + n)*KK + k] & (NN-1);
    const float* wl = ws + O_LA;
    float sa = wl[144];
    #pragma unroll
    for (int o = 0; o < 16; ++o) {
        float nf = wl[o*3+0]*a0 + wl[o*3+1]*a1 + wl[o*3+2]*a2 + wl[48+o];
        sa += wl[128+o]*nf;
    }
    float lg[KK]; float mx = -3.0e38f;
    #pragma unroll
    for (int k = 0; k < KK; ++k) {
        int m = ti[k];
        float d0 = a0 - xs0[m], d1 = a1 - xs1[m], d2 = a2 - xs2[m];
        float na = wl[144];
        #pragma unroll
        for (int o = 0; o < 16; ++o) {
            float ef = wl[64+o*3+0]*d0 + wl[64+o*3+1]*d1 + wl[64+o*3+2]*d2 + wl[112+o];
            na += wl[128+o]*ef;
        }
        float t = sa + na;
        t = t > 0.f ? t : 0.01f*t;
        lg[k] = t; mx = fmaxf(mx, t);
    }
    float ssum = 0.f;
    #pragma unroll
    for (int k = 0; k < KK; ++k) { lg[k] = expf(lg[k] - mx); ssum += lg[k]; }
    float vals[16];
    #pragma unroll
    for (int o = 0; o < 16; ++o) vals[o] = 0.f;
    #pragma unroll
    for (int k = 0; k < KK; ++k) {
        float coef = lg[k] / ssum;
        int m = ti[k];
        float d0 = a0 - xs0[m], d1 = a1 - xs1[m], d2 = a2 - xs2[m];
        #pragma unroll
        for (int o = 0; o < 16; ++o) {
            float ef = wl[64+o*3+0]*d0 + wl[64+o*3+1]*d1 + wl[64+o*3+2]*d2 + wl[112+o];
            vals[o] += coef * ef;
        }
    }
    #pragma unroll
    for (int o = 0; o < 16; ++o) {
        float v = vals[o];
        xm[(3+o)*NN + n] = v > 0.f ? v : expm1f(v);
    }
}

// ================= mlp (batch = blockIdx&7) =================
__global__ void mlp_kernel(float* ws) {
    __shared__ __align__(16) float xv[20];
    int tid = threadIdx.x;
    int b = blockIdx.x & 7, n = blockIdx.x >> 3;
    if (tid < 20) xv[tid] = (tid < 19) ? ws[O_XMAN + b*19*NN + tid*NN + n] : 0.f;
    __syncthreads();
    const float* mw = ws + O_MLPW;
    float acc = 0.f;
    #pragma unroll
    for (int c4 = 0; c4 < 5; ++c4) {
        float4 w = *(const float4*)&mw[tid*20 + c4*4];
        float4 g = *(const float4*)&xv[c4*4];
        acc += w.x*g.x + w.y*g.y + w.z*g.z + w.w*g.w;
    }
    float v = acc * ws[O_MLPSC + tid] + ws[O_MLPSH + tid];
    ws[O_XC2 + b*512*NN + tid*NN + n] = fmaxf(v, 0.f);
}

// ====== uv1: [U1;V1][n][128] = [A1;B1] @ xman via exact 3-split MFMA ======
__global__ __launch_bounds__(256, 2) void uv1_kernel(float* ws) {
    __shared__ float xt[19*64];
    int tid = threadIdx.x;
    int b = blockIdx.x & 7;
    int pn0 = (blockIdx.x >> 3) << 6;        // 64 points per block (32 groups/batch)
    const float* fb = ws + O_XMAN + (size_t)b*19*NN;
    for (int i = tid; i < 19*64; i += 256) {
        int c = i >> 6, j = i & 63;
        xt[i] = fb[(size_t)c*NN + pn0 + j];
    }
    __syncthreads();
    int lane = tid & 63, wv = tid >> 6;
    int quad = lane >> 4, l15 = lane & 15;

    short8 X[3][4][2];
    #pragma unroll
    for (int nt = 0; nt < 4; ++nt) {
        int pt = nt*16 + l15;
        #pragma unroll
        for (int kt = 0; kt < 2; ++kt) {
            #pragma unroll
            for (int e = 0; e < 8; ++e) {
                int kp = kt*32 + quad*8 + e;
                int c = kp / 3;
                float v = (c < 19) ? xt[c*64 + pt] : 0.f;
                ushort16_t h = f2bf(v); float r1 = v - bfbits2f(h);
                ushort16_t m = f2bf(r1); ushort16_t l = f2bf(r1 - bfbits2f(m));
                X[0][nt][kt][e] = (short)h;
                X[1][nt][kt][e] = (short)m;
                X[2][nt][kt][e] = (short)l;
            }
        }
    }
    const ushort16_t* w1s = (const ushort16_t*)(ws + O_W1S16);
    floatx4 acc[2][4];
    #pragma unroll
    for (int rt = 0; rt < 2; ++rt)
        #pragma unroll
        for (int nt = 0; nt < 4; ++nt) acc[rt][nt] = (floatx4){0.f,0.f,0.f,0.f};
    #pragma unroll
    for (int pass = 0; pass < 3; ++pass) {
        #pragma unroll
        for (int kt = 0; kt < 2; ++kt) {
            int c0 = kt*32 + quad*8;
            short8 a[2];
            a[0] = *(const short8*)&w1s[(wv*32 + l15)*64 + c0];
            a[1] = *(const short8*)&w1s[(wv*32 + 16 + l15)*64 + c0];
            #pragma unroll
            for (int rt = 0; rt < 2; ++rt)
                #pragma unroll
                for (int nt = 0; nt < 4; ++nt)
                    acc[rt][nt] = __builtin_amdgcn_mfma_f32_16x16x32_bf16(a[rt], X[pass][nt][kt], acc[rt][nt], 0, 0, 0);
        }
    }
    float* uv1 = ws + O_UV1 + (size_t)b*NN*128;
    #pragma unroll
    for (int rt = 0; rt < 2; ++rt)
        #pragma unroll
        for (int nt = 0; nt < 4; ++nt) {
            int n = pn0 + nt*16 + l15;
            int r = wv*32 + rt*16 + quad*4;
            *(float4*)&uv1[(size_t)n*128 + r] =
                make_float4(acc[rt][nt][0], acc[rt][nt][1], acc[rt][nt][2], acc[rt][nt][3]);
        }
}

// ================= edge1 v2: U1/V1 gather + exact 3-split att GEMM =================
// 4 points/block, batch->XCD locked. att logits exact (3-split both sides, p1_b dropped:
// per-channel constant is softmax-invariant).
__global__ __launch_bounds__(256, 2) void edge1_kernel(float* ws, const int* idx) {
    constexpr int SW = 200;   // hrS ushort stride (192 used)
    constexpr int ST = 65;    // attL float stride
    __shared__ __align__(16) ushort16_t hrS[80*SW];   // 32,000 B (3-split hr, K-interleaved)
    __shared__ __align__(16) float attL[80*ST];       // 20,800 B (att[hr-col][o])
    __shared__ float vL[4*64];
    __shared__ float scalL[256];
    __shared__ float outL[64*5];
    __shared__ int idxL[80];

    int tid = threadIdx.x;
    int b  = blockIdx.x & 7;
    int n0 = (blockIdx.x >> 3) << 2;         // 4 points (512 groups/batch)
    const float* uv1 = ws + O_UV1 + (size_t)b*NN*128;

    {
        int grp = tid >> 6, r6 = tid & 63;
        int off = grp==0 ? O_BN1SC : grp==1 ? O_BN1SH : grp==2 ? O_P1SC : O_P1SH;
        scalL[tid] = ws[off + r6];
        vL[tid] = uv1[(size_t)(n0 + grp)*128 + 64 + r6];
    }
    if (tid < 80) idxL[tid] = idx[(b*NN + n0 + tid/20)*KK + (tid%20)] & (NN-1);
    __syncthreads();

    // P1: build 3-split hr tile: hrS[col][3c+s] = split_s(relu(ps*h1+ph))
    {
        int rw = tid & 63, cg = tid >> 6;
        float s1 = scalL[rw], sh1 = scalL[64+rw], ps = scalL[128+rw], ph = scalL[192+rw];
        #pragma unroll 5
        for (int it = 0; it < 20; ++it) {
            int col = it*4 + cg;
            int p = col / 20;
            int j = idxL[col];
            float u = uv1[(size_t)j*128 + rw];
            float h1 = (u + vL[p*64+rw])*s1 + sh1;
            h1 = h1 > 0.f ? h1 : 0.2f*h1;
            float hv = h1*ps + ph;
            hv = hv > 0.f ? hv : 0.f;
            ushort16_t h = f2bf(hv); float r1 = hv - bfbits2f(h);
            ushort16_t m = f2bf(r1); ushort16_t l = f2bf(r1 - bfbits2f(m));
            hrS[col*SW + 3*rw + 0] = h;
            hrS[col*SW + 3*rw + 1] = m;
            hrS[col*SW + 3*rw + 2] = l;
        }
    }
    __syncthreads();

    // P2: att GEMM  M=hr-cols(80), N=o(64, wave-split), K=192, 3 weight passes
    int lane = tid & 63, wv = tid >> 6;
    int quad = lane >> 4, l15 = lane & 15;
    const ushort16_t* w1a3 = (const ushort16_t*)(ws + O_W1A3);
    floatx4 acc[5];
    #pragma unroll
    for (int mt = 0; mt < 5; ++mt) acc[mt] = (floatx4){0.f,0.f,0.f,0.f};
    #pragma unroll
    for (int pass = 0; pass < 3; ++pass) {
        #pragma unroll
        for (int kt = 0; kt < 6; ++kt) {
            int c0 = kt*32 + quad*8;
            short8 bfrag = *(const short8*)&w1a3[((size_t)pass*64 + wv*16 + l15)*192 + c0];
            #pragma unroll
            for (int mt = 0; mt < 5; ++mt) {
                short8 afrag = *(const short8*)&hrS[(mt*16 + l15)*SW + c0];
                acc[mt] = __builtin_amdgcn_mfma_f32_16x16x32_bf16(afrag, bfrag, acc[mt], 0, 0, 0);
            }
        }
    }
    #pragma unroll
    for (int mt = 0; mt < 5; ++mt)
        #pragma unroll
        for (int r = 0; r < 4; ++r)
            attL[(mt*16 + quad*4 + r)*ST + wv*16 + l15] = acc[mt][r];
    __syncthreads();

    // P3: softmax over k per (o,p) + weighted sum of recomputed h1
    {
        int o = tid & 63, p = tid >> 6;
        float av[KK]; float mx = -3.0e38f;
        #pragma unroll
        for (int k = 0; k < KK; ++k) { av[k] = attL[(p*20 + k)*ST + o]; mx = fmaxf(mx, av[k]); }
        float ssum = 0.f;
        #pragma unroll
        for (int k = 0; k < KK; ++k) { av[k] = expf(av[k] - mx); ssum += av[k]; }
        float inv = 1.f / ssum;
        float s1o = scalL[o], sh1o = scalL[64+o], vpo = vL[p*64+o];
        float sacc = 0.f;
        #pragma unroll
        for (int k = 0; k < KK; ++k) {
            int j = idxL[p*20 + k];
            float u = uv1[(size_t)j*128 + o];
            float h1 = (u + vpo)*s1o + sh1o;
            h1 = h1 > 0.f ? h1 : 0.2f*h1;
            sacc += av[k]*inv*h1;
        }
        outL[o*5 + p] = sacc;
    }
    __syncthreads();
    {
        int o = tid >> 2, p = tid & 3;
        ws[O_XC1 + (size_t)b*83*NN + (size_t)(19+o)*NN + n0 + p] = outL[o*5 + p];
    }
}

// ====== uv2: U2[b][n][r] = sum_c A2[r][c] * xc1[b][c][n] (batch = blockIdx&7) ======
__global__ __launch_bounds__(256, 2) void uv2_kernel(float* ws) {
    __shared__ ushort16_t xt[64*104];       // [point][chan] bf16, 13,312 B
    int tid = threadIdx.x;
    int b = blockIdx.x & 7;
    int pn0 = (blockIdx.x >> 3) << 6;       // 64 points per block (32 groups/batch)
    const float* xc1 = ws + O_XC1 + (size_t)b*83*NN;
    for (int i = tid; i < 96*64; i += 256) {
        int c = i >> 6, j = i & 63;
        xt[j*104 + c] = (c < 83) ? f2bf(xc1[c*NN + pn0 + j]) : (ushort16_t)0;
    }
    __syncthreads();
    int lane = tid & 63, wv = tid >> 6;
    int quad = lane >> 4, l15 = lane & 15;
    const ushort16_t* a2b = (const ushort16_t*)(ws + O_W2B16);
    floatx4 acc[4][4];
    #pragma unroll
    for (int rt = 0; rt < 4; ++rt)
        #pragma unroll
        for (int nt = 0; nt < 4; ++nt) acc[rt][nt] = (floatx4){0.f,0.f,0.f,0.f};
    #pragma unroll
    for (int kt = 0; kt < 3; ++kt) {
        int c0 = kt*32 + quad*8;
        short8 bfr[4], a[4];
        #pragma unroll
        for (int nt = 0; nt < 4; ++nt)
            bfr[nt] = *(const short8*)&xt[(nt*16 + l15)*104 + c0];
        #pragma unroll
        for (int rt = 0; rt < 4; ++rt)
            a[rt] = *(const short8*)&a2b[(wv*64 + rt*16 + l15)*96 + c0];
        #pragma unroll
        for (int rt = 0; rt < 4; ++rt)
            #pragma unroll
            for (int nt = 0; nt < 4; ++nt)
                acc[rt][nt] = __builtin_amdgcn_mfma_f32_16x16x32_bf16(a[rt], bfr[nt], acc[rt][nt], 0, 0, 0);
    }
    float* U2 = ws + O_XC2 + (size_t)b*512*NN;
    #pragma unroll
    for (int rt = 0; rt < 4; ++rt)
        #pragma unroll
        for (int nt = 0; nt < 4; ++nt) {
            int n = pn0 + nt*16 + l15;
            int r = wv*64 + rt*16 + quad*4;
            *(float4*)&U2[(size_t)n*256 + r] =
                make_float4(acc[rt][nt][0], acc[rt][nt][1], acc[rt][nt][2], acc[rt][nt][3]);
        }
}

// ================= edge2: 2 points/block, batch->XCD locked =================
__global__ __launch_bounds__(256, 2) void edge2_kernel(float* ws, const int* idx) {
    __shared__ __align__(16) ushort16_t hrb[48*264];   // 25,344 B
    __shared__ __align__(16) float attL[256*41];       // 41,984 B
    __shared__ float vL[2*256];
    __shared__ float scal[5*256];
    __shared__ float xcL[2*84];
    __shared__ int idxL[40];

    int tid = threadIdx.x;
    int b  = blockIdx.x & 7;
    int n0 = (blockIdx.x >> 3) << 1;

    scal[tid]        = ws[O_BN2SC + tid];
    scal[256 + tid]  = ws[O_BN2SH + tid];
    scal[512 + tid]  = ws[O_P2SC + tid];
    scal[768 + tid]  = ws[O_P2SH + tid];
    scal[1024 + tid] = ws[O_P2B + tid];
    if (tid < 40) idxL[tid] = idx[(b*NN + n0 + tid/20)*KK + (tid%20)] & (NN-1);
    if (tid < 166) {
        int p = tid / 83, c = tid - p*83;
        xcL[p*84 + c] = ws[O_XC1 + (size_t)b*83*NN + c*NN + n0 + p];
    }
    __syncthreads();

    {
        const float* b2fT = ws + O_P2W;
        float a0 = 0.f, a1 = 0.f;
        #pragma unroll 4
        for (int c = 0; c < 83; ++c) {
            float w = b2fT[c*256 + tid];
            a0 += w * xcL[c];
            a1 += w * xcL[84 + c];
        }
        vL[tid] = a0; vL[256 + tid] = a1;
    }
    __syncthreads();

    const float* U2 = ws + O_XC2 + (size_t)b*512*NN;
    #pragma unroll 10
    for (int col = 0; col < 40; ++col) {
        int p = col >= 20;
        int j = idxL[col];
        float u = U2[(size_t)j*256 + tid];
        float h2 = (u + vL[p*256 + tid]) * scal[tid] + scal[256 + tid];
        h2 = h2 > 0.f ? h2 : 0.2f*h2;
        float hv = h2*scal[512 + tid] + scal[768 + tid];
        hrb[col*264 + tid] = f2bf(fmaxf(hv, 0.f));
    }
    __syncthreads();

    int lane = tid & 63, wv = tid >> 6;
    int quad = lane >> 4, l15 = lane & 15;
    const ushort16_t* p2wb = (const ushort16_t*)(ws + O_P2W16);
    floatx4 acc2[4][3];
    #pragma unroll
    for (int mt = 0; mt < 4; ++mt)
        #pragma unroll
        for (int nt = 0; nt < 3; ++nt) acc2[mt][nt] = (floatx4){0.f,0.f,0.f,0.f};
    for (int kt = 0; kt < 8; ++kt) {
        int c0 = kt*32 + quad*8;
        short8 a[4], bb3[3];
        #pragma unroll
        for (int mt = 0; mt < 4; ++mt)
            a[mt] = *(const short8*)&p2wb[(wv*64 + mt*16 + l15)*256 + c0];
        #pragma unroll
        for (int nt = 0; nt < 3; ++nt)
            bb3[nt] = *(const short8*)&hrb[(nt*16 + l15)*264 + c0];
        #pragma unroll
        for (int mt = 0; mt < 4; ++mt)
            #pragma unroll
            for (int nt = 0; nt < 3; ++nt)
                acc2[mt][nt] = __builtin_amdgcn_mfma_f32_16x16x32_bf16(a[mt], bb3[nt], acc2[mt][nt], 0, 0, 0);
    }
    #pragma unroll
    for (int mt = 0; mt < 4; ++mt) {
        int k0 = wv*64 + mt*16 + quad*4;
        #pragma unroll
        for (int nt = 0; nt < 3; ++nt) {
            int col = nt*16 + l15;
            if (col < 40) {
                #pragma unroll
                for (int r = 0; r < 4; ++r)
                    attL[(k0 + r)*41 + col] = acc2[mt][nt][r] + scal[1024 + k0 + r];
            }
        }
    }
    __syncthreads();

    float* xp2 = ws + O_XC2 + (size_t)b*512*NN + (size_t)256*NN;
    float sc = scal[tid], sh = scal[256 + tid];
    #pragma unroll
    for (int p = 0; p < 2; ++p) {
        float av[KK]; float mx = -3.0e38f;
        #pragma unroll
        for (int k = 0; k < KK; ++k) { av[k] = attL[tid*41 + p*20 + k]; mx = fmaxf(mx, av[k]); }
        float ssum = 0.f;
        #pragma unroll
        for (int k = 0; k < KK; ++k) { av[k] = expf(av[k] - mx); ssum += av[k]; }
        float inv = 1.f / ssum;
        float vpr = vL[p*256 + tid];
        float sacc = 0.f;
        #pragma unroll
        for (int k = 0; k < KK; ++k) {
            int j = idxL[p*20 + k];
            float u = U2[(size_t)j*256 + tid];
            float h2 = (u + vpr)*sc + sh;
            h2 = h2 > 0.f ? h2 : 0.2f*h2;
            sacc += av[k] * inv * h2;
        }
        xp2[(size_t)(n0 + p)*256 + tid] = sacc;
    }
}

// ================= final: out = lrelu(bn3(w3 @ x_c2)) -> fp32 =================
__global__ void final_kernel(const float* ws, float* out) {
    __shared__ __align__(16) float tileF[512*20];
    int tid = threadIdx.x;
    int b = blockIdx.x & 7;
    int n0 = (blockIdx.x >> 3) << 4;
    const float* xc2 = ws + O_XC2 + (size_t)b*512*NN;
    for (int i = tid; i < 256*16; i += 256) {
        int c = i >> 4, nn = i & 15;
        tileF[c*20 + nn] = xc2[c*NN + n0 + nn];
    }
    const float* xp2 = xc2 + (size_t)256*NN;
    #pragma unroll
    for (int it = 0; it < 16; ++it) {
        tileF[(256 + tid)*20 + it] = xp2[(size_t)(n0 + it)*256 + tid];
    }
    __syncthreads();
    const float* w3p = ws + O_W3P;
    int r0 = tid*2, r1 = r0 + 1;
    float acc0[16], acc1[16];
    #pragma unroll
    for (int q = 0; q < 16; ++q) { acc0[q] = 0.f; acc1[q] = 0.f; }
    #pragma unroll 4
    for (int c = 0; c < 512; ++c) {
        float w0 = w3p[r0*512 + c], w1v = w3p[r1*512 + c];
        const float4* tr = (const float4*)&tileF[c*20];
        #pragma unroll
        for (int q = 0; q < 4; ++q) {
            float4 t = tr[q];
            acc0[q*4+0] += w0*t.x;  acc0[q*4+1] += w0*t.y;  acc0[q*4+2] += w0*t.z;  acc0[q*4+3] += w0*t.w;
            acc1[q*4+0] += w1v*t.x; acc1[q*4+1] += w1v*t.y; acc1[q*4+2] += w1v*t.z; acc1[q*4+3] += w1v*t.w;
        }
    }
    float s0 = ws[O_BN3SC + r0], q0 = ws[O_BN3SH + r0];
    float s1 = ws[O_BN3SC + r1], q1 = ws[O_BN3SH + r1];
    float* ob = out + (size_t)b*512*NN;
    #pragma unroll
    for (int nn = 0; nn < 16; ++nn) {
        float v = acc0[nn]*s0 + q0; v = v > 0.f ? v : 0.2f*v;
        ob[r0*NN + n0 + nn] = v;
        float u = acc1[nn]*s1 + q1; u = u > 0.f ? u : 0.2f*u;
        ob[r1*NN + n0 + nn] = u;
    }
}

extern "C" void kernel_launch(void* const* d_in, const int* in_sizes, int n_in,
                              void* d_out, int out_size, void* d_ws, size_t ws_size,
                              hipStream_t stream) {
    float* ws = (float*)d_ws;
    float* out = (float*)d_out;
    ushort16_t* hilo = (ushort16_t*)(ws + O_HILO);
    float* xxq = ws + O_XXQ;

    detect_kernel<<<1, 64, 0, stream>>>(d_in[0], (int*)ws + O_FLAG);
    prep_kernel<<<64, 256, 0, stream>>>(d_in[1], d_in[2], d_in[3], d_in[4], d_in[5], d_in[6],
                                        d_in[7], d_in[8], d_in[9], d_in[10], d_in[11], d_in[12],
                                        d_in[13], d_in[14], d_in[15], d_in[16], d_in[17], d_in[18],
                                        d_in[19], d_in[20], d_in[21], ws);
    // lafe = xconv + knn3 (fused MFMA+select) + attention
    xconv_kernel<<<192, 256, 0, stream>>>(d_in[0], ws);
    hilo_kernel<3, 19, 32><<<256, 256, 0, stream>>>(ws + O_XMAN, hilo);
    xx_kernel<3, 19><<<64, 256, 0, stream>>>(ws + O_XMAN, xxq);
    knn_fused_kernel<3, 19, 32><<<1024, 512, 0, stream>>>(ws + O_XMAN, hilo, xxq, (int*)(ws + O_IDX3));
    lafe_att_kernel<<<64, 256, 0, stream>>>(ws, (const int*)(ws + O_IDX3));
    xc1copy_kernel<<<1216, 256, 0, stream>>>(ws);
    // knn on x_manet (C=19)
    hilo_kernel<19, 19, 64><<<1024, 256, 0, stream>>>(ws + O_XMAN, hilo);
    xx_kernel<19, 19><<<64, 256, 0, stream>>>(ws + O_XMAN, xxq);
    knn_fused_kernel<19, 19, 64><<<1024, 512, 0, stream>>>(ws + O_XMAN, hilo, xxq, (int*)(ws + O_IDX2));
    // edge1 via exact A/B decomposition: U1/V1 dense MFMA, then fused gather kernel
    uv1_kernel<<<256, 256, 0, stream>>>(ws);
    edge1_kernel<<<BB*512, 256, 0, stream>>>(ws, (const int*)(ws + O_IDX2));
    // knn on x_c1 (C=83)
    hilo_kernel<83, 83, 256><<<2048, 256, 0, stream>>>(ws + O_XC1, hilo);
    xx_kernel<83, 83><<<64, 256, 0, stream>>>(ws + O_XC1, xxq);
    knn_fused_kernel<83, 83, 256><<<1024, 512, 0, stream>>>(ws + O_XC1, hilo, xxq, (int*)(ws + O_IDX3));
    // edge2 via A/B decomposition: U2 = A @ xc1 (MFMA, batch-locked), then fused gather kernel
    uv2_kernel<<<256, 256, 0, stream>>>(ws);
    edge2_kernel<<<BB*1024, 256, 0, stream>>>(ws, (const int*)(ws + O_IDX3));
    mlp_kernel<<<BB*NN, 256, 0, stream>>>(ws);
    final_kernel<<<BB*(NN/16), 256, 0, stream>>>(ws, out);
}

// Round 7
// 1190.351 us; speedup vs baseline: 1.5866x; 1.0602x over previous
//
#include <hip/hip_runtime.h>
#include <hip/hip_bf16.h>
#include <math.h>

typedef __hip_bfloat16 bf16;
typedef unsigned short ushort16_t;
typedef unsigned int uint32;
typedef __attribute__((ext_vector_type(8))) short short8;
typedef __attribute__((ext_vector_type(4))) float floatx4;

#define BB 8
#define NN 2048
#define KK 20

// ---- workspace layout (float offsets) ----
#define O_XMAN  0                        // [8][19][2048]  rows 0..2 = x (fp32), rows 3..18 = lafe out
#define O_XC1   311296                   // [8][83][2048]
#define O_XC2   1671168                  // [8][512][2048]:
                                         //   pre-mlp: [b] first half = U2 fp32 [2048][256]
                                         //            [b] second half = V2 fp32 [2048][256] -> overwritten by XP2
                                         //   post-mlp: rows 0..255 = x_mlp [c][n]
                                         //   reused earlier: knn scratch (hilo/xx) + UV1
#define O_IDX2  10059776                 // int [8][2048][20]
#define O_IDX3  10387456                 // int [8][2048][20] (also temp home for lafe knn idx)
#define O_MLPW  10715136                 // [256][20] padded
#define O_MLPSC 10720256
#define O_MLPSH 10720512
#define O_W1P   10720768                 // W1S16 (edge1 GEMM weights, 3-split)
#define O_BN1SC 10724864
#define O_BN1SH 10724928
#define O_P1SC  10724992
#define O_P1SH  10725056
#define O_P1W   10725120                 // (spare)
#define O_P1B   10729216                 // (spare; p1_b is softmax-invariant)
#define O_W2P   10729280                 // (spare)
#define O_BN2SC 10794816
#define O_BN2SH 10795072
#define O_P2SC  10795328
#define O_P2SH  10795584
#define O_P2W   10795840                 // b2fT fp32 [84][256] (edge2 B = Wce + Wdiff, transposed)
#define O_P2B   10861376
#define O_W3P   10861632                 // [512][512]
#define O_BN3SC 11123776
#define O_BN3SH 11124288
#define O_LA    11124800                 // w1[48] b1[16] w2[48] b2[16] w3[16] b3[1]
#define O_FLAG  11124960                 // int: 1 if inputs are fp32, 0 if bf16
#define O_W2B16 11125760                 // ushort A2b [256][96] bf16 (edge2 A = Wnb - Wdiff)
#define O_P2W16 11162624                 // ushort [256][256] bf16 p2w

#define O_W1S16 O_W1P                    // ushort [128][64]
#define O_W1A3  11195392                 // ushort [3][64][192], ends 11213824

// knn scratch inside XC2 region (consumed before uv2/v2/edge2/mlp write XC2):
#define O_HILO  O_XC2
#define O_XXQ   (O_XC2 + 2097152)
#define O_UV1   (O_XC2 + 2113536)        // fp32 [8][2048][128] (U1 rows 0..63, V1 64..127)

__device__ __forceinline__ float ldin(const void* p, int i, int f32) {
    return f32 ? ((const float*)p)[i]
               : __bfloat162float(((const bf16*)p)[i]);
}

__device__ __forceinline__ ushort16_t f2bf(float v) {
    union { bf16 h; ushort16_t u; } x; x.h = __float2bfloat16(v); return x.u;
}

__device__ __forceinline__ float bfbits2f(ushort16_t u) {
    union { uint32 i; float f; } c; c.i = ((uint32)u) << 16; return c.f;
}

// ============ detect: are inputs fp32 or bf16? ============
__global__ void detect_kernel(const void* x, int* flag) {
    if (threadIdx.x == 0 && blockIdx.x == 0) {
        const unsigned short* u = (const unsigned short*)x;
        int bad = 0;
        for (int i = 0; i < 64; ++i) {
            int e = (u[i] >> 7) & 0xFF;
            if (e >= 0x86) bad++;
        }
        *flag = (bad > 0) ? 1 : 0;
    }
}

// ================= prep =================
__global__ void prep_kernel(
    const void* la_w1, const void* la_b1, const void* la_w2, const void* la_b2,
    const void* la_w3, const void* la_b3,
    const void* mlp_w, const void* mlp_b, const void* mlp_bn,
    const void* w1, const void* bn1, const void* w2, const void* bn2,
    const void* w3, const void* bn3,
    const void* p1_bn, const void* p1_w, const void* p1_b,
    const void* p2_bn, const void* p2_w, const void* p2_b,
    float* ws)
{
    const int f32 = ((const int*)ws)[O_FLAG];
    int gid = blockIdx.x * blockDim.x + threadIdx.x;
    int gsz = gridDim.x * blockDim.x;

    for (int i = gid; i < 256*20; i += gsz) {
        int o = i / 20, c = i - o*20;
        ws[O_MLPW + i] = (c < 19) ? ldin(mlp_w, o*19 + c, f32) : 0.f;
    }
    for (int c = gid; c < 256; c += gsz) {
        float g = ldin(mlp_bn, c, f32), be = ldin(mlp_bn, 256+c, f32);
        float m = ldin(mlp_bn, 512+c, f32), vv = ldin(mlp_bn, 768+c, f32);
        float s = g / sqrtf(vv + 1e-5f);
        ws[O_MLPSC + c] = s;
        ws[O_MLPSH + c] = be + (ldin(mlp_b, c, f32) - m) * s;
    }
    for (int c = gid; c < 64; c += gsz) {
        float g = ldin(bn1, c, f32), be = ldin(bn1, 64+c, f32);
        float m = ldin(bn1, 128+c, f32), vv = ldin(bn1, 192+c, f32);
        float s = g / sqrtf(vv + 1e-5f);
        ws[O_BN1SC + c] = s; ws[O_BN1SH + c] = be - m*s;
        float g2 = ldin(p1_bn, c, f32), be2 = ldin(p1_bn, 64+c, f32);
        float m2 = ldin(p1_bn, 128+c, f32), vv2 = ldin(p1_bn, 192+c, f32);
        float s2 = g2 / sqrtf(vv2 + 1e-5f);
        ws[O_P1SC + c] = s2; ws[O_P1SH + c] = be2 - m2*s2;
    }
    for (int c = gid; c < 256; c += gsz) {
        float g = ldin(bn2, c, f32), be = ldin(bn2, 256+c, f32);
        float m = ldin(bn2, 512+c, f32), vv = ldin(bn2, 768+c, f32);
        float s = g / sqrtf(vv + 1e-5f);
        ws[O_BN2SC + c] = s; ws[O_BN2SH + c] = be - m*s;
        float g2 = ldin(p2_bn, c, f32), be2 = ldin(p2_bn, 256+c, f32);
        float m2 = ldin(p2_bn, 512+c, f32), vv2 = ldin(p2_bn, 768+c, f32);
        float s2 = g2 / sqrtf(vv2 + 1e-5f);
        ws[O_P2SC + c] = s2; ws[O_P2SH + c] = be2 - m2*s2;
        ws[O_P2B + c] = ldin(p2_b, c, f32);
    }
    for (int i = gid; i < 512*512; i += gsz) ws[O_W3P + i] = ldin(w3, i, f32);
    for (int c = gid; c < 512; c += gsz) {
        float g = ldin(bn3, c, f32), be = ldin(bn3, 512+c, f32);
        float m = ldin(bn3, 1024+c, f32), vv = ldin(bn3, 1536+c, f32);
        float s = g / sqrtf(vv + 1e-5f);
        ws[O_BN3SC + c] = s; ws[O_BN3SH + c] = be - m*s;
    }
    for (int i = gid; i < 48; i += gsz) ws[O_LA + i]       = ldin(la_w1, i, f32);
    for (int i = gid; i < 16; i += gsz) ws[O_LA + 48 + i]  = ldin(la_b1, i, f32);
    for (int i = gid; i < 48; i += gsz) ws[O_LA + 64 + i]  = ldin(la_w2, i, f32);
    for (int i = gid; i < 16; i += gsz) ws[O_LA + 112 + i] = ldin(la_b2, i, f32);
    for (int i = gid; i < 16; i += gsz) ws[O_LA + 128 + i] = ldin(la_w3, i, f32);
    if (gid == 0) ws[O_LA + 144] = ldin(la_b3, 0, f32);

    // ---- edge1 decomposition: W1split (3-split interleaved, K side) ----
    ushort16_t* w1s = (ushort16_t*)(ws + O_W1S16);
    for (int i = gid; i < 128*64; i += gsz) {
        int row = i >> 6, kp = i & 63;
        if (kp < 57) {
            int c = kp / 3, s = kp - c*3;
            int o = row & 63;
            float wnb = ldin(w1, o*57 + c, f32);
            float wce = ldin(w1, o*57 + 19 + c, f32);
            float wdf = ldin(w1, o*57 + 38 + c, f32);
            float v = (row < 64) ? (wnb - wdf) : (wce + wdf);
            ushort16_t h = f2bf(v); float r1 = v - bfbits2f(h);
            ushort16_t m = f2bf(r1); ushort16_t l = f2bf(r1 - bfbits2f(m));
            w1s[i] = (s==0) ? h : ((s==1) ? m : l);
        } else w1s[i] = 0;
    }
    ushort16_t* w1a3 = (ushort16_t*)(ws + O_W1A3);
    for (int i = gid; i < 3*64*192; i += gsz) {
        int t = i / (64*192), rem = i - t*64*192;
        int o = rem / 192, kp = rem - o*192;
        int c = kp / 3;
        float v = ldin(p1_w, o*64 + c, f32);
        ushort16_t h = f2bf(v); float r1 = v - bfbits2f(h);
        ushort16_t m = f2bf(r1); ushort16_t l = f2bf(r1 - bfbits2f(m));
        w1a3[i] = (t==0) ? h : ((t==1) ? m : l);
    }

    // edge2 decomposition
    ushort16_t* a2b = (ushort16_t*)(ws + O_W2B16);
    for (int i = gid; i < 256*96; i += gsz) {
        int row = i / 96, c = i - row*96;
        float v = (c < 83) ? (ldin(w2, row*249 + c, f32) - ldin(w2, row*249 + 166 + c, f32)) : 0.f;
        a2b[i] = f2bf(v);
    }
    float* b2fT = ws + O_P2W;
    for (int i = gid; i < 84*256; i += gsz) {
        int c = i >> 8, row = i & 255;
        b2fT[i] = (c < 83) ? (ldin(w2, row*249 + 83 + c, f32) + ldin(w2, row*249 + 166 + c, f32)) : 0.f;
    }
    ushort16_t* pwb = (ushort16_t*)(ws + O_P2W16);
    for (int i = gid; i < 256*256; i += gsz) pwb[i] = f2bf(ldin(p2_w, i, f32));
}

// ================= xconv: x -> fp32 into XMAN rows 0..2 =================
__global__ __launch_bounds__(256) void xconv_kernel(const void* x, float* ws) {
    const int f32 = ((const int*)ws)[O_FLAG];
    int gid = blockIdx.x*256 + threadIdx.x;
    int b = gid / (3*NN), r = gid - b*3*NN;
    ws[O_XMAN + b*19*NN + r] = ldin(x, gid, f32);
}

// ================= xc1copy: xman rows 0..18 -> xc1 rows 0..18 (coalesced) =====
__global__ __launch_bounds__(256) void xc1copy_kernel(float* ws) {
    int gid = blockIdx.x*256 + threadIdx.x;
    int b = gid / (19*NN), r = gid - b*19*NN;
    ws[O_XC1 + (size_t)b*83*NN + r] = ws[O_XMAN + gid];
}

// ====== 3-way bf16 split precompute (batch locked to XCD via blockIdx&7) ======
template<int C, int CS, int KP>
__global__ void hilo_kernel(const float* feat, ushort16_t* out) {
    int b  = blockIdx.x & 7;
    int lb = blockIdx.x >> 3;
    int nb = gridDim.x >> 3;
    const float* fb = feat + (size_t)b*CS*NN;
    ushort16_t* ob = out + (size_t)b*NN*KP;
    for (int i = lb*blockDim.x + threadIdx.x; i < C*NN; i += nb*blockDim.x) {
        int c = i >> 11, n = i & (NN-1);
        float v = fb[(size_t)c*NN + n];
        ushort16_t h = f2bf(v);
        float r1 = v - bfbits2f(h);
        ushort16_t m = f2bf(r1);
        ushort16_t l = f2bf(r1 - bfbits2f(m));
        size_t base = (size_t)n*KP + 3*c;
        ob[base] = h; ob[base+1] = m; ob[base+2] = l;
    }
    constexpr int PAD = KP - 3*C;
    for (int i = lb*blockDim.x + threadIdx.x; i < NN*PAD; i += nb*blockDim.x) {
        int n = i / PAD, p = i - n*PAD;
        ob[(size_t)n*KP + 3*C + p] = 0;
    }
}

// ====== exact fp32 squared norms ======
template<int C, int CS>
__global__ __launch_bounds__(256) void xx_kernel(const float* feat, float* xxg) {
    int gid = blockIdx.x*256 + threadIdx.x;
    int b = gid >> 11, n = gid & (NN-1);
    const float* fb = feat + (size_t)b*CS*NN;
    float s = 0.f;
    #pragma unroll
    for (int c = 0; c < C; ++c) { float v = fb[c*NN + n]; s += v*v; }
    xxg[gid] = s;
}

// ====== fused knn: MFMA distance tile + lazy top-3 u64-butterfly extraction ======
template<int C, int CS, int KP>
__global__ __launch_bounds__(512, 2) void knn_fused_kernel(
    const float* feat, const ushort16_t* hilo, const float* xxg, int* idxout)
{
    constexpr int KT = KP / 32;
    constexpr int ST = 2057;
    __shared__ float Dt[16 * ST];
    int tid = threadIdx.x;
    int b  = blockIdx.x & 7;
    int n0 = (blockIdx.x >> 3) << 4;
    int lane = tid & 63, wv = tid >> 6;
    int quad = lane >> 4, l15 = lane & 15;
    const float* fb = feat + (size_t)b * CS * NN;

    short8 Bh[KT], Bm[KT], Bl[KT];
    #pragma unroll
    for (int kt = 0; kt < KT; ++kt) {
        #pragma unroll
        for (int e = 0; e < 8; ++e) {
            int kp = kt*32 + quad*8 + e;
            int c = kp / 3;
            float v = (c < C) ? fb[(size_t)c*NN + n0 + l15] : 0.f;
            ushort16_t h = f2bf(v);
            float r1 = v - bfbits2f(h);
            ushort16_t m = f2bf(r1);
            ushort16_t l = f2bf(r1 - bfbits2f(m));
            Bh[kt][e] = (short)h; Bm[kt][e] = (short)m; Bl[kt][e] = (short)l;
        }
    }

    const ushort16_t* hb = hilo + (size_t)b * NN * KP;
    const float* xxb = xxg + b * NN;

    #pragma unroll
    for (int i = 0; i < 4; ++i) {
        int base = (wv*4 + i) * 64;
        floatx4 acc[4];
        #pragma unroll
        for (int st = 0; st < 4; ++st) {
            acc[st] = (floatx4){0.f,0.f,0.f,0.f};
            #pragma unroll
            for (int kt = 0; kt < KT; ++kt) {
                short8 a = *(const short8*)&hb[(size_t)(base + st*16 + l15)*KP + kt*32 + quad*8];
                acc[st] = __builtin_amdgcn_mfma_f32_16x16x32_bf16(a, Bh[kt], acc[st], 0, 0, 0);
                acc[st] = __builtin_amdgcn_mfma_f32_16x16x32_bf16(a, Bm[kt], acc[st], 0, 0, 0);
                acc[st] = __builtin_amdgcn_mfma_f32_16x16x32_bf16(a, Bl[kt], acc[st], 0, 0, 0);
            }
        }
        #pragma unroll
        for (int st = 0; st < 4; ++st) {
            #pragma unroll
            for (int r = 0; r < 4; ++r) {
                int cand = base + st*16 + quad*4 + r;
                Dt[l15*ST + cand] = 2.f*acc[st][r] - xxb[cand];
            }
        }
    }
    __syncthreads();

    int r0 = wv*2, r1 = wv*2 + 1;
    unsigned int basei = 2047u - (unsigned int)lane;
    unsigned int a0[32], a1[32];
    unsigned int dead0 = 0, dead1 = 0;
    unsigned long long p0 = 0, p1 = 0, p2 = 0;
    unsigned long long q0 = 0, q1 = 0, q2 = 0;
    #pragma unroll
    for (int j = 0; j < 32; ++j) {
        unsigned int u0 = __float_as_uint(Dt[r0*ST + j*64 + lane]);
        unsigned int u1 = __float_as_uint(Dt[r1*ST + j*64 + lane]);
        unsigned int o0 = u0 ^ (unsigned int)(((int)u0 >> 31) | 0x80000000);
        unsigned int o1 = u1 ^ (unsigned int)(((int)u1 >> 31) | 0x80000000);
        a0[j] = o0; a1[j] = o1;
        unsigned long long k0 = ((unsigned long long)o0 << 32) | (basei - j*64);
        unsigned long long k1 = ((unsigned long long)o1 << 32) | (basei - j*64);
        bool g00 = k0 > p0, g01 = k0 > p1, g02 = k0 > p2;
        p2 = g01 ? p1 : (g02 ? k0 : p2);
        p1 = g00 ? p0 : (g01 ? k0 : p1);
        p0 = g00 ? k0 : p0;
        bool g10 = k1 > q0, g11 = k1 > q1, g12 = k1 > q2;
        q2 = g11 ? q1 : (g12 ? k1 : q2);
        q1 = g10 ? q0 : (g11 ? k1 : q1);
        q0 = g10 ? k1 : q0;
    }
    int myg0 = 0, myg1 = 0;
    #pragma unroll 1
    for (int it = 0; it < KK; ++it) {
        unsigned long long b0 = p0, b1 = q0;
        #pragma unroll
        for (int sh = 1; sh < 64; sh <<= 1) {
            unsigned long long o0 = __shfl_xor(b0, sh);
            unsigned long long o1 = __shfl_xor(b1, sh);
            b0 = (o0 > b0) ? o0 : b0;
            b1 = (o1 > b1) ? o1 : b1;
        }
        if (lane == it) {
            myg0 = (int)(2047u - (unsigned int)b0);
            myg1 = (int)(2047u - (unsigned int)b1);
        }
        if (p0 == b0) {
            dead0 |= 1u << ((int)(basei - (unsigned int)b0) >> 6);
            p0 = p1; p1 = p2; p2 = 0;
        }
        if (q0 == b1) {
            dead1 |= 1u << ((int)(basei - (unsigned int)b1) >> 6);
            q0 = q1; q1 = q2; q2 = 0;
        }
        if (__any((p0 == 0ull) | (q0 == 0ull))) {
            if (p0 == 0ull) {
                unsigned long long t0 = 0, t1 = 0, t2 = 0;
                #pragma unroll
                for (int j = 0; j < 32; ++j) {
                    unsigned long long k = ((dead0 >> j) & 1u) ? 0ull
                        : (((unsigned long long)a0[j] << 32) | (basei - j*64));
                    bool g0 = k > t0, g1 = k > t1, g2 = k > t2;
                    t2 = g1 ? t1 : (g2 ? k : t2);
                    t1 = g0 ? t0 : (g1 ? k : t1);
                    t0 = g0 ? k : t0;
                }
                p0 = t0; p1 = t1; p2 = t2;
            }
            if (q0 == 0ull) {
                unsigned long long t0 = 0, t1 = 0, t2 = 0;
                #pragma unroll
                for (int j = 0; j < 32; ++j) {
                    unsigned long long k = ((dead1 >> j) & 1u) ? 0ull
                        : (((unsigned long long)a1[j] << 32) | (basei - j*64));
                    bool g0 = k > t0, g1 = k > t1, g2 = k > t2;
                    t2 = g1 ? t1 : (g2 ? k : t2);
                    t1 = g0 ? t0 : (g1 ? k : t1);
                    t0 = g0 ? k : t0;
                }
                q0 = t0; q1 = t1; q2 = t2;
            }
        }
    }
    if (lane < KK) {
        idxout[((size_t)(b*NN + n0 + r0))*KK + lane] = myg0;
        idxout[((size_t)(b*NN + n0 + r1))*KK + lane] = myg1;
    }
}

// ================= lafe attention (post-knn) =================
__global__ __launch_bounds__(256, 1) void lafe_att_kernel(float* ws, const int* idx) {
    __shared__ float xs0[NN], xs1[NN], xs2[NN];
    int tid = threadIdx.x;
    int b = blockIdx.x >> 3;
    int n = ((blockIdx.x & 7) << 8) + tid;
    float* xm = ws + O_XMAN + b*19*NN;
    for (int i = tid; i < NN; i += 256) {
        xs0[i] = xm[i]; xs1[i] = xm[NN + i]; xs2[i] = xm[2*NN + i];
    }
    __syncthreads();
    float a0 = xs0[n], a1 = xs1[n], a2 = xs2[n];
    int ti[KK];
    #pragma unroll
    for (int k = 0; k < KK; ++k) ti[k] = idx[(b*NN + n)*KK + k] & (NN-1);
    const float* wl = ws + O_LA;
    float sa = wl[144];
    #pragma unroll
    for (int o = 0; o < 16; ++o) {
        float nf = wl[o*3+0]*a0 + wl[o*3+1]*a1 + wl[o*3+2]*a2 + wl[48+o];
        sa += wl[128+o]*nf;
    }
    float lg[KK]; float mx = -3.0e38f;
    #pragma unroll
    for (int k = 0; k < KK; ++k) {
        int m = ti[k];
        float d0 = a0 - xs0[m], d1 = a1 - xs1[m], d2 = a2 - xs2[m];
        float na = wl[144];
        #pragma unroll
        for (int o = 0; o < 16; ++o) {
            float ef = wl[64+o*3+0]*d0 + wl[64+o*3+1]*d1 + wl[64+o*3+2]*d2 + wl[112+o];
            na += wl[128+o]*ef;
        }
        float t = sa + na;
        t = t > 0.f ? t : 0.01f*t;
        lg[k] = t; mx = fmaxf(mx, t);
    }
    float ssum = 0.f;
    #pragma unroll
    for (int k = 0; k < KK; ++k) { lg[k] = expf(lg[k] - mx); ssum += lg[k]; }
    float vals[16];
    #pragma unroll
    for (int o = 0; o < 16; ++o) vals[o] = 0.f;
    #pragma unroll
    for (int k = 0; k < KK; ++k) {
        float coef = lg[k] / ssum;
        int m = ti[k];
        float d0 = a0 - xs0[m], d1 = a1 - xs1[m], d2 = a2 - xs2[m];
        #pragma unroll
        for (int o = 0; o < 16; ++o) {
            float ef = wl[64+o*3+0]*d0 + wl[64+o*3+1]*d1 + wl[64+o*3+2]*d2 + wl[112+o];
            vals[o] += coef * ef;
        }
    }
    #pragma unroll
    for (int o = 0; o < 16; ++o) {
        float v = vals[o];
        xm[(3+o)*NN + n] = v > 0.f ? v : expm1f(v);
    }
}

// ================= mlp (batch = blockIdx&7) =================
__global__ void mlp_kernel(float* ws) {
    __shared__ __align__(16) float xv[20];
    int tid = threadIdx.x;
    int b = blockIdx.x & 7, n = blockIdx.x >> 3;
    if (tid < 20) xv[tid] = (tid < 19) ? ws[O_XMAN + b*19*NN + tid*NN + n] : 0.f;
    __syncthreads();
    const float* mw = ws + O_MLPW;
    float acc = 0.f;
    #pragma unroll
    for (int c4 = 0; c4 < 5; ++c4) {
        float4 w = *(const float4*)&mw[tid*20 + c4*4];
        float4 g = *(const float4*)&xv[c4*4];
        acc += w.x*g.x + w.y*g.y + w.z*g.z + w.w*g.w;
    }
    float v = acc * ws[O_MLPSC + tid] + ws[O_MLPSH + tid];
    ws[O_XC2 + b*512*NN + tid*NN + n] = fmaxf(v, 0.f);
}

// ====== uv1: [U1;V1][n][128] = [A1;B1] @ xman via exact 3-split MFMA ======
__global__ __launch_bounds__(256, 2) void uv1_kernel(float* ws) {
    __shared__ float xt[19*64];
    int tid = threadIdx.x;
    int b = blockIdx.x & 7;
    int pn0 = (blockIdx.x >> 3) << 6;
    const float* fb = ws + O_XMAN + (size_t)b*19*NN;
    for (int i = tid; i < 19*64; i += 256) {
        int c = i >> 6, j = i & 63;
        xt[i] = fb[(size_t)c*NN + pn0 + j];
    }
    __syncthreads();
    int lane = tid & 63, wv = tid >> 6;
    int quad = lane >> 4, l15 = lane & 15;

    short8 X[3][4][2];
    #pragma unroll
    for (int nt = 0; nt < 4; ++nt) {
        int pt = nt*16 + l15;
        #pragma unroll
        for (int kt = 0; kt < 2; ++kt) {
            #pragma unroll
            for (int e = 0; e < 8; ++e) {
                int kp = kt*32 + quad*8 + e;
                int c = kp / 3;
                float v = (c < 19) ? xt[c*64 + pt] : 0.f;
                ushort16_t h = f2bf(v); float r1 = v - bfbits2f(h);
                ushort16_t m = f2bf(r1); ushort16_t l = f2bf(r1 - bfbits2f(m));
                X[0][nt][kt][e] = (short)h;
                X[1][nt][kt][e] = (short)m;
                X[2][nt][kt][e] = (short)l;
            }
        }
    }
    const ushort16_t* w1s = (const ushort16_t*)(ws + O_W1S16);
    floatx4 acc[2][4];
    #pragma unroll
    for (int rt = 0; rt < 2; ++rt)
        #pragma unroll
        for (int nt = 0; nt < 4; ++nt) acc[rt][nt] = (floatx4){0.f,0.f,0.f,0.f};
    #pragma unroll
    for (int pass = 0; pass < 3; ++pass) {
        #pragma unroll
        for (int kt = 0; kt < 2; ++kt) {
            int c0 = kt*32 + quad*8;
            short8 a[2];
            a[0] = *(const short8*)&w1s[(wv*32 + l15)*64 + c0];
            a[1] = *(const short8*)&w1s[(wv*32 + 16 + l15)*64 + c0];
            #pragma unroll
            for (int rt = 0; rt < 2; ++rt)
                #pragma unroll
                for (int nt = 0; nt < 4; ++nt)
                    acc[rt][nt] = __builtin_amdgcn_mfma_f32_16x16x32_bf16(a[rt], X[pass][nt][kt], acc[rt][nt], 0, 0, 0);
        }
    }
    float* uv1 = ws + O_UV1 + (size_t)b*NN*128;
    #pragma unroll
    for (int rt = 0; rt < 2; ++rt)
        #pragma unroll
        for (int nt = 0; nt < 4; ++nt) {
            int n = pn0 + nt*16 + l15;
            int r = wv*32 + rt*16 + quad*4;
            *(float4*)&uv1[(size_t)n*128 + r] =
                make_float4(acc[rt][nt][0], acc[rt][nt][1], acc[rt][nt][2], acc[rt][nt][3]);
        }
}

// ================= edge1 v2: U1/V1 gather + exact 3-split att GEMM =================
__global__ __launch_bounds__(256, 2) void edge1_kernel(float* ws, const int* idx) {
    constexpr int SW = 204;   // hrS ushort stride (192 used; 102 words -> 6*l15 mod 32 distinct)
    constexpr int ST = 65;    // attL float stride
    __shared__ __align__(16) ushort16_t hrS[80*SW];   // 32,640 B
    __shared__ __align__(16) float attL[80*ST];       // 20,800 B
    __shared__ float vL[4*64];
    __shared__ float scalL[256];
    __shared__ float outL[64*5];
    __shared__ int idxL[80];

    int tid = threadIdx.x;
    int b  = blockIdx.x & 7;
    int n0 = (blockIdx.x >> 3) << 2;
    const float* uv1 = ws + O_UV1 + (size_t)b*NN*128;

    {
        int grp = tid >> 6, r6 = tid & 63;
        int off = grp==0 ? O_BN1SC : grp==1 ? O_BN1SH : grp==2 ? O_P1SC : O_P1SH;
        scalL[tid] = ws[off + r6];
        vL[tid] = uv1[(size_t)(n0 + grp)*128 + 64 + r6];
    }
    if (tid < 80) idxL[tid] = idx[(b*NN + n0 + tid/20)*KK + (tid%20)] & (NN-1);
    __syncthreads();

    {
        int rw = tid & 63, cg = tid >> 6;
        float s1 = scalL[rw], sh1 = scalL[64+rw], ps = scalL[128+rw], ph = scalL[192+rw];
        #pragma unroll 5
        for (int it = 0; it < 20; ++it) {
            int col = it*4 + cg;
            int p = col / 20;
            int j = idxL[col];
            float u = uv1[(size_t)j*128 + rw];
            float h1 = (u + vL[p*64+rw])*s1 + sh1;
            h1 = h1 > 0.f ? h1 : 0.2f*h1;
            float hv = h1*ps + ph;
            hv = hv > 0.f ? hv : 0.f;
            ushort16_t h = f2bf(hv); float r1 = hv - bfbits2f(h);
            ushort16_t m = f2bf(r1); ushort16_t l = f2bf(r1 - bfbits2f(m));
            hrS[col*SW + 3*rw + 0] = h;
            hrS[col*SW + 3*rw + 1] = m;
            hrS[col*SW + 3*rw + 2] = l;
        }
    }
    __syncthreads();

    int lane = tid & 63, wv = tid >> 6;
    int quad = lane >> 4, l15 = lane & 15;
    const ushort16_t* w1a3 = (const ushort16_t*)(ws + O_W1A3);
    floatx4 acc[5];
    #pragma unroll
    for (int mt = 0; mt < 5; ++mt) acc[mt] = (floatx4){0.f,0.f,0.f,0.f};
    #pragma unroll
    for (int pass = 0; pass < 3; ++pass) {
        #pragma unroll
        for (int kt = 0; kt < 6; ++kt) {
            int c0 = kt*32 + quad*8;
            short8 bfrag = *(const short8*)&w1a3[((size_t)pass*64 + wv*16 + l15)*192 + c0];
            #pragma unroll
            for (int mt = 0; mt < 5; ++mt) {
                short8 afrag = *(const short8*)&hrS[(mt*16 + l15)*SW + c0];
                acc[mt] = __builtin_amdgcn_mfma_f32_16x16x32_bf16(afrag, bfrag, acc[mt], 0, 0, 0);
            }
        }
    }
    #pragma unroll
    for (int mt = 0; mt < 5; ++mt)
        #pragma unroll
        for (int r = 0; r < 4; ++r)
            attL[(mt*16 + quad*4 + r)*ST + wv*16 + l15] = acc[mt][r];
    __syncthreads();

    {
        int o = tid & 63, p = tid >> 6;
        float av[KK]; float mx = -3.0e38f;
        #pragma unroll
        for (int k = 0; k < KK; ++k) { av[k] = attL[(p*20 + k)*ST + o]; mx = fmaxf(mx, av[k]); }
        float ssum = 0.f;
        #pragma unroll
        for (int k = 0; k < KK; ++k) { av[k] = expf(av[k] - mx); ssum += av[k]; }
        float inv = 1.f / ssum;
        float s1o = scalL[o], sh1o = scalL[64+o], vpo = vL[p*64+o];
        float sacc = 0.f;
        #pragma unroll
        for (int k = 0; k < KK; ++k) {
            int j = idxL[p*20 + k];
            float u = uv1[(size_t)j*128 + o];
            float h1 = (u + vpo)*s1o + sh1o;
            h1 = h1 > 0.f ? h1 : 0.2f*h1;
            sacc += av[k]*inv*h1;
        }
        outL[o*5 + p] = sacc;
    }
    __syncthreads();
    {
        int o = tid >> 2, p = tid & 3;
        ws[O_XC1 + (size_t)b*83*NN + (size_t)(19+o)*NN + n0 + p] = outL[o*5 + p];
    }
}

// ====== uv2: U2[b][n][r] = sum_c A2[r][c] * xc1[b][c][n] (batch = blockIdx&7) ======
__global__ __launch_bounds__(256, 2) void uv2_kernel(float* ws) {
    constexpr int XS = 108;                 // 54 words -> 22*l15 mod 32 distinct: conflict-free
    __shared__ ushort16_t xt[64*XS];        // 13,824 B
    int tid = threadIdx.x;
    int b = blockIdx.x & 7;
    int pn0 = (blockIdx.x >> 3) << 6;
    const float* xc1 = ws + O_XC1 + (size_t)b*83*NN;
    for (int i = tid; i < 96*64; i += 256) {
        int c = i >> 6, j = i & 63;
        xt[j*XS + c] = (c < 83) ? f2bf(xc1[c*NN + pn0 + j]) : (ushort16_t)0;
    }
    __syncthreads();
    int lane = tid & 63, wv = tid >> 6;
    int quad = lane >> 4, l15 = lane & 15;
    const ushort16_t* a2b = (const ushort16_t*)(ws + O_W2B16);
    floatx4 acc[4][4];
    #pragma unroll
    for (int rt = 0; rt < 4; ++rt)
        #pragma unroll
        for (int nt = 0; nt < 4; ++nt) acc[rt][nt] = (floatx4){0.f,0.f,0.f,0.f};
    #pragma unroll
    for (int kt = 0; kt < 3; ++kt) {
        int c0 = kt*32 + quad*8;
        short8 bfr[4], a[4];
        #pragma unroll
        for (int nt = 0; nt < 4; ++nt)
            bfr[nt] = *(const short8*)&xt[(nt*16 + l15)*XS + c0];
        #pragma unroll
        for (int rt = 0; rt < 4; ++rt)
            a[rt] = *(const short8*)&a2b[(wv*64 + rt*16 + l15)*96 + c0];
        #pragma unroll
        for (int rt = 0; rt < 4; ++rt)
            #pragma unroll
            for (int nt = 0; nt < 4; ++nt)
                acc[rt][nt] = __builtin_amdgcn_mfma_f32_16x16x32_bf16(a[rt], bfr[nt], acc[rt][nt], 0, 0, 0);
    }
    float* U2 = ws + O_XC2 + (size_t)b*512*NN;
    #pragma unroll
    for (int rt = 0; rt < 4; ++rt)
        #pragma unroll
        for (int nt = 0; nt < 4; ++nt) {
            int n = pn0 + nt*16 + l15;
            int r = wv*64 + rt*16 + quad*4;
            *(float4*)&U2[(size_t)n*256 + r] =
                make_float4(acc[rt][nt][0], acc[rt][nt][1], acc[rt][nt][2], acc[rt][nt][3]);
        }
}

// ====== v2: V2[b][n][r] = sum_c b2fT[c][r] * xc1[b][c][n], exact fp32, point-major ======
// stored in the XP2 half of XC2 (each edge2 block consumes its 2 rows before writing xp2 there)
__global__ __launch_bounds__(256, 4) void v2_kernel(float* ws) {
    __shared__ float xs[83*16];             // 5,312 B
    int tid = threadIdx.x;
    int b = blockIdx.x & 7;
    int pn0 = (blockIdx.x >> 3) << 4;       // 16 points per block, 128 groups/batch
    const float* xc1 = ws + O_XC1 + (size_t)b*83*NN;
    for (int i = tid; i < 83*16; i += 256) {
        int c = i >> 4, j = i & 15;
        xs[i] = xc1[(size_t)c*NN + pn0 + j];
    }
    __syncthreads();
    const float* b2fT = ws + O_P2W;
    float acc[16];
    #pragma unroll
    for (int j = 0; j < 16; ++j) acc[j] = 0.f;
    #pragma unroll 4
    for (int c = 0; c < 83; ++c) {
        float w = b2fT[c*256 + tid];
        #pragma unroll
        for (int j = 0; j < 16; ++j) acc[j] += w * xs[c*16 + j];
    }
    float* V2 = ws + O_XC2 + (size_t)b*512*NN + (size_t)256*NN;
    #pragma unroll
    for (int j = 0; j < 16; ++j) V2[(size_t)(pn0 + j)*256 + tid] = acc[j];
}

// ================= edge2 v3: 2 points/block, V precomputed, h2 reg-cached =================
__global__ __launch_bounds__(256, 2) void edge2_kernel(float* ws, const int* idx) {
    constexpr int HS = 268;   // 134 words -> 6*l15 mod 32 distinct: conflict-free ds_read_b128
    __shared__ __align__(16) ushort16_t hrb[48*HS];    // 25,728 B (cols 40..47 pad, discarded)
    __shared__ __align__(16) float attL[256*41];       // 41,984 B
    __shared__ float p2bL[256];
    __shared__ int idxL[40];

    int tid = threadIdx.x;
    int b  = blockIdx.x & 7;                // batch -> XCD lock (U2/V2[b] L2-resident)
    int n0 = (blockIdx.x >> 3) << 1;        // 2 points per block

    const float* U2 = ws + O_XC2 + (size_t)b*512*NN;
    float* V2 = ws + O_XC2 + (size_t)b*512*NN + (size_t)256*NN;   // also xp2 output

    float sc = ws[O_BN2SC + tid], sh = ws[O_BN2SH + tid];
    float ps = ws[O_P2SC + tid],  ph = ws[O_P2SH + tid];
    p2bL[tid] = ws[O_P2B + tid];
    float v0 = V2[(size_t)n0*256 + tid];
    float v1 = V2[(size_t)(n0+1)*256 + tid];
    if (tid < 40) idxL[tid] = idx[(b*NN + n0 + tid/20)*KK + (tid%20)] & (NN-1);
    __syncthreads();

    // P1: gather U2 rows (L2-hit), compute h2 (kept in VGPRs), write hr tile bf16
    float h2r[40];
    #pragma unroll
    for (int col = 0; col < 40; ++col) {
        int j = idxL[col];
        float u = U2[(size_t)j*256 + tid];
        float h2 = (u + (col >= 20 ? v1 : v0))*sc + sh;
        h2 = h2 > 0.f ? h2 : 0.2f*h2;
        h2r[col] = h2;
        float hv = h2*ps + ph;
        hrb[col*HS + tid] = f2bf(fmaxf(hv, 0.f));
    }
    __syncthreads();

    // P2: att GEMM (p2w [256x256] bf16 x hr [256 x 48(40 used)])
    int lane = tid & 63, wv = tid >> 6;
    int quad = lane >> 4, l15 = lane & 15;
    const ushort16_t* p2wb = (const ushort16_t*)(ws + O_P2W16);
    floatx4 acc2[4][3];
    #pragma unroll
    for (int mt = 0; mt < 4; ++mt)
        #pragma unroll
        for (int nt = 0; nt < 3; ++nt) acc2[mt][nt] = (floatx4){0.f,0.f,0.f,0.f};
    for (int kt = 0; kt < 8; ++kt) {
        int c0 = kt*32 + quad*8;
        short8 a[4], bb3[3];
        #pragma unroll
        for (int mt = 0; mt < 4; ++mt)
            a[mt] = *(const short8*)&p2wb[(wv*64 + mt*16 + l15)*256 + c0];
        #pragma unroll
        for (int nt = 0; nt < 3; ++nt)
            bb3[nt] = *(const short8*)&hrb[(nt*16 + l15)*HS + c0];
        #pragma unroll
        for (int mt = 0; mt < 4; ++mt)
            #pragma unroll
            for (int nt = 0; nt < 3; ++nt)
                acc2[mt][nt] = __builtin_amdgcn_mfma_f32_16x16x32_bf16(a[mt], bb3[nt], acc2[mt][nt], 0, 0, 0);
    }
    #pragma unroll
    for (int mt = 0; mt < 4; ++mt) {
        int k0 = wv*64 + mt*16 + quad*4;
        #pragma unroll
        for (int nt = 0; nt < 3; ++nt) {
            int col = nt*16 + l15;
            if (col < 40) {
                #pragma unroll
                for (int r = 0; r < 4; ++r)
                    attL[(k0 + r)*41 + col] = acc2[mt][nt][r] + p2bL[k0 + r];
            }
        }
    }
    __syncthreads();

    // P3: per-row softmax over k + weighted sum of reg-cached h2 -> xp2 (overwrites V2 rows)
    #pragma unroll
    for (int p = 0; p < 2; ++p) {
        float av[KK]; float mx = -3.0e38f;
        #pragma unroll
        for (int k = 0; k < KK; ++k) { av[k] = attL[tid*41 + p*20 + k]; mx = fmaxf(mx, av[k]); }
        float ssum = 0.f;
        #pragma unroll
        for (int k = 0; k < KK; ++k) { av[k] = expf(av[k] - mx); ssum += av[k]; }
        float inv = 1.f / ssum;
        float sacc = 0.f;
        #pragma unroll
        for (int k = 0; k < KK; ++k) sacc += av[k] * inv * h2r[p*20 + k];
        V2[(size_t)(n0 + p)*256 + tid] = sacc;
    }
}

// ================= final: out = lrelu(bn3(w3 @ x_c2)) -> fp32 =================
__global__ void final_kernel(const float* ws, float* out) {
    __shared__ __align__(16) float tileF[512*20];
    int tid = threadIdx.x;
    int b = blockIdx.x & 7;
    int n0 = (blockIdx.x >> 3) << 4;
    const float* xc2 = ws + O_XC2 + (size_t)b*512*NN;
    for (int i = tid; i < 256*16; i += 256) {
        int c = i >> 4, nn = i & 15;
        tileF[c*20 + nn] = xc2[c*NN + n0 + nn];
    }
    const float* xp2 = xc2 + (size_t)256*NN;
    #pragma unroll
    for (int it = 0; it < 16; ++it) {
        tileF[(256 + tid)*20 + it] = xp2[(size_t)(n0 + it)*256 + tid];
    }
    __syncthreads();
    const float* w3p = ws + O_W3P;
    int r0 = tid*2, r1 = r0 + 1;
    float acc0[16], acc1[16];
    #pragma unroll
    for (int q = 0; q < 16; ++q) { acc0[q] = 0.f; acc1[q] = 0.f; }
    #pragma unroll 4
    for (int c = 0; c < 512; ++c) {
        float w0 = w3p[r0*512 + c], w1v = w3p[r1*512 + c];
        const float4* tr = (const float4*)&tileF[c*20];
        #pragma unroll
        for (int q = 0; q < 4; ++q) {
            float4 t = tr[q];
            acc0[q*4+0] += w0*t.x;  acc0[q*4+1] += w0*t.y;  acc0[q*4+2] += w0*t.z;  acc0[q*4+3] += w0*t.w;
            acc1[q*4+0] += w1v*t.x; acc1[q*4+1] += w1v*t.y; acc1[q*4+2] += w1v*t.z; acc1[q*4+3] += w1v*t.w;
        }
    }
    float s0 = ws[O_BN3SC + r0], q0 = ws[O_BN3SH + r0];
    float s1 = ws[O_BN3SC + r1], q1 = ws[O_BN3SH + r1];
    float* ob = out + (size_t)b*512*NN;
    #pragma unroll
    for (int nn = 0; nn < 16; ++nn) {
        float v = acc0[nn]*s0 + q0; v = v > 0.f ? v : 0.2f*v;
        ob[r0*NN + n0 + nn] = v;
        float u = acc1[nn]*s1 + q1; u = u > 0.f ? u : 0.2f*u;
        ob[r1*NN + n0 + nn] = u;
    }
}

extern "C" void kernel_launch(void* const* d_in, const int* in_sizes, int n_in,
                              void* d_out, int out_size, void* d_ws, size_t ws_size,
                              hipStream_t stream) {
    float* ws = (float*)d_ws;
    float* out = (float*)d_out;
    ushort16_t* hilo = (ushort16_t*)(ws + O_HILO);
    float* xxq = ws + O_XXQ;

    detect_kernel<<<1, 64, 0, stream>>>(d_in[0], (int*)ws + O_FLAG);
    prep_kernel<<<64, 256, 0, stream>>>(d_in[1], d_in[2], d_in[3], d_in[4], d_in[5], d_in[6],
                                        d_in[7], d_in[8], d_in[9], d_in[10], d_in[11], d_in[12],
                                        d_in[13], d_in[14], d_in[15], d_in[16], d_in[17], d_in[18],
                                        d_in[19], d_in[20], d_in[21], ws);
    // lafe = xconv + knn3 (fused MFMA+select) + attention
    xconv_kernel<<<192, 256, 0, stream>>>(d_in[0], ws);
    hilo_kernel<3, 19, 32><<<256, 256, 0, stream>>>(ws + O_XMAN, hilo);
    xx_kernel<3, 19><<<64, 256, 0, stream>>>(ws + O_XMAN, xxq);
    knn_fused_kernel<3, 19, 32><<<1024, 512, 0, stream>>>(ws + O_XMAN, hilo, xxq, (int*)(ws + O_IDX3));
    lafe_att_kernel<<<64, 256, 0, stream>>>(ws, (const int*)(ws + O_IDX3));
    xc1copy_kernel<<<1216, 256, 0, stream>>>(ws);
    // knn on x_manet (C=19)
    hilo_kernel<19, 19, 64><<<1024, 256, 0, stream>>>(ws + O_XMAN, hilo);
    xx_kernel<19, 19><<<64, 256, 0, stream>>>(ws + O_XMAN, xxq);
    knn_fused_kernel<19, 19, 64><<<1024, 512, 0, stream>>>(ws + O_XMAN, hilo, xxq, (int*)(ws + O_IDX2));
    // edge1 via exact A/B decomposition
    uv1_kernel<<<256, 256, 0, stream>>>(ws);
    edge1_kernel<<<BB*512, 256, 0, stream>>>(ws, (const int*)(ws + O_IDX2));
    // knn on x_c1 (C=83)
    hilo_kernel<83, 83, 256><<<2048, 256, 0, stream>>>(ws + O_XC1, hilo);
    xx_kernel<83, 83><<<64, 256, 0, stream>>>(ws + O_XC1, xxq);
    knn_fused_kernel<83, 83, 256><<<1024, 512, 0, stream>>>(ws + O_XC1, hilo, xxq, (int*)(ws + O_IDX3));
    // edge2 via A/B decomposition: U2 (MFMA) + V2 (exact fp32 dense), then fused gather kernel
    uv2_kernel<<<256, 256, 0, stream>>>(ws);
    v2_kernel<<<1024, 256, 0, stream>>>(ws);
    edge2_kernel<<<BB*1024, 256, 0, stream>>>(ws, (const int*)(ws + O_IDX3));
    mlp_kernel<<<BB*NN, 256, 0, stream>>>(ws);
    final_kernel<<<BB*(NN/16), 256, 0, stream>>>(ws, out);
}

// Round 8
// 1008.255 us; speedup vs baseline: 1.8732x; 1.1806x over previous
//
#include <hip/hip_runtime.h>
#include <hip/hip_bf16.h>
#include <math.h>

typedef __hip_bfloat16 bf16;
typedef unsigned short ushort16_t;
typedef unsigned int uint32;
typedef __attribute__((ext_vector_type(8))) short short8;
typedef __attribute__((ext_vector_type(4))) float floatx4;

#define BB 8
#define NN 2048
#define KK 20

// ---- workspace layout (float offsets) ----
#define O_XMAN  0                        // [8][19][2048]  rows 0..2 = x (fp32), rows 3..18 = lafe out
#define O_XC1   311296                   // [8][83][2048]
#define O_XC2   1671168                  // [8][512][2048]:
                                         //   pre-mlp: [b] first half = U2 fp32 [2048][256]
                                         //            [b] second half = V2 fp32 [2048][256] -> overwritten by XP2
                                         //   post-mlp: rows 0..255 = x_mlp [c][n]
                                         //   reused earlier: knn scratch (hilo/xx) + UV1
#define O_IDX2  10059776                 // int [8][2048][20]
#define O_IDX3  10387456                 // int [8][2048][20] (also temp home for lafe knn idx)
#define O_MLPW  10715136                 // [256][20] padded
#define O_MLPSC 10720256
#define O_MLPSH 10720512
#define O_W1P   10720768                 // W1S16 (edge1 GEMM weights, 3-split)
#define O_BN1SC 10724864
#define O_BN1SH 10724928
#define O_P1SC  10724992
#define O_P1SH  10725056
#define O_P1W   10725120                 // (spare)
#define O_P1B   10729216                 // (spare; p1_b is softmax-invariant)
#define O_W2P   10729280                 // (spare)
#define O_BN2SC 10794816
#define O_BN2SH 10795072
#define O_P2SC  10795328
#define O_P2SH  10795584
#define O_P2W   10795840                 // b2fT fp32 [84][256] (edge2 B = Wce + Wdiff, transposed)
#define O_P2B   10861376
#define O_W3P   10861632                 // REUSED: w3s ushort [512][1024] 2-split (exactly 262144 floats)
#define O_BN3SC 11123776
#define O_BN3SH 11124288
#define O_LA    11124800                 // w1[48] b1[16] w2[48] b2[16] w3[16] b3[1]
#define O_FLAG  11124960                 // int: 1 if inputs are fp32, 0 if bf16
#define O_W2B16 11125760                 // ushort A2b [256][96] bf16 (edge2 A = Wnb - Wdiff)
#define O_P2W16 11162624                 // ushort [256][256] bf16 p2w

#define O_W1S16 O_W1P                    // ushort [128][64]
#define O_W3S16 O_W3P                    // ushort [512][1024] (w3 2-split K-interleaved)
#define O_W1A3  11195392                 // ushort [3][64][192], ends 11213824

// knn scratch inside XC2 region (consumed before uv2/v2/edge2/mlp write XC2):
#define O_HILO  O_XC2
#define O_XXQ   (O_XC2 + 2097152)
#define O_UV1   (O_XC2 + 2113536)        // fp32 [8][2048][128] (U1 rows 0..63, V1 64..127)

__device__ __forceinline__ float ldin(const void* p, int i, int f32) {
    return f32 ? ((const float*)p)[i]
               : __bfloat162float(((const bf16*)p)[i]);
}

__device__ __forceinline__ ushort16_t f2bf(float v) {
    union { bf16 h; ushort16_t u; } x; x.h = __float2bfloat16(v); return x.u;
}

__device__ __forceinline__ float bfbits2f(ushort16_t u) {
    union { uint32 i; float f; } c; c.i = ((uint32)u) << 16; return c.f;
}

// ============ detect: are inputs fp32 or bf16? ============
__global__ void detect_kernel(const void* x, int* flag) {
    if (threadIdx.x == 0 && blockIdx.x == 0) {
        const unsigned short* u = (const unsigned short*)x;
        int bad = 0;
        for (int i = 0; i < 64; ++i) {
            int e = (u[i] >> 7) & 0xFF;
            if (e >= 0x86) bad++;
        }
        *flag = (bad > 0) ? 1 : 0;
    }
}

// ================= prep =================
__global__ void prep_kernel(
    const void* la_w1, const void* la_b1, const void* la_w2, const void* la_b2,
    const void* la_w3, const void* la_b3,
    const void* mlp_w, const void* mlp_b, const void* mlp_bn,
    const void* w1, const void* bn1, const void* w2, const void* bn2,
    const void* w3, const void* bn3,
    const void* p1_bn, const void* p1_w, const void* p1_b,
    const void* p2_bn, const void* p2_w, const void* p2_b,
    float* ws)
{
    const int f32 = ((const int*)ws)[O_FLAG];
    int gid = blockIdx.x * blockDim.x + threadIdx.x;
    int gsz = gridDim.x * blockDim.x;

    for (int i = gid; i < 256*20; i += gsz) {
        int o = i / 20, c = i - o*20;
        ws[O_MLPW + i] = (c < 19) ? ldin(mlp_w, o*19 + c, f32) : 0.f;
    }
    for (int c = gid; c < 256; c += gsz) {
        float g = ldin(mlp_bn, c, f32), be = ldin(mlp_bn, 256+c, f32);
        float m = ldin(mlp_bn, 512+c, f32), vv = ldin(mlp_bn, 768+c, f32);
        float s = g / sqrtf(vv + 1e-5f);
        ws[O_MLPSC + c] = s;
        ws[O_MLPSH + c] = be + (ldin(mlp_b, c, f32) - m) * s;
    }
    for (int c = gid; c < 64; c += gsz) {
        float g = ldin(bn1, c, f32), be = ldin(bn1, 64+c, f32);
        float m = ldin(bn1, 128+c, f32), vv = ldin(bn1, 192+c, f32);
        float s = g / sqrtf(vv + 1e-5f);
        ws[O_BN1SC + c] = s; ws[O_BN1SH + c] = be - m*s;
        float g2 = ldin(p1_bn, c, f32), be2 = ldin(p1_bn, 64+c, f32);
        float m2 = ldin(p1_bn, 128+c, f32), vv2 = ldin(p1_bn, 192+c, f32);
        float s2 = g2 / sqrtf(vv2 + 1e-5f);
        ws[O_P1SC + c] = s2; ws[O_P1SH + c] = be2 - m2*s2;
    }
    for (int c = gid; c < 256; c += gsz) {
        float g = ldin(bn2, c, f32), be = ldin(bn2, 256+c, f32);
        float m = ldin(bn2, 512+c, f32), vv = ldin(bn2, 768+c, f32);
        float s = g / sqrtf(vv + 1e-5f);
        ws[O_BN2SC + c] = s; ws[O_BN2SH + c] = be - m*s;
        float g2 = ldin(p2_bn, c, f32), be2 = ldin(p2_bn, 256+c, f32);
        float m2 = ldin(p2_bn, 512+c, f32), vv2 = ldin(p2_bn, 768+c, f32);
        float s2 = g2 / sqrtf(vv2 + 1e-5f);
        ws[O_P2SC + c] = s2; ws[O_P2SH + c] = be2 - m2*s2;
        ws[O_P2B + c] = ldin(p2_b, c, f32);
    }
    // w3 2-split K-interleaved: w3s[o][2c+s] = split_s(w3[o][c])
    {
        ushort16_t* w3s = (ushort16_t*)(ws + O_W3S16);
        for (int i = gid; i < 512*1024; i += gsz) {
            int o = i >> 10, kp = i & 1023;
            int c = kp >> 1, s = kp & 1;
            float v = ldin(w3, o*512 + c, f32);
            ushort16_t h = f2bf(v);
            w3s[i] = (s == 0) ? h : f2bf(v - bfbits2f(h));
        }
    }
    for (int c = gid; c < 512; c += gsz) {
        float g = ldin(bn3, c, f32), be = ldin(bn3, 512+c, f32);
        float m = ldin(bn3, 1024+c, f32), vv = ldin(bn3, 1536+c, f32);
        float s = g / sqrtf(vv + 1e-5f);
        ws[O_BN3SC + c] = s; ws[O_BN3SH + c] = be - m*s;
    }
    for (int i = gid; i < 48; i += gsz) ws[O_LA + i]       = ldin(la_w1, i, f32);
    for (int i = gid; i < 16; i += gsz) ws[O_LA + 48 + i]  = ldin(la_b1, i, f32);
    for (int i = gid; i < 48; i += gsz) ws[O_LA + 64 + i]  = ldin(la_w2, i, f32);
    for (int i = gid; i < 16; i += gsz) ws[O_LA + 112 + i] = ldin(la_b2, i, f32);
    for (int i = gid; i < 16; i += gsz) ws[O_LA + 128 + i] = ldin(la_w3, i, f32);
    if (gid == 0) ws[O_LA + 144] = ldin(la_b3, 0, f32);

    // ---- edge1 decomposition: W1split (3-split interleaved, K side) ----
    ushort16_t* w1s = (ushort16_t*)(ws + O_W1S16);
    for (int i = gid; i < 128*64; i += gsz) {
        int row = i >> 6, kp = i & 63;
        if (kp < 57) {
            int c = kp / 3, s = kp - c*3;
            int o = row & 63;
            float wnb = ldin(w1, o*57 + c, f32);
            float wce = ldin(w1, o*57 + 19 + c, f32);
            float wdf = ldin(w1, o*57 + 38 + c, f32);
            float v = (row < 64) ? (wnb - wdf) : (wce + wdf);
            ushort16_t h = f2bf(v); float r1 = v - bfbits2f(h);
            ushort16_t m = f2bf(r1); ushort16_t l = f2bf(r1 - bfbits2f(m));
            w1s[i] = (s==0) ? h : ((s==1) ? m : l);
        } else w1s[i] = 0;
    }
    ushort16_t* w1a3 = (ushort16_t*)(ws + O_W1A3);
    for (int i = gid; i < 3*64*192; i += gsz) {
        int t = i / (64*192), rem = i - t*64*192;
        int o = rem / 192, kp = rem - o*192;
        int c = kp / 3;
        float v = ldin(p1_w, o*64 + c, f32);
        ushort16_t h = f2bf(v); float r1 = v - bfbits2f(h);
        ushort16_t m = f2bf(r1); ushort16_t l = f2bf(r1 - bfbits2f(m));
        w1a3[i] = (t==0) ? h : ((t==1) ? m : l);
    }

    // edge2 decomposition
    ushort16_t* a2b = (ushort16_t*)(ws + O_W2B16);
    for (int i = gid; i < 256*96; i += gsz) {
        int row = i / 96, c = i - row*96;
        float v = (c < 83) ? (ldin(w2, row*249 + c, f32) - ldin(w2, row*249 + 166 + c, f32)) : 0.f;
        a2b[i] = f2bf(v);
    }
    float* b2fT = ws + O_P2W;
    for (int i = gid; i < 84*256; i += gsz) {
        int c = i >> 8, row = i & 255;
        b2fT[i] = (c < 83) ? (ldin(w2, row*249 + 83 + c, f32) + ldin(w2, row*249 + 166 + c, f32)) : 0.f;
    }
    ushort16_t* pwb = (ushort16_t*)(ws + O_P2W16);
    for (int i = gid; i < 256*256; i += gsz) pwb[i] = f2bf(ldin(p2_w, i, f32));
}

// ================= xconv: x -> fp32 into XMAN rows 0..2 =================
__global__ __launch_bounds__(256) void xconv_kernel(const void* x, float* ws) {
    const int f32 = ((const int*)ws)[O_FLAG];
    int gid = blockIdx.x*256 + threadIdx.x;
    int b = gid / (3*NN), r = gid - b*3*NN;
    ws[O_XMAN + b*19*NN + r] = ldin(x, gid, f32);
}

// ================= xc1copy: xman rows 0..18 -> xc1 rows 0..18 (coalesced) =====
__global__ __launch_bounds__(256) void xc1copy_kernel(float* ws) {
    int gid = blockIdx.x*256 + threadIdx.x;
    int b = gid / (19*NN), r = gid - b*19*NN;
    ws[O_XC1 + (size_t)b*83*NN + r] = ws[O_XMAN + gid];
}

// ====== 3-way bf16 split precompute (batch locked to XCD via blockIdx&7) ======
template<int C, int CS, int KP>
__global__ void hilo_kernel(const float* feat, ushort16_t* out) {
    int b  = blockIdx.x & 7;
    int lb = blockIdx.x >> 3;
    int nb = gridDim.x >> 3;
    const float* fb = feat + (size_t)b*CS*NN;
    ushort16_t* ob = out + (size_t)b*NN*KP;
    for (int i = lb*blockDim.x + threadIdx.x; i < C*NN; i += nb*blockDim.x) {
        int c = i >> 11, n = i & (NN-1);
        float v = fb[(size_t)c*NN + n];
        ushort16_t h = f2bf(v);
        float r1 = v - bfbits2f(h);
        ushort16_t m = f2bf(r1);
        ushort16_t l = f2bf(r1 - bfbits2f(m));
        size_t base = (size_t)n*KP + 3*c;
        ob[base] = h; ob[base+1] = m; ob[base+2] = l;
    }
    constexpr int PAD = KP - 3*C;
    for (int i = lb*blockDim.x + threadIdx.x; i < NN*PAD; i += nb*blockDim.x) {
        int n = i / PAD, p = i - n*PAD;
        ob[(size_t)n*KP + 3*C + p] = 0;
    }
}

// ====== exact fp32 squared norms ======
template<int C, int CS>
__global__ __launch_bounds__(256) void xx_kernel(const float* feat, float* xxg) {
    int gid = blockIdx.x*256 + threadIdx.x;
    int b = gid >> 11, n = gid & (NN-1);
    const float* fb = feat + (size_t)b*CS*NN;
    float s = 0.f;
    #pragma unroll
    for (int c = 0; c < C; ++c) { float v = fb[c*NN + n]; s += v*v; }
    xxg[gid] = s;
}

// ====== fused knn: MFMA distance tile + lazy top-3 u64-butterfly extraction ======
template<int C, int CS, int KP>
__global__ __launch_bounds__(512, 2) void knn_fused_kernel(
    const float* feat, const ushort16_t* hilo, const float* xxg, int* idxout)
{
    constexpr int KT = KP / 32;
    constexpr int ST = 2057;
    __shared__ float Dt[16 * ST];
    int tid = threadIdx.x;
    int b  = blockIdx.x & 7;
    int n0 = (blockIdx.x >> 3) << 4;
    int lane = tid & 63, wv = tid >> 6;
    int quad = lane >> 4, l15 = lane & 15;
    const float* fb = feat + (size_t)b * CS * NN;

    short8 Bh[KT], Bm[KT], Bl[KT];
    #pragma unroll
    for (int kt = 0; kt < KT; ++kt) {
        #pragma unroll
        for (int e = 0; e < 8; ++e) {
            int kp = kt*32 + quad*8 + e;
            int c = kp / 3;
            float v = (c < C) ? fb[(size_t)c*NN + n0 + l15] : 0.f;
            ushort16_t h = f2bf(v);
            float r1 = v - bfbits2f(h);
            ushort16_t m = f2bf(r1);
            ushort16_t l = f2bf(r1 - bfbits2f(m));
            Bh[kt][e] = (short)h; Bm[kt][e] = (short)m; Bl[kt][e] = (short)l;
        }
    }

    const ushort16_t* hb = hilo + (size_t)b * NN * KP;
    const float* xxb = xxg + b * NN;

    #pragma unroll
    for (int i = 0; i < 4; ++i) {
        int base = (wv*4 + i) * 64;
        floatx4 acc[4];
        #pragma unroll
        for (int st = 0; st < 4; ++st) {
            acc[st] = (floatx4){0.f,0.f,0.f,0.f};
            #pragma unroll
            for (int kt = 0; kt < KT; ++kt) {
                short8 a = *(const short8*)&hb[(size_t)(base + st*16 + l15)*KP + kt*32 + quad*8];
                acc[st] = __builtin_amdgcn_mfma_f32_16x16x32_bf16(a, Bh[kt], acc[st], 0, 0, 0);
                acc[st] = __builtin_amdgcn_mfma_f32_16x16x32_bf16(a, Bm[kt], acc[st], 0, 0, 0);
                acc[st] = __builtin_amdgcn_mfma_f32_16x16x32_bf16(a, Bl[kt], acc[st], 0, 0, 0);
            }
        }
        #pragma unroll
        for (int st = 0; st < 4; ++st) {
            #pragma unroll
            for (int r = 0; r < 4; ++r) {
                int cand = base + st*16 + quad*4 + r;
                Dt[l15*ST + cand] = 2.f*acc[st][r] - xxb[cand];
            }
        }
    }
    __syncthreads();

    int r0 = wv*2, r1 = wv*2 + 1;
    unsigned int basei = 2047u - (unsigned int)lane;
    unsigned int a0[32], a1[32];
    unsigned int dead0 = 0, dead1 = 0;
    unsigned long long p0 = 0, p1 = 0, p2 = 0;
    unsigned long long q0 = 0, q1 = 0, q2 = 0;
    #pragma unroll
    for (int j = 0; j < 32; ++j) {
        unsigned int u0 = __float_as_uint(Dt[r0*ST + j*64 + lane]);
        unsigned int u1 = __float_as_uint(Dt[r1*ST + j*64 + lane]);
        unsigned int o0 = u0 ^ (unsigned int)(((int)u0 >> 31) | 0x80000000);
        unsigned int o1 = u1 ^ (unsigned int)(((int)u1 >> 31) | 0x80000000);
        a0[j] = o0; a1[j] = o1;
        unsigned long long k0 = ((unsigned long long)o0 << 32) | (basei - j*64);
        unsigned long long k1 = ((unsigned long long)o1 << 32) | (basei - j*64);
        bool g00 = k0 > p0, g01 = k0 > p1, g02 = k0 > p2;
        p2 = g01 ? p1 : (g02 ? k0 : p2);
        p1 = g00 ? p0 : (g01 ? k0 : p1);
        p0 = g00 ? k0 : p0;
        bool g10 = k1 > q0, g11 = k1 > q1, g12 = k1 > q2;
        q2 = g11 ? q1 : (g12 ? k1 : q2);
        q1 = g10 ? q0 : (g11 ? k1 : q1);
        q0 = g10 ? k1 : q0;
    }
    int myg0 = 0, myg1 = 0;
    #pragma unroll 1
    for (int it = 0; it < KK; ++it) {
        unsigned long long b0 = p0, b1 = q0;
        #pragma unroll
        for (int sh = 1; sh < 64; sh <<= 1) {
            unsigned long long o0 = __shfl_xor(b0, sh);
            unsigned long long o1 = __shfl_xor(b1, sh);
            b0 = (o0 > b0) ? o0 : b0;
            b1 = (o1 > b1) ? o1 : b1;
        }
        if (lane == it) {
            myg0 = (int)(2047u - (unsigned int)b0);
            myg1 = (int)(2047u - (unsigned int)b1);
        }
        if (p0 == b0) {
            dead0 |= 1u << ((int)(basei - (unsigned int)b0) >> 6);
            p0 = p1; p1 = p2; p2 = 0;
        }
        if (q0 == b1) {
            dead1 |= 1u << ((int)(basei - (unsigned int)b1) >> 6);
            q0 = q1; q1 = q2; q2 = 0;
        }
        if (__any((p0 == 0ull) | (q0 == 0ull))) {
            if (p0 == 0ull) {
                unsigned long long t0 = 0, t1 = 0, t2 = 0;
                #pragma unroll
                for (int j = 0; j < 32; ++j) {
                    unsigned long long k = ((dead0 >> j) & 1u) ? 0ull
                        : (((unsigned long long)a0[j] << 32) | (basei - j*64));
                    bool g0 = k > t0, g1 = k > t1, g2 = k > t2;
                    t2 = g1 ? t1 : (g2 ? k : t2);
                    t1 = g0 ? t0 : (g1 ? k : t1);
                    t0 = g0 ? k : t0;
                }
                p0 = t0; p1 = t1; p2 = t2;
            }
            if (q0 == 0ull) {
                unsigned long long t0 = 0, t1 = 0, t2 = 0;
                #pragma unroll
                for (int j = 0; j < 32; ++j) {
                    unsigned long long k = ((dead1 >> j) & 1u) ? 0ull
                        : (((unsigned long long)a1[j] << 32) | (basei - j*64));
                    bool g0 = k > t0, g1 = k > t1, g2 = k > t2;
                    t2 = g1 ? t1 : (g2 ? k : t2);
                    t1 = g0 ? t0 : (g1 ? k : t1);
                    t0 = g0 ? k : t0;
                }
                q0 = t0; q1 = t1; q2 = t2;
            }
        }
    }
    if (lane < KK) {
        idxout[((size_t)(b*NN + n0 + r0))*KK + lane] = myg0;
        idxout[((size_t)(b*NN + n0 + r1))*KK + lane] = myg1;
    }
}

// ================= lafe attention (post-knn) =================
__global__ __launch_bounds__(256, 1) void lafe_att_kernel(float* ws, const int* idx) {
    __shared__ float xs0[NN], xs1[NN], xs2[NN];
    int tid = threadIdx.x;
    int b = blockIdx.x >> 3;
    int n = ((blockIdx.x & 7) << 8) + tid;
    float* xm = ws + O_XMAN + b*19*NN;
    for (int i = tid; i < NN; i += 256) {
        xs0[i] = xm[i]; xs1[i] = xm[NN + i]; xs2[i] = xm[2*NN + i];
    }
    __syncthreads();
    float a0 = xs0[n], a1 = xs1[n], a2 = xs2[n];
    int ti[KK];
    #pragma unroll
    for (int k = 0; k < KK; ++k) ti[k] = idx[(b*NN + n)*KK + k] & (NN-1);
    const float* wl = ws + O_LA;
    float sa = wl[144];
    #pragma unroll
    for (int o = 0; o < 16; ++o) {
        float nf = wl[o*3+0]*a0 + wl[o*3+1]*a1 + wl[o*3+2]*a2 + wl[48+o];
        sa += wl[128+o]*nf;
    }
    float lg[KK]; float mx = -3.0e38f;
    #pragma unroll
    for (int k = 0; k < KK; ++k) {
        int m = ti[k];
        float d0 = a0 - xs0[m], d1 = a1 - xs1[m], d2 = a2 - xs2[m];
        float na = wl[144];
        #pragma unroll
        for (int o = 0; o < 16; ++o) {
            float ef = wl[64+o*3+0]*d0 + wl[64+o*3+1]*d1 + wl[64+o*3+2]*d2 + wl[112+o];
            na += wl[128+o]*ef;
        }
        float t = sa + na;
        t = t > 0.f ? t : 0.01f*t;
        lg[k] = t; mx = fmaxf(mx, t);
    }
    float ssum = 0.f;
    #pragma unroll
    for (int k = 0; k < KK; ++k) { lg[k] = expf(lg[k] - mx); ssum += lg[k]; }
    float vals[16];
    #pragma unroll
    for (int o = 0; o < 16; ++o) vals[o] = 0.f;
    #pragma unroll
    for (int k = 0; k < KK; ++k) {
        float coef = lg[k] / ssum;
        int m = ti[k];
        float d0 = a0 - xs0[m], d1 = a1 - xs1[m], d2 = a2 - xs2[m];
        #pragma unroll
        for (int o = 0; o < 16; ++o) {
            float ef = wl[64+o*3+0]*d0 + wl[64+o*3+1]*d1 + wl[64+o*3+2]*d2 + wl[112+o];
            vals[o] += coef * ef;
        }
    }
    #pragma unroll
    for (int o = 0; o < 16; ++o) {
        float v = vals[o];
        xm[(3+o)*NN + n] = v > 0.f ? v : expm1f(v);
    }
}

// ================= mlp (batch = blockIdx&7) =================
__global__ void mlp_kernel(float* ws) {
    __shared__ __align__(16) float xv[20];
    int tid = threadIdx.x;
    int b = blockIdx.x & 7, n = blockIdx.x >> 3;
    if (tid < 20) xv[tid] = (tid < 19) ? ws[O_XMAN + b*19*NN + tid*NN + n] : 0.f;
    __syncthreads();
    const float* mw = ws + O_MLPW;
    float acc = 0.f;
    #pragma unroll
    for (int c4 = 0; c4 < 5; ++c4) {
        float4 w = *(const float4*)&mw[tid*20 + c4*4];
        float4 g = *(const float4*)&xv[c4*4];
        acc += w.x*g.x + w.y*g.y + w.z*g.z + w.w*g.w;
    }
    float v = acc * ws[O_MLPSC + tid] + ws[O_MLPSH + tid];
    ws[O_XC2 + b*512*NN + tid*NN + n] = fmaxf(v, 0.f);
}

// ====== uv1: [U1;V1][n][128] = [A1;B1] @ xman via exact 3-split MFMA ======
__global__ __launch_bounds__(256, 2) void uv1_kernel(float* ws) {
    __shared__ float xt[19*64];
    int tid = threadIdx.x;
    int b = blockIdx.x & 7;
    int pn0 = (blockIdx.x >> 3) << 6;
    const float* fb = ws + O_XMAN + (size_t)b*19*NN;
    for (int i = tid; i < 19*64; i += 256) {
        int c = i >> 6, j = i & 63;
        xt[i] = fb[(size_t)c*NN + pn0 + j];
    }
    __syncthreads();
    int lane = tid & 63, wv = tid >> 6;
    int quad = lane >> 4, l15 = lane & 15;

    short8 X[3][4][2];
    #pragma unroll
    for (int nt = 0; nt < 4; ++nt) {
        int pt = nt*16 + l15;
        #pragma unroll
        for (int kt = 0; kt < 2; ++kt) {
            #pragma unroll
            for (int e = 0; e < 8; ++e) {
                int kp = kt*32 + quad*8 + e;
                int c = kp / 3;
                float v = (c < 19) ? xt[c*64 + pt] : 0.f;
                ushort16_t h = f2bf(v); float r1 = v - bfbits2f(h);
                ushort16_t m = f2bf(r1); ushort16_t l = f2bf(r1 - bfbits2f(m));
                X[0][nt][kt][e] = (short)h;
                X[1][nt][kt][e] = (short)m;
                X[2][nt][kt][e] = (short)l;
            }
        }
    }
    const ushort16_t* w1s = (const ushort16_t*)(ws + O_W1S16);
    floatx4 acc[2][4];
    #pragma unroll
    for (int rt = 0; rt < 2; ++rt)
        #pragma unroll
        for (int nt = 0; nt < 4; ++nt) acc[rt][nt] = (floatx4){0.f,0.f,0.f,0.f};
    #pragma unroll
    for (int pass = 0; pass < 3; ++pass) {
        #pragma unroll
        for (int kt = 0; kt < 2; ++kt) {
            int c0 = kt*32 + quad*8;
            short8 a[2];
            a[0] = *(const short8*)&w1s[(wv*32 + l15)*64 + c0];
            a[1] = *(const short8*)&w1s[(wv*32 + 16 + l15)*64 + c0];
            #pragma unroll
            for (int rt = 0; rt < 2; ++rt)
                #pragma unroll
                for (int nt = 0; nt < 4; ++nt)
                    acc[rt][nt] = __builtin_amdgcn_mfma_f32_16x16x32_bf16(a[rt], X[pass][nt][kt], acc[rt][nt], 0, 0, 0);
        }
    }
    float* uv1 = ws + O_UV1 + (size_t)b*NN*128;
    #pragma unroll
    for (int rt = 0; rt < 2; ++rt)
        #pragma unroll
        for (int nt = 0; nt < 4; ++nt) {
            int n = pn0 + nt*16 + l15;
            int r = wv*32 + rt*16 + quad*4;
            *(float4*)&uv1[(size_t)n*128 + r] =
                make_float4(acc[rt][nt][0], acc[rt][nt][1], acc[rt][nt][2], acc[rt][nt][3]);
        }
}

// ================= edge1 v2: U1/V1 gather + exact 3-split att GEMM =================
__global__ __launch_bounds__(256, 2) void edge1_kernel(float* ws, const int* idx) {
    constexpr int SW = 204;
    constexpr int ST = 65;
    __shared__ __align__(16) ushort16_t hrS[80*SW];
    __shared__ __align__(16) float attL[80*ST];
    __shared__ float vL[4*64];
    __shared__ float scalL[256];
    __shared__ float outL[64*5];
    __shared__ int idxL[80];

    int tid = threadIdx.x;
    int b  = blockIdx.x & 7;
    int n0 = (blockIdx.x >> 3) << 2;
    const float* uv1 = ws + O_UV1 + (size_t)b*NN*128;

    {
        int grp = tid >> 6, r6 = tid & 63;
        int off = grp==0 ? O_BN1SC : grp==1 ? O_BN1SH : grp==2 ? O_P1SC : O_P1SH;
        scalL[tid] = ws[off + r6];
        vL[tid] = uv1[(size_t)(n0 + grp)*128 + 64 + r6];
    }
    if (tid < 80) idxL[tid] = idx[(b*NN + n0 + tid/20)*KK + (tid%20)] & (NN-1);
    __syncthreads();

    {
        int rw = tid & 63, cg = tid >> 6;
        float s1 = scalL[rw], sh1 = scalL[64+rw], ps = scalL[128+rw], ph = scalL[192+rw];
        #pragma unroll 5
        for (int it = 0; it < 20; ++it) {
            int col = it*4 + cg;
            int p = col / 20;
            int j = idxL[col];
            float u = uv1[(size_t)j*128 + rw];
            float h1 = (u + vL[p*64+rw])*s1 + sh1;
            h1 = h1 > 0.f ? h1 : 0.2f*h1;
            float hv = h1*ps + ph;
            hv = hv > 0.f ? hv : 0.f;
            ushort16_t h = f2bf(hv); float r1 = hv - bfbits2f(h);
            ushort16_t m = f2bf(r1); ushort16_t l = f2bf(r1 - bfbits2f(m));
            hrS[col*SW + 3*rw + 0] = h;
            hrS[col*SW + 3*rw + 1] = m;
            hrS[col*SW + 3*rw + 2] = l;
        }
    }
    __syncthreads();

    int lane = tid & 63, wv = tid >> 6;
    int quad = lane >> 4, l15 = lane & 15;
    const ushort16_t* w1a3 = (const ushort16_t*)(ws + O_W1A3);
    floatx4 acc[5];
    #pragma unroll
    for (int mt = 0; mt < 5; ++mt) acc[mt] = (floatx4){0.f,0.f,0.f,0.f};
    #pragma unroll
    for (int pass = 0; pass < 3; ++pass) {
        #pragma unroll
        for (int kt = 0; kt < 6; ++kt) {
            int c0 = kt*32 + quad*8;
            short8 bfrag = *(const short8*)&w1a3[((size_t)pass*64 + wv*16 + l15)*192 + c0];
            #pragma unroll
            for (int mt = 0; mt < 5; ++mt) {
                short8 afrag = *(const short8*)&hrS[(mt*16 + l15)*SW + c0];
                acc[mt] = __builtin_amdgcn_mfma_f32_16x16x32_bf16(afrag, bfrag, acc[mt], 0, 0, 0);
            }
        }
    }
    #pragma unroll
    for (int mt = 0; mt < 5; ++mt)
        #pragma unroll
        for (int r = 0; r < 4; ++r)
            attL[(mt*16 + quad*4 + r)*ST + wv*16 + l15] = acc[mt][r];
    __syncthreads();

    {
        int o = tid & 63, p = tid >> 6;
        float av[KK]; float mx = -3.0e38f;
        #pragma unroll
        for (int k = 0; k < KK; ++k) { av[k] = attL[(p*20 + k)*ST + o]; mx = fmaxf(mx, av[k]); }
        float ssum = 0.f;
        #pragma unroll
        for (int k = 0; k < KK; ++k) { av[k] = expf(av[k] - mx); ssum += av[k]; }
        float inv = 1.f / ssum;
        float s1o = scalL[o], sh1o = scalL[64+o], vpo = vL[p*64+o];
        float sacc = 0.f;
        #pragma unroll
        for (int k = 0; k < KK; ++k) {
            int j = idxL[p*20 + k];
            float u = uv1[(size_t)j*128 + o];
            float h1 = (u + vpo)*s1o + sh1o;
            h1 = h1 > 0.f ? h1 : 0.2f*h1;
            sacc += av[k]*inv*h1;
        }
        outL[o*5 + p] = sacc;
    }
    __syncthreads();
    {
        int o = tid >> 2, p = tid & 3;
        ws[O_XC1 + (size_t)b*83*NN + (size_t)(19+o)*NN + n0 + p] = outL[o*5 + p];
    }
}

// ====== uv2: U2[b][n][r] = sum_c A2[r][c] * xc1[b][c][n] (batch = blockIdx&7) ======
__global__ __launch_bounds__(256, 2) void uv2_kernel(float* ws) {
    constexpr int XS = 108;
    __shared__ ushort16_t xt[64*XS];
    int tid = threadIdx.x;
    int b = blockIdx.x & 7;
    int pn0 = (blockIdx.x >> 3) << 6;
    const float* xc1 = ws + O_XC1 + (size_t)b*83*NN;
    for (int i = tid; i < 96*64; i += 256) {
        int c = i >> 6, j = i & 63;
        xt[j*XS + c] = (c < 83) ? f2bf(xc1[c*NN + pn0 + j]) : (ushort16_t)0;
    }
    __syncthreads();
    int lane = tid & 63, wv = tid >> 6;
    int quad = lane >> 4, l15 = lane & 15;
    const ushort16_t* a2b = (const ushort16_t*)(ws + O_W2B16);
    floatx4 acc[4][4];
    #pragma unroll
    for (int rt = 0; rt < 4; ++rt)
        #pragma unroll
        for (int nt = 0; nt < 4; ++nt) acc[rt][nt] = (floatx4){0.f,0.f,0.f,0.f};
    #pragma unroll
    for (int kt = 0; kt < 3; ++kt) {
        int c0 = kt*32 + quad*8;
        short8 bfr[4], a[4];
        #pragma unroll
        for (int nt = 0; nt < 4; ++nt)
            bfr[nt] = *(const short8*)&xt[(nt*16 + l15)*XS + c0];
        #pragma unroll
        for (int rt = 0; rt < 4; ++rt)
            a[rt] = *(const short8*)&a2b[(wv*64 + rt*16 + l15)*96 + c0];
        #pragma unroll
        for (int rt = 0; rt < 4; ++rt)
            #pragma unroll
            for (int nt = 0; nt < 4; ++nt)
                acc[rt][nt] = __builtin_amdgcn_mfma_f32_16x16x32_bf16(a[rt], bfr[nt], acc[rt][nt], 0, 0, 0);
    }
    float* U2 = ws + O_XC2 + (size_t)b*512*NN;
    #pragma unroll
    for (int rt = 0; rt < 4; ++rt)
        #pragma unroll
        for (int nt = 0; nt < 4; ++nt) {
            int n = pn0 + nt*16 + l15;
            int r = wv*64 + rt*16 + quad*4;
            *(float4*)&U2[(size_t)n*256 + r] =
                make_float4(acc[rt][nt][0], acc[rt][nt][1], acc[rt][nt][2], acc[rt][nt][3]);
        }
}

// ====== v2: V2[b][n][r] = sum_c b2fT[c][r] * xc1[b][c][n], exact fp32, point-major ======
__global__ __launch_bounds__(256, 4) void v2_kernel(float* ws) {
    __shared__ float xs[83*16];
    int tid = threadIdx.x;
    int b = blockIdx.x & 7;
    int pn0 = (blockIdx.x >> 3) << 4;
    const float* xc1 = ws + O_XC1 + (size_t)b*83*NN;
    for (int i = tid; i < 83*16; i += 256) {
        int c = i >> 4, j = i & 15;
        xs[i] = xc1[(size_t)c*NN + pn0 + j];
    }
    __syncthreads();
    const float* b2fT = ws + O_P2W;
    float acc[16];
    #pragma unroll
    for (int j = 0; j < 16; ++j) acc[j] = 0.f;
    #pragma unroll 4
    for (int c = 0; c < 83; ++c) {
        float w = b2fT[c*256 + tid];
        #pragma unroll
        for (int j = 0; j < 16; ++j) acc[j] += w * xs[c*16 + j];
    }
    float* V2 = ws + O_XC2 + (size_t)b*512*NN + (size_t)256*NN;
    #pragma unroll
    for (int j = 0; j < 16; ++j) V2[(size_t)(pn0 + j)*256 + tid] = acc[j];
}

// ================= edge2 v3: 2 points/block, V precomputed, h2 reg-cached =================
__global__ __launch_bounds__(256, 2) void edge2_kernel(float* ws, const int* idx) {
    constexpr int HS = 268;
    __shared__ __align__(16) ushort16_t hrb[48*HS];
    __shared__ __align__(16) float attL[256*41];
    __shared__ float p2bL[256];
    __shared__ int idxL[40];

    int tid = threadIdx.x;
    int b  = blockIdx.x & 7;
    int n0 = (blockIdx.x >> 3) << 1;

    const float* U2 = ws + O_XC2 + (size_t)b*512*NN;
    float* V2 = ws + O_XC2 + (size_t)b*512*NN + (size_t)256*NN;

    float sc = ws[O_BN2SC + tid], sh = ws[O_BN2SH + tid];
    float ps = ws[O_P2SC + tid],  ph = ws[O_P2SH + tid];
    p2bL[tid] = ws[O_P2B + tid];
    float v0 = V2[(size_t)n0*256 + tid];
    float v1 = V2[(size_t)(n0+1)*256 + tid];
    if (tid < 40) idxL[tid] = idx[(b*NN + n0 + tid/20)*KK + (tid%20)] & (NN-1);
    __syncthreads();

    float h2r[40];
    #pragma unroll
    for (int col = 0; col < 40; ++col) {
        int j = idxL[col];
        float u = U2[(size_t)j*256 + tid];
        float h2 = (u + (col >= 20 ? v1 : v0))*sc + sh;
        h2 = h2 > 0.f ? h2 : 0.2f*h2;
        h2r[col] = h2;
        float hv = h2*ps + ph;
        hrb[col*HS + tid] = f2bf(fmaxf(hv, 0.f));
    }
    __syncthreads();

    int lane = tid & 63, wv = tid >> 6;
    int quad = lane >> 4, l15 = lane & 15;
    const ushort16_t* p2wb = (const ushort16_t*)(ws + O_P2W16);
    floatx4 acc2[4][3];
    #pragma unroll
    for (int mt = 0; mt < 4; ++mt)
        #pragma unroll
        for (int nt = 0; nt < 3; ++nt) acc2[mt][nt] = (floatx4){0.f,0.f,0.f,0.f};
    for (int kt = 0; kt < 8; ++kt) {
        int c0 = kt*32 + quad*8;
        short8 a[4], bb3[3];
        #pragma unroll
        for (int mt = 0; mt < 4; ++mt)
            a[mt] = *(const short8*)&p2wb[(wv*64 + mt*16 + l15)*256 + c0];
        #pragma unroll
        for (int nt = 0; nt < 3; ++nt)
            bb3[nt] = *(const short8*)&hrb[(nt*16 + l15)*HS + c0];
        #pragma unroll
        for (int mt = 0; mt < 4; ++mt)
            #pragma unroll
            for (int nt = 0; nt < 3; ++nt)
                acc2[mt][nt] = __builtin_amdgcn_mfma_f32_16x16x32_bf16(a[mt], bb3[nt], acc2[mt][nt], 0, 0, 0);
    }
    #pragma unroll
    for (int mt = 0; mt < 4; ++mt) {
        int k0 = wv*64 + mt*16 + quad*4;
        #pragma unroll
        for (int nt = 0; nt < 3; ++nt) {
            int col = nt*16 + l15;
            if (col < 40) {
                #pragma unroll
                for (int r = 0; r < 4; ++r)
                    attL[(k0 + r)*41 + col] = acc2[mt][nt][r] + p2bL[k0 + r];
            }
        }
    }
    __syncthreads();

    #pragma unroll
    for (int p = 0; p < 2; ++p) {
        float av[KK]; float mx = -3.0e38f;
        #pragma unroll
        for (int k = 0; k < KK; ++k) { av[k] = attL[tid*41 + p*20 + k]; mx = fmaxf(mx, av[k]); }
        float ssum = 0.f;
        #pragma unroll
        for (int k = 0; k < KK; ++k) { av[k] = expf(av[k] - mx); ssum += av[k]; }
        float inv = 1.f / ssum;
        float sacc = 0.f;
        #pragma unroll
        for (int k = 0; k < KK; ++k) sacc += av[k] * inv * h2r[p*20 + k];
        V2[(size_t)(n0 + p)*256 + tid] = sacc;
    }
}

// ================= final (MFMA, 2-split x 2-split exact-enough) =================
// out = lrelu(bn3(w3 @ x_c2)); w3 2-split K-interleaved (w3s), x_c2 2-split dup passes.
__global__ __launch_bounds__(512, 1) void final_kernel(const float* ws, float* out) {
    __shared__ __align__(16) uint32 smem[17408];      // 69,632 B union
    __shared__ float s3L[512], q3L[512];
    uint32* xh32 = smem;                              // [64][132]
    uint32* xm32 = smem + 8448;                       // [64][132]
    float*  outF = (float*)smem;                      // [256][68]

    int tid = threadIdx.x;
    int b = blockIdx.x & 7;
    int pn0 = (blockIdx.x >> 3) << 6;                 // 64 points/block, 32 groups/batch
    int lane = tid & 63, wv = tid >> 6;               // 8 waves
    int quad = lane >> 4, l15 = lane & 15;
    if (tid < 512) { s3L[tid] = ws[O_BN3SC + tid]; q3L[tid] = ws[O_BN3SH + tid]; }

    const float* xc2 = ws + O_XC2 + (size_t)b*512*NN; // x_mlp [c][n]
    const float* xp2 = xc2 + (size_t)256*NN;          // xp2 [n][256]
    const ushort16_t* w3s = (const ushort16_t*)(ws + O_W3S16);
    int r0 = wv*64;

    floatx4 acc[4][4];
    #pragma unroll
    for (int mt = 0; mt < 4; ++mt)
        #pragma unroll
        for (int nt = 0; nt < 4; ++nt) acc[mt][nt] = (floatx4){0.f,0.f,0.f,0.f};

    for (int ch = 0; ch < 4; ++ch) {
        __syncthreads();
        if (ch < 2) {   // channels 0..255: x_mlp channel-major (coalesce along n)
            int gc0 = ch*128;
            #pragma unroll 4
            for (int it = 0; it < 16; ++it) {
                int idx = it*512 + tid;
                int cl = idx >> 6, n = idx & 63;
                float v = xc2[(size_t)(gc0+cl)*NN + pn0 + n];
                ushort16_t h = f2bf(v);
                ushort16_t m = f2bf(v - bfbits2f(h));
                xh32[n*132 + cl] = (uint32)h * 0x10001u;
                xm32[n*132 + cl] = (uint32)m * 0x10001u;
            }
        } else {        // channels 256..511: xp2 point-major (coalesce along c)
            int gco = (ch-2)*128;
            #pragma unroll 4
            for (int it = 0; it < 16; ++it) {
                int idx = it*512 + tid;
                int n = idx >> 7, cl = idx & 127;
                float v = xp2[(size_t)(pn0+n)*256 + gco + cl];
                ushort16_t h = f2bf(v);
                ushort16_t m = f2bf(v - bfbits2f(h));
                xh32[n*132 + cl] = (uint32)h * 0x10001u;
                xm32[n*132 + cl] = (uint32)m * 0x10001u;
            }
        }
        __syncthreads();
        const ushort16_t* ph = (const ushort16_t*)xh32;
        const ushort16_t* pm = (const ushort16_t*)xm32;
        #pragma unroll
        for (int kt = 0; kt < 8; ++kt) {
            int c0k = kt*32 + quad*8;
            short8 a[4], bh[4], bm[4];
            #pragma unroll
            for (int mt = 0; mt < 4; ++mt)
                a[mt] = *(const short8*)&w3s[(size_t)(r0 + mt*16 + l15)*1024 + ch*256 + c0k];
            #pragma unroll
            for (int nt = 0; nt < 4; ++nt) {
                bh[nt] = *(const short8*)&ph[(nt*16 + l15)*264 + c0k];
                bm[nt] = *(const short8*)&pm[(nt*16 + l15)*264 + c0k];
            }
            #pragma unroll
            for (int mt = 0; mt < 4; ++mt)
                #pragma unroll
                for (int nt = 0; nt < 4; ++nt) {
                    acc[mt][nt] = __builtin_amdgcn_mfma_f32_16x16x32_bf16(a[mt], bh[nt], acc[mt][nt], 0, 0, 0);
                    acc[mt][nt] = __builtin_amdgcn_mfma_f32_16x16x32_bf16(a[mt], bm[nt], acc[mt][nt], 0, 0, 0);
                }
        }
    }

    // epilogue: bn3 + lrelu in-register, stage rows through LDS in two halves, coalesced stores
    float* ob = out + (size_t)b*512*NN;
    #pragma unroll
    for (int half = 0; half < 2; ++half) {
        __syncthreads();
        if ((wv >> 2) == half) {
            int rb = r0 - half*256;
            #pragma unroll
            for (int mt = 0; mt < 4; ++mt)
                #pragma unroll
                for (int nt = 0; nt < 4; ++nt)
                    #pragma unroll
                    for (int r = 0; r < 4; ++r) {
                        int row = r0 + mt*16 + quad*4 + r;
                        float v = acc[mt][nt][r]*s3L[row] + q3L[row];
                        v = v > 0.f ? v : 0.2f*v;
                        outF[(rb + mt*16 + quad*4 + r)*68 + nt*16 + l15] = v;
                    }
        }
        __syncthreads();
        #pragma unroll
        for (int it = 0; it < 8; ++it) {
            int idx = it*512 + tid;
            int row = idx >> 4, f4 = idx & 15;
            float4 v = *(const float4*)&outF[row*68 + f4*4];
            *(float4*)&ob[(size_t)(half*256 + row)*NN + pn0 + f4*4] = v;
        }
    }
}

extern "C" void kernel_launch(void* const* d_in, const int* in_sizes, int n_in,
                              void* d_out, int out_size, void* d_ws, size_t ws_size,
                              hipStream_t stream) {
    float* ws = (float*)d_ws;
    float* out = (float*)d_out;
    ushort16_t* hilo = (ushort16_t*)(ws + O_HILO);
    float* xxq = ws + O_XXQ;

    detect_kernel<<<1, 64, 0, stream>>>(d_in[0], (int*)ws + O_FLAG);
    prep_kernel<<<64, 256, 0, stream>>>(d_in[1], d_in[2], d_in[3], d_in[4], d_in[5], d_in[6],
                                        d_in[7], d_in[8], d_in[9], d_in[10], d_in[11], d_in[12],
                                        d_in[13], d_in[14], d_in[15], d_in[16], d_in[17], d_in[18],
                                        d_in[19], d_in[20], d_in[21], ws);
    // lafe = xconv + knn3 (fused MFMA+select) + attention
    xconv_kernel<<<192, 256, 0, stream>>>(d_in[0], ws);
    hilo_kernel<3, 19, 32><<<256, 256, 0, stream>>>(ws + O_XMAN, hilo);
    xx_kernel<3, 19><<<64, 256, 0, stream>>>(ws + O_XMAN, xxq);
    knn_fused_kernel<3, 19, 32><<<1024, 512, 0, stream>>>(ws + O_XMAN, hilo, xxq, (int*)(ws + O_IDX3));
    lafe_att_kernel<<<64, 256, 0, stream>>>(ws, (const int*)(ws + O_IDX3));
    xc1copy_kernel<<<1216, 256, 0, stream>>>(ws);
    // knn on x_manet (C=19)
    hilo_kernel<19, 19, 64><<<1024, 256, 0, stream>>>(ws + O_XMAN, hilo);
    xx_kernel<19, 19><<<64, 256, 0, stream>>>(ws + O_XMAN, xxq);
    knn_fused_kernel<19, 19, 64><<<1024, 512, 0, stream>>>(ws + O_XMAN, hilo, xxq, (int*)(ws + O_IDX2));
    // edge1 via exact A/B decomposition
    uv1_kernel<<<256, 256, 0, stream>>>(ws);
    edge1_kernel<<<BB*512, 256, 0, stream>>>(ws, (const int*)(ws + O_IDX2));
    // knn on x_c1 (C=83)
    hilo_kernel<83, 83, 256><<<2048, 256, 0, stream>>>(ws + O_XC1, hilo);
    xx_kernel<83, 83><<<64, 256, 0, stream>>>(ws + O_XC1, xxq);
    knn_fused_kernel<83, 83, 256><<<1024, 512, 0, stream>>>(ws + O_XC1, hilo, xxq, (int*)(ws + O_IDX3));
    // edge2 via A/B decomposition: U2 (MFMA) + V2 (exact fp32 dense), then fused gather kernel
    uv2_kernel<<<256, 256, 0, stream>>>(ws);
    v2_kernel<<<1024, 256, 0, stream>>>(ws);
    edge2_kernel<<<BB*1024, 256, 0, stream>>>(ws, (const int*)(ws + O_IDX3));
    mlp_kernel<<<BB*NN, 256, 0, stream>>>(ws);
    final_kernel<<<256, 512, 0, stream>>>(ws, out);
}

// Round 9
// 977.233 us; speedup vs baseline: 1.9326x; 1.0317x over previous
//
#include <hip/hip_runtime.h>
#include <hip/hip_bf16.h>
#include <math.h>

typedef __hip_bfloat16 bf16;
typedef unsigned short ushort16_t;
typedef unsigned int uint32;
typedef __attribute__((ext_vector_type(8))) short short8;
typedef __attribute__((ext_vector_type(4))) float floatx4;

#define BB 8
#define NN 2048
#define KK 20

// ---- workspace layout (float offsets) ----
#define O_XMAN  0                        // [8][19][2048]  rows 0..2 = x (fp32), rows 3..18 = lafe out
#define O_XC1   311296                   // [8][83][2048]
#define O_XC2   1671168                  // [8][512][2048]:
                                         //   pre-mlp: [b] first half = U2 fp32 [2048][256]
                                         //            [b] second half = V2 fp32 [2048][256] -> overwritten by XP2
                                         //   post-mlp: rows 0..255 = x_mlp [c][n]
                                         //   reused earlier: knn scratch (hilo/xx) + UV1
#define O_IDX2  10059776                 // int [8][2048][20]
#define O_IDX3  10387456                 // int [8][2048][20] (also temp home for lafe knn idx)
#define O_MLPW  10715136                 // [256][20] padded
#define O_MLPSC 10720256
#define O_MLPSH 10720512
#define O_W1P   10720768                 // W1S16 (edge1 GEMM weights, 3-split)
#define O_BN1SC 10724864
#define O_BN1SH 10724928
#define O_P1SC  10724992
#define O_P1SH  10725056
#define O_P1W   10725120                 // (spare)
#define O_P1B   10729216                 // (spare; p1_b is softmax-invariant)
#define O_W2P   10729280                 // (spare)
#define O_BN2SC 10794816
#define O_BN2SH 10795072
#define O_P2SC  10795328
#define O_P2SH  10795584
#define O_P2W   10795840                 // b2fT fp32 [84][256] (edge2 B = Wce + Wdiff, transposed)
#define O_P2B   10861376
#define O_W3P   10861632                 // REUSED: w3s ushort [512][1024] 2-split (exactly 262144 floats)
#define O_BN3SC 11123776
#define O_BN3SH 11124288
#define O_LA    11124800                 // w1[48] b1[16] w2[48] b2[16] w3[16] b3[1]
#define O_FLAG  11124960                 // int: 1 if inputs are fp32, 0 if bf16
#define O_W2B16 11125760                 // ushort A2b [256][96] bf16 (edge2 A = Wnb - Wdiff)
#define O_P2W16 11162624                 // ushort [256][256] bf16 p2w

#define O_W1S16 O_W1P                    // ushort [128][64]
#define O_W3S16 O_W3P                    // ushort [512][1024] (w3 2-split K-interleaved)
#define O_W1A3  11195392                 // ushort [3][64][192], ends 11213824

// knn scratch inside XC2 region (consumed before uv2/v2/edge2/mlp write XC2):
#define O_HILO  O_XC2
#define O_XXQ   (O_XC2 + 2097152)
#define O_UV1   (O_XC2 + 2113536)        // fp32 [8][2048][128] (U1 rows 0..63, V1 64..127)

__device__ __forceinline__ float ldin(const void* p, int i, int f32) {
    return f32 ? ((const float*)p)[i]
               : __bfloat162float(((const bf16*)p)[i]);
}

__device__ __forceinline__ ushort16_t f2bf(float v) {
    union { bf16 h; ushort16_t u; } x; x.h = __float2bfloat16(v); return x.u;
}

__device__ __forceinline__ float bfbits2f(ushort16_t u) {
    union { uint32 i; float f; } c; c.i = ((uint32)u) << 16; return c.f;
}

// ============ detect: are inputs fp32 or bf16? ============
__global__ void detect_kernel(const void* x, int* flag) {
    if (threadIdx.x == 0 && blockIdx.x == 0) {
        const unsigned short* u = (const unsigned short*)x;
        int bad = 0;
        for (int i = 0; i < 64; ++i) {
            int e = (u[i] >> 7) & 0xFF;
            if (e >= 0x86) bad++;
        }
        *flag = (bad > 0) ? 1 : 0;
    }
}

// ================= prep =================
__global__ void prep_kernel(
    const void* la_w1, const void* la_b1, const void* la_w2, const void* la_b2,
    const void* la_w3, const void* la_b3,
    const void* mlp_w, const void* mlp_b, const void* mlp_bn,
    const void* w1, const void* bn1, const void* w2, const void* bn2,
    const void* w3, const void* bn3,
    const void* p1_bn, const void* p1_w, const void* p1_b,
    const void* p2_bn, const void* p2_w, const void* p2_b,
    float* ws)
{
    const int f32 = ((const int*)ws)[O_FLAG];
    int gid = blockIdx.x * blockDim.x + threadIdx.x;
    int gsz = gridDim.x * blockDim.x;

    for (int i = gid; i < 256*20; i += gsz) {
        int o = i / 20, c = i - o*20;
        ws[O_MLPW + i] = (c < 19) ? ldin(mlp_w, o*19 + c, f32) : 0.f;
    }
    for (int c = gid; c < 256; c += gsz) {
        float g = ldin(mlp_bn, c, f32), be = ldin(mlp_bn, 256+c, f32);
        float m = ldin(mlp_bn, 512+c, f32), vv = ldin(mlp_bn, 768+c, f32);
        float s = g / sqrtf(vv + 1e-5f);
        ws[O_MLPSC + c] = s;
        ws[O_MLPSH + c] = be + (ldin(mlp_b, c, f32) - m) * s;
    }
    for (int c = gid; c < 64; c += gsz) {
        float g = ldin(bn1, c, f32), be = ldin(bn1, 64+c, f32);
        float m = ldin(bn1, 128+c, f32), vv = ldin(bn1, 192+c, f32);
        float s = g / sqrtf(vv + 1e-5f);
        ws[O_BN1SC + c] = s; ws[O_BN1SH + c] = be - m*s;
        float g2 = ldin(p1_bn, c, f32), be2 = ldin(p1_bn, 64+c, f32);
        float m2 = ldin(p1_bn, 128+c, f32), vv2 = ldin(p1_bn, 192+c, f32);
        float s2 = g2 / sqrtf(vv2 + 1e-5f);
        ws[O_P1SC + c] = s2; ws[O_P1SH + c] = be2 - m2*s2;
    }
    for (int c = gid; c < 256; c += gsz) {
        float g = ldin(bn2, c, f32), be = ldin(bn2, 256+c, f32);
        float m = ldin(bn2, 512+c, f32), vv = ldin(bn2, 768+c, f32);
        float s = g / sqrtf(vv + 1e-5f);
        ws[O_BN2SC + c] = s; ws[O_BN2SH + c] = be - m*s;
        float g2 = ldin(p2_bn, c, f32), be2 = ldin(p2_bn, 256+c, f32);
        float m2 = ldin(p2_bn, 512+c, f32), vv2 = ldin(p2_bn, 768+c, f32);
        float s2 = g2 / sqrtf(vv2 + 1e-5f);
        ws[O_P2SC + c] = s2; ws[O_P2SH + c] = be2 - m2*s2;
        ws[O_P2B + c] = ldin(p2_b, c, f32);
    }
    // w3 2-split K-interleaved: w3s[o][2c+s] = split_s(w3[o][c])
    {
        ushort16_t* w3s = (ushort16_t*)(ws + O_W3S16);
        for (int i = gid; i < 512*1024; i += gsz) {
            int o = i >> 10, kp = i & 1023;
            int c = kp >> 1, s = kp & 1;
            float v = ldin(w3, o*512 + c, f32);
            ushort16_t h = f2bf(v);
            w3s[i] = (s == 0) ? h : f2bf(v - bfbits2f(h));
        }
    }
    for (int c = gid; c < 512; c += gsz) {
        float g = ldin(bn3, c, f32), be = ldin(bn3, 512+c, f32);
        float m = ldin(bn3, 1024+c, f32), vv = ldin(bn3, 1536+c, f32);
        float s = g / sqrtf(vv + 1e-5f);
        ws[O_BN3SC + c] = s; ws[O_BN3SH + c] = be - m*s;
    }
    for (int i = gid; i < 48; i += gsz) ws[O_LA + i]       = ldin(la_w1, i, f32);
    for (int i = gid; i < 16; i += gsz) ws[O_LA + 48 + i]  = ldin(la_b1, i, f32);
    for (int i = gid; i < 48; i += gsz) ws[O_LA + 64 + i]  = ldin(la_w2, i, f32);
    for (int i = gid; i < 16; i += gsz) ws[O_LA + 112 + i] = ldin(la_b2, i, f32);
    for (int i = gid; i < 16; i += gsz) ws[O_LA + 128 + i] = ldin(la_w3, i, f32);
    if (gid == 0) ws[O_LA + 144] = ldin(la_b3, 0, f32);

    // ---- edge1 decomposition: W1split (3-split interleaved, K side) ----
    ushort16_t* w1s = (ushort16_t*)(ws + O_W1S16);
    for (int i = gid; i < 128*64; i += gsz) {
        int row = i >> 6, kp = i & 63;
        if (kp < 57) {
            int c = kp / 3, s = kp - c*3;
            int o = row & 63;
            float wnb = ldin(w1, o*57 + c, f32);
            float wce = ldin(w1, o*57 + 19 + c, f32);
            float wdf = ldin(w1, o*57 + 38 + c, f32);
            float v = (row < 64) ? (wnb - wdf) : (wce + wdf);
            ushort16_t h = f2bf(v); float r1 = v - bfbits2f(h);
            ushort16_t m = f2bf(r1); ushort16_t l = f2bf(r1 - bfbits2f(m));
            w1s[i] = (s==0) ? h : ((s==1) ? m : l);
        } else w1s[i] = 0;
    }
    ushort16_t* w1a3 = (ushort16_t*)(ws + O_W1A3);
    for (int i = gid; i < 3*64*192; i += gsz) {
        int t = i / (64*192), rem = i - t*64*192;
        int o = rem / 192, kp = rem - o*192;
        int c = kp / 3;
        float v = ldin(p1_w, o*64 + c, f32);
        ushort16_t h = f2bf(v); float r1 = v - bfbits2f(h);
        ushort16_t m = f2bf(r1); ushort16_t l = f2bf(r1 - bfbits2f(m));
        w1a3[i] = (t==0) ? h : ((t==1) ? m : l);
    }

    // edge2 decomposition
    ushort16_t* a2b = (ushort16_t*)(ws + O_W2B16);
    for (int i = gid; i < 256*96; i += gsz) {
        int row = i / 96, c = i - row*96;
        float v = (c < 83) ? (ldin(w2, row*249 + c, f32) - ldin(w2, row*249 + 166 + c, f32)) : 0.f;
        a2b[i] = f2bf(v);
    }
    float* b2fT = ws + O_P2W;
    for (int i = gid; i < 84*256; i += gsz) {
        int c = i >> 8, row = i & 255;
        b2fT[i] = (c < 83) ? (ldin(w2, row*249 + 83 + c, f32) + ldin(w2, row*249 + 166 + c, f32)) : 0.f;
    }
    ushort16_t* pwb = (ushort16_t*)(ws + O_P2W16);
    for (int i = gid; i < 256*256; i += gsz) pwb[i] = f2bf(ldin(p2_w, i, f32));
}

// ================= xconv: x -> fp32 into XMAN rows 0..2 =================
__global__ __launch_bounds__(256) void xconv_kernel(const void* x, float* ws) {
    const int f32 = ((const int*)ws)[O_FLAG];
    int gid = blockIdx.x*256 + threadIdx.x;
    int b = gid / (3*NN), r = gid - b*3*NN;
    ws[O_XMAN + b*19*NN + r] = ldin(x, gid, f32);
}

// ================= xc1copy: xman rows 0..18 -> xc1 rows 0..18 (coalesced) =====
__global__ __launch_bounds__(256) void xc1copy_kernel(float* ws) {
    int gid = blockIdx.x*256 + threadIdx.x;
    int b = gid / (19*NN), r = gid - b*19*NN;
    ws[O_XC1 + (size_t)b*83*NN + r] = ws[O_XMAN + gid];
}

// ====== 3-way bf16 split precompute (batch locked to XCD via blockIdx&7) ======
template<int C, int CS, int KP>
__global__ void hilo_kernel(const float* feat, ushort16_t* out) {
    int b  = blockIdx.x & 7;
    int lb = blockIdx.x >> 3;
    int nb = gridDim.x >> 3;
    const float* fb = feat + (size_t)b*CS*NN;
    ushort16_t* ob = out + (size_t)b*NN*KP;
    for (int i = lb*blockDim.x + threadIdx.x; i < C*NN; i += nb*blockDim.x) {
        int c = i >> 11, n = i & (NN-1);
        float v = fb[(size_t)c*NN + n];
        ushort16_t h = f2bf(v);
        float r1 = v - bfbits2f(h);
        ushort16_t m = f2bf(r1);
        ushort16_t l = f2bf(r1 - bfbits2f(m));
        size_t base = (size_t)n*KP + 3*c;
        ob[base] = h; ob[base+1] = m; ob[base+2] = l;
    }
    constexpr int PAD = KP - 3*C;
    for (int i = lb*blockDim.x + threadIdx.x; i < NN*PAD; i += nb*blockDim.x) {
        int n = i / PAD, p = i - n*PAD;
        ob[(size_t)n*KP + 3*C + p] = 0;
    }
}

// ====== exact fp32 squared norms ======
template<int C, int CS>
__global__ __launch_bounds__(256) void xx_kernel(const float* feat, float* xxg) {
    int gid = blockIdx.x*256 + threadIdx.x;
    int b = gid >> 11, n = gid & (NN-1);
    const float* fb = feat + (size_t)b*CS*NN;
    float s = 0.f;
    #pragma unroll
    for (int c = 0; c < C; ++c) { float v = fb[c*NN + n]; s += v*v; }
    xxg[gid] = s;
}

// ====== fused knn: MFMA distance tile + lazy top-3 u64-butterfly extraction ======
// v2 geometry: 1024 threads (16 waves) per block -> 4 waves/SIMD (2x occupancy).
// Distance: wave wv covers candidate tiles wv*2, wv*2+1 (K-chunked B-frags for KT>4
// to fit 128 VGPR; kt order preserved -> bitwise-identical accumulation).
// Selection: wave wv owns exactly row wv (one point per wave).
template<int C, int CS, int KP>
__global__ __launch_bounds__(1024, 4) void knn_fused_kernel(
    const float* feat, const ushort16_t* hilo, const float* xxg, int* idxout)
{
    constexpr int KT = KP / 32;
    constexpr int NCH = (KT > 4) ? 2 : 1;
    constexpr int KTC = KT / NCH;
    constexpr int ST = 2057;
    __shared__ float Dt[16 * ST];
    int tid = threadIdx.x;
    int b  = blockIdx.x & 7;
    int n0 = (blockIdx.x >> 3) << 4;
    int lane = tid & 63, wv = tid >> 6;      // 16 waves
    int quad = lane >> 4, l15 = lane & 15;
    const float* fb = feat + (size_t)b * CS * NN;
    const ushort16_t* hb = hilo + (size_t)b * NN * KP;
    const float* xxb = xxg + b * NN;

    // ---- distance: wave wv covers candidate tiles wv*2, wv*2+1 ----
    floatx4 acc[2][4];
    #pragma unroll
    for (int i = 0; i < 2; ++i)
        #pragma unroll
        for (int st = 0; st < 4; ++st) acc[i][st] = (floatx4){0.f,0.f,0.f,0.f};

    #pragma unroll
    for (int ch = 0; ch < NCH; ++ch) {
        // point-side B fragments for this K chunk (point = n0 + l15)
        short8 Bh[KTC], Bm[KTC], Bl[KTC];
        #pragma unroll
        for (int ktc = 0; ktc < KTC; ++ktc) {
            #pragma unroll
            for (int e = 0; e < 8; ++e) {
                int kp = (ch*KTC + ktc)*32 + quad*8 + e;
                int c = kp / 3;
                float v = (c < C) ? fb[(size_t)c*NN + n0 + l15] : 0.f;
                ushort16_t h = f2bf(v);
                float r1 = v - bfbits2f(h);
                ushort16_t m = f2bf(r1);
                ushort16_t l = f2bf(r1 - bfbits2f(m));
                Bh[ktc][e] = (short)h; Bm[ktc][e] = (short)m; Bl[ktc][e] = (short)l;
            }
        }
        #pragma unroll
        for (int i = 0; i < 2; ++i) {
            int base = (wv*2 + i) * 64;
            #pragma unroll
            for (int st = 0; st < 4; ++st) {
                #pragma unroll
                for (int ktc = 0; ktc < KTC; ++ktc) {
                    int kt = ch*KTC + ktc;
                    short8 a = *(const short8*)&hb[(size_t)(base + st*16 + l15)*KP + kt*32 + quad*8];
                    acc[i][st] = __builtin_amdgcn_mfma_f32_16x16x32_bf16(a, Bh[ktc], acc[i][st], 0, 0, 0);
                    acc[i][st] = __builtin_amdgcn_mfma_f32_16x16x32_bf16(a, Bm[ktc], acc[i][st], 0, 0, 0);
                    acc[i][st] = __builtin_amdgcn_mfma_f32_16x16x32_bf16(a, Bl[ktc], acc[i][st], 0, 0, 0);
                }
            }
        }
    }
    #pragma unroll
    for (int i = 0; i < 2; ++i) {
        #pragma unroll
        for (int st = 0; st < 4; ++st) {
            #pragma unroll
            for (int r = 0; r < 4; ++r) {
                int cand = (wv*2 + i)*64 + st*16 + quad*4 + r;
                Dt[l15*ST + cand] = 2.f*acc[i][st][r] - xxb[cand];
            }
        }
    }
    __syncthreads();

    // ---- selection: wave wv owns row wv ----
    int r0 = wv;
    unsigned int basei = 2047u - (unsigned int)lane;
    unsigned int a0[32];
    unsigned int dead0 = 0;
    unsigned long long p0 = 0, p1 = 0, p2 = 0;
    #pragma unroll
    for (int j = 0; j < 32; ++j) {
        unsigned int u0 = __float_as_uint(Dt[r0*ST + j*64 + lane]);
        unsigned int o0 = u0 ^ (unsigned int)(((int)u0 >> 31) | 0x80000000);
        a0[j] = o0;
        unsigned long long k0 = ((unsigned long long)o0 << 32) | (basei - j*64);
        bool g00 = k0 > p0, g01 = k0 > p1, g02 = k0 > p2;
        p2 = g01 ? p1 : (g02 ? k0 : p2);
        p1 = g00 ? p0 : (g01 ? k0 : p1);
        p0 = g00 ? k0 : p0;
    }
    int myg0 = 0;
    #pragma unroll 1
    for (int it = 0; it < KK; ++it) {
        unsigned long long b0 = p0;
        #pragma unroll
        for (int sh = 1; sh < 64; sh <<= 1) {
            unsigned long long o0 = __shfl_xor(b0, sh);
            b0 = (o0 > b0) ? o0 : b0;
        }
        if (lane == it) myg0 = (int)(2047u - (unsigned int)b0);
        if (p0 == b0) {
            dead0 |= 1u << ((int)(basei - (unsigned int)b0) >> 6);
            p0 = p1; p1 = p2; p2 = 0;
        }
        if (__any(p0 == 0ull)) {   // rare: lane popped 3x since build
            if (p0 == 0ull) {
                unsigned long long t0 = 0, t1 = 0, t2 = 0;
                #pragma unroll
                for (int j = 0; j < 32; ++j) {
                    unsigned long long k = ((dead0 >> j) & 1u) ? 0ull
                        : (((unsigned long long)a0[j] << 32) | (basei - j*64));
                    bool g0 = k > t0, g1 = k > t1, g2 = k > t2;
                    t2 = g1 ? t1 : (g2 ? k : t2);
                    t1 = g0 ? t0 : (g1 ? k : t1);
                    t0 = g0 ? k : t0;
                }
                p0 = t0; p1 = t1; p2 = t2;
            }
        }
    }
    if (lane < KK)
        idxout[((size_t)(b*NN + n0 + r0))*KK + lane] = myg0;
}

// ================= lafe attention (post-knn) =================
__global__ __launch_bounds__(256, 1) void lafe_att_kernel(float* ws, const int* idx) {
    __shared__ float xs0[NN], xs1[NN], xs2[NN];
    int tid = threadIdx.x;
    int b = blockIdx.x >> 3;
    int n = ((blockIdx.x & 7) << 8) + tid;
    float* xm = ws + O_XMAN + b*19*NN;
    for (int i = tid; i < NN; i += 256) {
        xs0[i] = xm[i]; xs1[i] = xm[NN + i]; xs2[i] = xm[2*NN + i];
    }
    __syncthreads();
    float a0 = xs0[n], a1 = xs1[n], a2 = xs2[n];
    int ti[KK];
    #pragma unroll
    for (int k = 0; k < KK; ++k) ti[k] = idx[(b*NN + n)*KK + k] & (NN-1);
    const float* wl = ws + O_LA;
    float sa = wl[144];
    #pragma unroll
    for (int o = 0; o < 16; ++o) {
        float nf = wl[o*3+0]*a0 + wl[o*3+1]*a1 + wl[o*3+2]*a2 + wl[48+o];
        sa += wl[128+o]*nf;
    }
    float lg[KK]; float mx = -3.0e38f;
    #pragma unroll
    for (int k = 0; k < KK; ++k) {
        int m = ti[k];
        float d0 = a0 - xs0[m], d1 = a1 - xs1[m], d2 = a2 - xs2[m];
        float na = wl[144];
        #pragma unroll
        for (int o = 0; o < 16; ++o) {
            float ef = wl[64+o*3+0]*d0 + wl[64+o*3+1]*d1 + wl[64+o*3+2]*d2 + wl[112+o];
            na += wl[128+o]*ef;
        }
        float t = sa + na;
        t = t > 0.f ? t : 0.01f*t;
        lg[k] = t; mx = fmaxf(mx, t);
    }
    float ssum = 0.f;
    #pragma unroll
    for (int k = 0; k < KK; ++k) { lg[k] = expf(lg[k] - mx); ssum += lg[k]; }
    float vals[16];
    #pragma unroll
    for (int o = 0; o < 16; ++o) vals[o] = 0.f;
    #pragma unroll
    for (int k = 0; k < KK; ++k) {
        float coef = lg[k] / ssum;
        int m = ti[k];
        float d0 = a0 - xs0[m], d1 = a1 - xs1[m], d2 = a2 - xs2[m];
        #pragma unroll
        for (int o = 0; o < 16; ++o) {
            float ef = wl[64+o*3+0]*d0 + wl[64+o*3+1]*d1 + wl[64+o*3+2]*d2 + wl[112+o];
            vals[o] += coef * ef;
        }
    }
    #pragma unroll
    for (int o = 0; o < 16; ++o) {
        float v = vals[o];
        xm[(3+o)*NN + n] = v > 0.f ? v : expm1f(v);
    }
}

// ================= mlp (batch = blockIdx&7) =================
__global__ void mlp_kernel(float* ws) {
    __shared__ __align__(16) float xv[20];
    int tid = threadIdx.x;
    int b = blockIdx.x & 7, n = blockIdx.x >> 3;
    if (tid < 20) xv[tid] = (tid < 19) ? ws[O_XMAN + b*19*NN + tid*NN + n] : 0.f;
    __syncthreads();
    const float* mw = ws + O_MLPW;
    float acc = 0.f;
    #pragma unroll
    for (int c4 = 0; c4 < 5; ++c4) {
        float4 w = *(const float4*)&mw[tid*20 + c4*4];
        float4 g = *(const float4*)&xv[c4*4];
        acc += w.x*g.x + w.y*g.y + w.z*g.z + w.w*g.w;
    }
    float v = acc * ws[O_MLPSC + tid] + ws[O_MLPSH + tid];
    ws[O_XC2 + b*512*NN + tid*NN + n] = fmaxf(v, 0.f);
}

// ====== uv1: [U1;V1][n][128] = [A1;B1] @ xman via exact 3-split MFMA ======
__global__ __launch_bounds__(256, 2) void uv1_kernel(float* ws) {
    __shared__ float xt[19*64];
    int tid = threadIdx.x;
    int b = blockIdx.x & 7;
    int pn0 = (blockIdx.x >> 3) << 6;
    const float* fb = ws + O_XMAN + (size_t)b*19*NN;
    for (int i = tid; i < 19*64; i += 256) {
        int c = i >> 6, j = i & 63;
        xt[i] = fb[(size_t)c*NN + pn0 + j];
    }
    __syncthreads();
    int lane = tid & 63, wv = tid >> 6;
    int quad = lane >> 4, l15 = lane & 15;

    short8 X[3][4][2];
    #pragma unroll
    for (int nt = 0; nt < 4; ++nt) {
        int pt = nt*16 + l15;
        #pragma unroll
        for (int kt = 0; kt < 2; ++kt) {
            #pragma unroll
            for (int e = 0; e < 8; ++e) {
                int kp = kt*32 + quad*8 + e;
                int c = kp / 3;
                float v = (c < 19) ? xt[c*64 + pt] : 0.f;
                ushort16_t h = f2bf(v); float r1 = v - bfbits2f(h);
                ushort16_t m = f2bf(r1); ushort16_t l = f2bf(r1 - bfbits2f(m));
                X[0][nt][kt][e] = (short)h;
                X[1][nt][kt][e] = (short)m;
                X[2][nt][kt][e] = (short)l;
            }
        }
    }
    const ushort16_t* w1s = (const ushort16_t*)(ws + O_W1S16);
    floatx4 acc[2][4];
    #pragma unroll
    for (int rt = 0; rt < 2; ++rt)
        #pragma unroll
        for (int nt = 0; nt < 4; ++nt) acc[rt][nt] = (floatx4){0.f,0.f,0.f,0.f};
    #pragma unroll
    for (int pass = 0; pass < 3; ++pass) {
        #pragma unroll
        for (int kt = 0; kt < 2; ++kt) {
            int c0 = kt*32 + quad*8;
            short8 a[2];
            a[0] = *(const short8*)&w1s[(wv*32 + l15)*64 + c0];
            a[1] = *(const short8*)&w1s[(wv*32 + 16 + l15)*64 + c0];
            #pragma unroll
            for (int rt = 0; rt < 2; ++rt)
                #pragma unroll
                for (int nt = 0; nt < 4; ++nt)
                    acc[rt][nt] = __builtin_amdgcn_mfma_f32_16x16x32_bf16(a[rt], X[pass][nt][kt], acc[rt][nt], 0, 0, 0);
        }
    }
    float* uv1 = ws + O_UV1 + (size_t)b*NN*128;
    #pragma unroll
    for (int rt = 0; rt < 2; ++rt)
        #pragma unroll
        for (int nt = 0; nt < 4; ++nt) {
            int n = pn0 + nt*16 + l15;
            int r = wv*32 + rt*16 + quad*4;
            *(float4*)&uv1[(size_t)n*128 + r] =
                make_float4(acc[rt][nt][0], acc[rt][nt][1], acc[rt][nt][2], acc[rt][nt][3]);
        }
}

// ================= edge1 v2: U1/V1 gather + exact 3-split att GEMM =================
__global__ __launch_bounds__(256, 2) void edge1_kernel(float* ws, const int* idx) {
    constexpr int SW = 204;
    constexpr int ST = 65;
    __shared__ __align__(16) ushort16_t hrS[80*SW];
    __shared__ __align__(16) float attL[80*ST];
    __shared__ float vL[4*64];
    __shared__ float scalL[256];
    __shared__ float outL[64*5];
    __shared__ int idxL[80];

    int tid = threadIdx.x;
    int b  = blockIdx.x & 7;
    int n0 = (blockIdx.x >> 3) << 2;
    const float* uv1 = ws + O_UV1 + (size_t)b*NN*128;

    {
        int grp = tid >> 6, r6 = tid & 63;
        int off = grp==0 ? O_BN1SC : grp==1 ? O_BN1SH : grp==2 ? O_P1SC : O_P1SH;
        scalL[tid] = ws[off + r6];
        vL[tid] = uv1[(size_t)(n0 + grp)*128 + 64 + r6];
    }
    if (tid < 80) idxL[tid] = idx[(b*NN + n0 + tid/20)*KK + (tid%20)] & (NN-1);
    __syncthreads();

    {
        int rw = tid & 63, cg = tid >> 6;
        float s1 = scalL[rw], sh1 = scalL[64+rw], ps = scalL[128+rw], ph = scalL[192+rw];
        #pragma unroll 5
        for (int it = 0; it < 20; ++it) {
            int col = it*4 + cg;
            int p = col / 20;
            int j = idxL[col];
            float u = uv1[(size_t)j*128 + rw];
            float h1 = (u + vL[p*64+rw])*s1 + sh1;
            h1 = h1 > 0.f ? h1 : 0.2f*h1;
            float hv = h1*ps + ph;
            hv = hv > 0.f ? hv : 0.f;
            ushort16_t h = f2bf(hv); float r1 = hv - bfbits2f(h);
            ushort16_t m = f2bf(r1); ushort16_t l = f2bf(r1 - bfbits2f(m));
            hrS[col*SW + 3*rw + 0] = h;
            hrS[col*SW + 3*rw + 1] = m;
            hrS[col*SW + 3*rw + 2] = l;
        }
    }
    __syncthreads();

    int lane = tid & 63, wv = tid >> 6;
    int quad = lane >> 4, l15 = lane & 15;
    const ushort16_t* w1a3 = (const ushort16_t*)(ws + O_W1A3);
    floatx4 acc[5];
    #pragma unroll
    for (int mt = 0; mt < 5; ++mt) acc[mt] = (floatx4){0.f,0.f,0.f,0.f};
    #pragma unroll
    for (int pass = 0; pass < 3; ++pass) {
        #pragma unroll
        for (int kt = 0; kt < 6; ++kt) {
            int c0 = kt*32 + quad*8;
            short8 bfrag = *(const short8*)&w1a3[((size_t)pass*64 + wv*16 + l15)*192 + c0];
            #pragma unroll
            for (int mt = 0; mt < 5; ++mt) {
                short8 afrag = *(const short8*)&hrS[(mt*16 + l15)*SW + c0];
                acc[mt] = __builtin_amdgcn_mfma_f32_16x16x32_bf16(afrag, bfrag, acc[mt], 0, 0, 0);
            }
        }
    }
    #pragma unroll
    for (int mt = 0; mt < 5; ++mt)
        #pragma unroll
        for (int r = 0; r < 4; ++r)
            attL[(mt*16 + quad*4 + r)*ST + wv*16 + l15] = acc[mt][r];
    __syncthreads();

    {
        int o = tid & 63, p = tid >> 6;
        float av[KK]; float mx = -3.0e38f;
        #pragma unroll
        for (int k = 0; k < KK; ++k) { av[k] = attL[(p*20 + k)*ST + o]; mx = fmaxf(mx, av[k]); }
        float ssum = 0.f;
        #pragma unroll
        for (int k = 0; k < KK; ++k) { av[k] = expf(av[k] - mx); ssum += av[k]; }
        float inv = 1.f / ssum;
        float s1o = scalL[o], sh1o = scalL[64+o], vpo = vL[p*64+o];
        float sacc = 0.f;
        #pragma unroll
        for (int k = 0; k < KK; ++k) {
            int j = idxL[p*20 + k];
            float u = uv1[(size_t)j*128 + o];
            float h1 = (u + vpo)*s1o + sh1o;
            h1 = h1 > 0.f ? h1 : 0.2f*h1;
            sacc += av[k]*inv*h1;
        }
        outL[o*5 + p] = sacc;
    }
    __syncthreads();
    {
        int o = tid >> 2, p = tid & 3;
        ws[O_XC1 + (size_t)b*83*NN + (size_t)(19+o)*NN + n0 + p] = outL[o*5 + p];
    }
}

// ====== uv2: U2[b][n][r] = sum_c A2[r][c] * xc1[b][c][n] (batch = blockIdx&7) ======
__global__ __launch_bounds__(256, 2) void uv2_kernel(float* ws) {
    constexpr int XS = 108;
    __shared__ ushort16_t xt[64*XS];
    int tid = threadIdx.x;
    int b = blockIdx.x & 7;
    int pn0 = (blockIdx.x >> 3) << 6;
    const float* xc1 = ws + O_XC1 + (size_t)b*83*NN;
    for (int i = tid; i < 96*64; i += 256) {
        int c = i >> 6, j = i & 63;
        xt[j*XS + c] = (c < 83) ? f2bf(xc1[c*NN + pn0 + j]) : (ushort16_t)0;
    }
    __syncthreads();
    int lane = tid & 63, wv = tid >> 6;
    int quad = lane >> 4, l15 = lane & 15;
    const ushort16_t* a2b = (const ushort16_t*)(ws + O_W2B16);
    floatx4 acc[4][4];
    #pragma unroll
    for (int rt = 0; rt < 4; ++rt)
        #pragma unroll
        for (int nt = 0; nt < 4; ++nt) acc[rt][nt] = (floatx4){0.f,0.f,0.f,0.f};
    #pragma unroll
    for (int kt = 0; kt < 3; ++kt) {
        int c0 = kt*32 + quad*8;
        short8 bfr[4], a[4];
        #pragma unroll
        for (int nt = 0; nt < 4; ++nt)
            bfr[nt] = *(const short8*)&xt[(nt*16 + l15)*XS + c0];
        #pragma unroll
        for (int rt = 0; rt < 4; ++rt)
            a[rt] = *(const short8*)&a2b[(wv*64 + rt*16 + l15)*96 + c0];
        #pragma unroll
        for (int rt = 0; rt < 4; ++rt)
            #pragma unroll
            for (int nt = 0; nt < 4; ++nt)
                acc[rt][nt] = __builtin_amdgcn_mfma_f32_16x16x32_bf16(a[rt], bfr[nt], acc[rt][nt], 0, 0, 0);
    }
    float* U2 = ws + O_XC2 + (size_t)b*512*NN;
    #pragma unroll
    for (int rt = 0; rt < 4; ++rt)
        #pragma unroll
        for (int nt = 0; nt < 4; ++nt) {
            int n = pn0 + nt*16 + l15;
            int r = wv*64 + rt*16 + quad*4;
            *(float4*)&U2[(size_t)n*256 + r] =
                make_float4(acc[rt][nt][0], acc[rt][nt][1], acc[rt][nt][2], acc[rt][nt][3]);
        }
}

// ====== v2: V2[b][n][r] = sum_c b2fT[c][r] * xc1[b][c][n], exact fp32, point-major ======
__global__ __launch_bounds__(256, 4) void v2_kernel(float* ws) {
    __shared__ float xs[83*16];
    int tid = threadIdx.x;
    int b = blockIdx.x & 7;
    int pn0 = (blockIdx.x >> 3) << 4;
    const float* xc1 = ws + O_XC1 + (size_t)b*83*NN;
    for (int i = tid; i < 83*16; i += 256) {
        int c = i >> 4, j = i & 15;
        xs[i] = xc1[(size_t)c*NN + pn0 + j];
    }
    __syncthreads();
    const float* b2fT = ws + O_P2W;
    float acc[16];
    #pragma unroll
    for (int j = 0; j < 16; ++j) acc[j] = 0.f;
    #pragma unroll 4
    for (int c = 0; c < 83; ++c) {
        float w = b2fT[c*256 + tid];
        #pragma unroll
        for (int j = 0; j < 16; ++j) acc[j] += w * xs[c*16 + j];
    }
    float* V2 = ws + O_XC2 + (size_t)b*512*NN + (size_t)256*NN;
    #pragma unroll
    for (int j = 0; j < 16; ++j) V2[(size_t)(pn0 + j)*256 + tid] = acc[j];
}

// ================= edge2 v3: 2 points/block, V precomputed, h2 reg-cached =================
__global__ __launch_bounds__(256, 2) void edge2_kernel(float* ws, const int* idx) {
    constexpr int HS = 268;
    __shared__ __align__(16) ushort16_t hrb[48*HS];
    __shared__ __align__(16) float attL[256*41];
    __shared__ float p2bL[256];
    __shared__ int idxL[40];

    int tid = threadIdx.x;
    int b  = blockIdx.x & 7;
    int n0 = (blockIdx.x >> 3) << 1;

    const float* U2 = ws + O_XC2 + (size_t)b*512*NN;
    float* V2 = ws + O_XC2 + (size_t)b*512*NN + (size_t)256*NN;

    float sc = ws[O_BN2SC + tid], sh = ws[O_BN2SH + tid];
    float ps = ws[O_P2SC + tid],  ph = ws[O_P2SH + tid];
    p2bL[tid] = ws[O_P2B + tid];
    float v0 = V2[(size_t)n0*256 + tid];
    float v1 = V2[(size_t)(n0+1)*256 + tid];
    if (tid < 40) idxL[tid] = idx[(b*NN + n0 + tid/20)*KK + (tid%20)] & (NN-1);
    __syncthreads();

    float h2r[40];
    #pragma unroll
    for (int col = 0; col < 40; ++col) {
        int j = idxL[col];
        float u = U2[(size_t)j*256 + tid];
        float h2 = (u + (col >= 20 ? v1 : v0))*sc + sh;
        h2 = h2 > 0.f ? h2 : 0.2f*h2;
        h2r[col] = h2;
        float hv = h2*ps + ph;
        hrb[col*HS + tid] = f2bf(fmaxf(hv, 0.f));
    }
    __syncthreads();

    int lane = tid & 63, wv = tid >> 6;
    int quad = lane >> 4, l15 = lane & 15;
    const ushort16_t* p2wb = (const ushort16_t*)(ws + O_P2W16);
    floatx4 acc2[4][3];
    #pragma unroll
    for (int mt = 0; mt < 4; ++mt)
        #pragma unroll
        for (int nt = 0; nt < 3; ++nt) acc2[mt][nt] = (floatx4){0.f,0.f,0.f,0.f};
    for (int kt = 0; kt < 8; ++kt) {
        int c0 = kt*32 + quad*8;
        short8 a[4], bb3[3];
        #pragma unroll
        for (int mt = 0; mt < 4; ++mt)
            a[mt] = *(const short8*)&p2wb[(wv*64 + mt*16 + l15)*256 + c0];
        #pragma unroll
        for (int nt = 0; nt < 3; ++nt)
            bb3[nt] = *(const short8*)&hrb[(nt*16 + l15)*HS + c0];
        #pragma unroll
        for (int mt = 0; mt < 4; ++mt)
            #pragma unroll
            for (int nt = 0; nt < 3; ++nt)
                acc2[mt][nt] = __builtin_amdgcn_mfma_f32_16x16x32_bf16(a[mt], bb3[nt], acc2[mt][nt], 0, 0, 0);
    }
    #pragma unroll
    for (int mt = 0; mt < 4; ++mt) {
        int k0 = wv*64 + mt*16 + quad*4;
        #pragma unroll
        for (int nt = 0; nt < 3; ++nt) {
            int col = nt*16 + l15;
            if (col < 40) {
                #pragma unroll
                for (int r = 0; r < 4; ++r)
                    attL[(k0 + r)*41 + col] = acc2[mt][nt][r] + p2bL[k0 + r];
            }
        }
    }
    __syncthreads();

    #pragma unroll
    for (int p = 0; p < 2; ++p) {
        float av[KK]; float mx = -3.0e38f;
        #pragma unroll
        for (int k = 0; k < KK; ++k) { av[k] = attL[tid*41 + p*20 + k]; mx = fmaxf(mx, av[k]); }
        float ssum = 0.f;
        #pragma unroll
        for (int k = 0; k < KK; ++k) { av[k] = expf(av[k] - mx); ssum += av[k]; }
        float inv = 1.f / ssum;
        float sacc = 0.f;
        #pragma unroll
        for (int k = 0; k < KK; ++k) sacc += av[k] * inv * h2r[p*20 + k];
        V2[(size_t)(n0 + p)*256 + tid] = sacc;
    }
}

// ================= final (MFMA, 2-split x 2-split exact-enough) =================
__global__ __launch_bounds__(512, 1) void final_kernel(const float* ws, float* out) {
    __shared__ __align__(16) uint32 smem[17408];      // 69,632 B union
    __shared__ float s3L[512], q3L[512];
    uint32* xh32 = smem;                              // [64][132]
    uint32* xm32 = smem + 8448;                       // [64][132]
    float*  outF = (float*)smem;                      // [256][68]

    int tid = threadIdx.x;
    int b = blockIdx.x & 7;
    int pn0 = (blockIdx.x >> 3) << 6;
    int lane = tid & 63, wv = tid >> 6;
    int quad = lane >> 4, l15 = lane & 15;
    if (tid < 512) { s3L[tid] = ws[O_BN3SC + tid]; q3L[tid] = ws[O_BN3SH + tid]; }

    const float* xc2 = ws + O_XC2 + (size_t)b*512*NN;
    const float* xp2 = xc2 + (size_t)256*NN;
    const ushort16_t* w3s = (const ushort16_t*)(ws + O_W3S16);
    int r0 = wv*64;

    floatx4 acc[4][4];
    #pragma unroll
    for (int mt = 0; mt < 4; ++mt)
        #pragma unroll
        for (int nt = 0; nt < 4; ++nt) acc[mt][nt] = (floatx4){0.f,0.f,0.f,0.f};

    for (int ch = 0; ch < 4; ++ch) {
        __syncthreads();
        if (ch < 2) {
            int gc0 = ch*128;
            #pragma unroll 4
            for (int it = 0; it < 16; ++it) {
                int idx = it*512 + tid;
                int cl = idx >> 6, n = idx & 63;
                float v = xc2[(size_t)(gc0+cl)*NN + pn0 + n];
                ushort16_t h = f2bf(v);
                ushort16_t m = f2bf(v - bfbits2f(h));
                xh32[n*132 + cl] = (uint32)h * 0x10001u;
                xm32[n*132 + cl] = (uint32)m * 0x10001u;
            }
        } else {
            int gco = (ch-2)*128;
            #pragma unroll 4
            for (int it = 0; it < 16; ++it) {
                int idx = it*512 + tid;
                int n = idx >> 7, cl = idx & 127;
                float v = xp2[(size_t)(pn0+n)*256 + gco + cl];
                ushort16_t h = f2bf(v);
                ushort16_t m = f2bf(v - bfbits2f(h));
                xh32[n*132 + cl] = (uint32)h * 0x10001u;
                xm32[n*132 + cl] = (uint32)m * 0x10001u;
            }
        }
        __syncthreads();
        const ushort16_t* ph = (const ushort16_t*)xh32;
        const ushort16_t* pm = (const ushort16_t*)xm32;
        #pragma unroll
        for (int kt = 0; kt < 8; ++kt) {
            int c0k = kt*32 + quad*8;
            short8 a[4], bh[4], bm[4];
            #pragma unroll
            for (int mt = 0; mt < 4; ++mt)
                a[mt] = *(const short8*)&w3s[(size_t)(r0 + mt*16 + l15)*1024 + ch*256 + c0k];
            #pragma unroll
            for (int nt = 0; nt < 4; ++nt) {
                bh[nt] = *(const short8*)&ph[(nt*16 + l15)*264 + c0k];
                bm[nt] = *(const short8*)&pm[(nt*16 + l15)*264 + c0k];
            }
            #pragma unroll
            for (int mt = 0; mt < 4; ++mt)
                #pragma unroll
                for (int nt = 0; nt < 4; ++nt) {
                    acc[mt][nt] = __builtin_amdgcn_mfma_f32_16x16x32_bf16(a[mt], bh[nt], acc[mt][nt], 0, 0, 0);
                    acc[mt][nt] = __builtin_amdgcn_mfma_f32_16x16x32_bf16(a[mt], bm[nt], acc[mt][nt], 0, 0, 0);
                }
        }
    }

    float* ob = out + (size_t)b*512*NN;
    #pragma unroll
    for (int half = 0; half < 2; ++half) {
        __syncthreads();
        if ((wv >> 2) == half) {
            int rb = r0 - half*256;
            #pragma unroll
            for (int mt = 0; mt < 4; ++mt)
                #pragma unroll
                for (int nt = 0; nt < 4; ++nt)
                    #pragma unroll
                    for (int r = 0; r < 4; ++r) {
                        int row = r0 + mt*16 + quad*4 + r;
                        float v = acc[mt][nt][r]*s3L[row] + q3L[row];
                        v = v > 0.f ? v : 0.2f*v;
                        outF[(rb + mt*16 + quad*4 + r)*68 + nt*16 + l15] = v;
                    }
        }
        __syncthreads();
        #pragma unroll
        for (int it = 0; it < 8; ++it) {
            int idx = it*512 + tid;
            int row = idx >> 4, f4 = idx & 15;
            float4 v = *(const float4*)&outF[row*68 + f4*4];
            *(float4*)&ob[(size_t)(half*256 + row)*NN + pn0 + f4*4] = v;
        }
    }
}

extern "C" void kernel_launch(void* const* d_in, const int* in_sizes, int n_in,
                              void* d_out, int out_size, void* d_ws, size_t ws_size,
                              hipStream_t stream) {
    float* ws = (float*)d_ws;
    float* out = (float*)d_out;
    ushort16_t* hilo = (ushort16_t*)(ws + O_HILO);
    float* xxq = ws + O_XXQ;

    detect_kernel<<<1, 64, 0, stream>>>(d_in[0], (int*)ws + O_FLAG);
    prep_kernel<<<64, 256, 0, stream>>>(d_in[1], d_in[2], d_in[3], d_in[4], d_in[5], d_in[6],
                                        d_in[7], d_in[8], d_in[9], d_in[10], d_in[11], d_in[12],
                                        d_in[13], d_in[14], d_in[15], d_in[16], d_in[17], d_in[18],
                                        d_in[19], d_in[20], d_in[21], ws);
    // lafe = xconv + knn3 (fused MFMA+select) + attention
    xconv_kernel<<<192, 256, 0, stream>>>(d_in[0], ws);
    hilo_kernel<3, 19, 32><<<256, 256, 0, stream>>>(ws + O_XMAN, hilo);
    xx_kernel<3, 19><<<64, 256, 0, stream>>>(ws + O_XMAN, xxq);
    knn_fused_kernel<3, 19, 32><<<1024, 1024, 0, stream>>>(ws + O_XMAN, hilo, xxq, (int*)(ws + O_IDX3));
    lafe_att_kernel<<<64, 256, 0, stream>>>(ws, (const int*)(ws + O_IDX3));
    xc1copy_kernel<<<1216, 256, 0, stream>>>(ws);
    // knn on x_manet (C=19)
    hilo_kernel<19, 19, 64><<<1024, 256, 0, stream>>>(ws + O_XMAN, hilo);
    xx_kernel<19, 19><<<64, 256, 0, stream>>>(ws + O_XMAN, xxq);
    knn_fused_kernel<19, 19, 64><<<1024, 1024, 0, stream>>>(ws + O_XMAN, hilo, xxq, (int*)(ws + O_IDX2));
    // edge1 via exact A/B decomposition
    uv1_kernel<<<256, 256, 0, stream>>>(ws);
    edge1_kernel<<<BB*512, 256, 0, stream>>>(ws, (const int*)(ws + O_IDX2));
    // knn on x_c1 (C=83)
    hilo_kernel<83, 83, 256><<<2048, 256, 0, stream>>>(ws + O_XC1, hilo);
    xx_kernel<83, 83><<<64, 256, 0, stream>>>(ws + O_XC1, xxq);
    knn_fused_kernel<83, 83, 256><<<1024, 1024, 0, stream>>>(ws + O_XC1, hilo, xxq, (int*)(ws + O_IDX3));
    // edge2 via A/B decomposition: U2 (MFMA) + V2 (exact fp32 dense), then fused gather kernel
    uv2_kernel<<<256, 256, 0, stream>>>(ws);
    v2_kernel<<<1024, 256, 0, stream>>>(ws);
    edge2_kernel<<<BB*1024, 256, 0, stream>>>(ws, (const int*)(ws + O_IDX3));
    mlp_kernel<<<BB*NN, 256, 0, stream>>>(ws);
    final_kernel<<<256, 512, 0, stream>>>(ws, out);
}

// Round 10
// 888.317 us; speedup vs baseline: 2.1261x; 1.1001x over previous
//
#include <hip/hip_runtime.h>
#include <hip/hip_bf16.h>
#include <math.h>

typedef __hip_bfloat16 bf16;
typedef unsigned short ushort16_t;
typedef unsigned int uint32;
typedef __attribute__((ext_vector_type(8))) short short8;
typedef __attribute__((ext_vector_type(4))) float floatx4;

#define BB 8
#define NN 2048
#define KK 20

// ---- workspace layout (float offsets) ----
#define O_XMAN  0                        // [8][19][2048]  rows 0..2 = x (fp32), rows 3..18 = lafe out
#define O_XC1   311296                   // [8][83][2048]
#define O_XC2   1671168                  // [8][512][2048]:
                                         //   pre-mlp: [b] first half = U2 fp32 [2048][256]
                                         //            [b] second half = V2 fp32 [2048][256] -> overwritten by XP2
                                         //   post-mlp: rows 0..255 = x_mlp [c][n]
                                         //   reused earlier: knn scratch (hilo/xx) + UV1
#define O_IDX2  10059776                 // int [8][2048][20]
#define O_IDX3  10387456                 // int [8][2048][20] (also temp home for lafe knn idx)
#define O_MLPW  10715136                 // [256][20] padded
#define O_MLPSC 10720256
#define O_MLPSH 10720512
#define O_W1P   10720768                 // W1S16 (edge1 GEMM weights, 3-split)
#define O_BN1SC 10724864
#define O_BN1SH 10724928
#define O_P1SC  10724992
#define O_P1SH  10725056
#define O_P1W   10725120                 // (spare)
#define O_P1B   10729216                 // (spare; p1_b is softmax-invariant)
#define O_W2P   10729280                 // (spare)
#define O_BN2SC 10794816
#define O_BN2SH 10795072
#define O_P2SC  10795328
#define O_P2SH  10795584
#define O_P2W   10795840                 // b2fT fp32 [84][256] (edge2 B = Wce + Wdiff, transposed)
#define O_P2B   10861376
#define O_W3P   10861632                 // REUSED: w3s ushort [512][1024] 2-split (exactly 262144 floats)
#define O_BN3SC 11123776
#define O_BN3SH 11124288
#define O_LA    11124800                 // w1[48] b1[16] w2[48] b2[16] w3[16] b3[1]
#define O_FLAG  11124960                 // int: 1 if inputs are fp32, 0 if bf16
#define O_W2B16 11125760                 // ushort A2b [256][96] bf16 (edge2 A = Wnb - Wdiff)
#define O_P2W16 11162624                 // ushort [256][256] bf16 p2w

#define O_W1S16 O_W1P                    // ushort [128][64]
#define O_W3S16 O_W3P                    // ushort [512][1024] (w3 2-split K-interleaved)
#define O_W1A3  11195392                 // ushort [3][64][192], ends 11213824

// knn scratch inside XC2 region (consumed before uv2/v2/edge2/mlp write XC2):
#define O_HILO  O_XC2
#define O_XXQ   (O_XC2 + 2097152)
#define O_UV1   (O_XC2 + 2113536)        // fp32 [8][2048][128] (U1 rows 0..63, V1 64..127)

__device__ __forceinline__ float ldin(const void* p, int i, int f32) {
    return f32 ? ((const float*)p)[i]
               : __bfloat162float(((const bf16*)p)[i]);
}

__device__ __forceinline__ ushort16_t f2bf(float v) {
    union { bf16 h; ushort16_t u; } x; x.h = __float2bfloat16(v); return x.u;
}

__device__ __forceinline__ float bfbits2f(ushort16_t u) {
    union { uint32 i; float f; } c; c.i = ((uint32)u) << 16; return c.f;
}

// ---- DPP wave-max (pure VALU, no LDS): lane 63 ends with the 64-lane max ----
__device__ __forceinline__ uint32 dpp_wavemax(uint32 v) {
    uint32 t;
    t = (uint32)__builtin_amdgcn_update_dpp((int)v, (int)v, 0x111, 0xF, 0xF, false); v = v > t ? v : t; // row_shr:1
    t = (uint32)__builtin_amdgcn_update_dpp((int)v, (int)v, 0x112, 0xF, 0xF, false); v = v > t ? v : t; // row_shr:2
    t = (uint32)__builtin_amdgcn_update_dpp((int)v, (int)v, 0x114, 0xF, 0xF, false); v = v > t ? v : t; // row_shr:4
    t = (uint32)__builtin_amdgcn_update_dpp((int)v, (int)v, 0x118, 0xF, 0xF, false); v = v > t ? v : t; // row_shr:8
    t = (uint32)__builtin_amdgcn_update_dpp((int)v, (int)v, 0x142, 0xF, 0xF, false); v = v > t ? v : t; // row_bcast:15
    t = (uint32)__builtin_amdgcn_update_dpp((int)v, (int)v, 0x143, 0xF, 0xF, false); v = v > t ? v : t; // row_bcast:31
    return v;
}

// ============ detect: are inputs fp32 or bf16? ============
__global__ void detect_kernel(const void* x, int* flag) {
    if (threadIdx.x == 0 && blockIdx.x == 0) {
        const unsigned short* u = (const unsigned short*)x;
        int bad = 0;
        for (int i = 0; i < 64; ++i) {
            int e = (u[i] >> 7) & 0xFF;
            if (e >= 0x86) bad++;
        }
        *flag = (bad > 0) ? 1 : 0;
    }
}

// ================= prep =================
__global__ void prep_kernel(
    const void* la_w1, const void* la_b1, const void* la_w2, const void* la_b2,
    const void* la_w3, const void* la_b3,
    const void* mlp_w, const void* mlp_b, const void* mlp_bn,
    const void* w1, const void* bn1, const void* w2, const void* bn2,
    const void* w3, const void* bn3,
    const void* p1_bn, const void* p1_w, const void* p1_b,
    const void* p2_bn, const void* p2_w, const void* p2_b,
    float* ws)
{
    const int f32 = ((const int*)ws)[O_FLAG];
    int gid = blockIdx.x * blockDim.x + threadIdx.x;
    int gsz = gridDim.x * blockDim.x;

    for (int i = gid; i < 256*20; i += gsz) {
        int o = i / 20, c = i - o*20;
        ws[O_MLPW + i] = (c < 19) ? ldin(mlp_w, o*19 + c, f32) : 0.f;
    }
    for (int c = gid; c < 256; c += gsz) {
        float g = ldin(mlp_bn, c, f32), be = ldin(mlp_bn, 256+c, f32);
        float m = ldin(mlp_bn, 512+c, f32), vv = ldin(mlp_bn, 768+c, f32);
        float s = g / sqrtf(vv + 1e-5f);
        ws[O_MLPSC + c] = s;
        ws[O_MLPSH + c] = be + (ldin(mlp_b, c, f32) - m) * s;
    }
    for (int c = gid; c < 64; c += gsz) {
        float g = ldin(bn1, c, f32), be = ldin(bn1, 64+c, f32);
        float m = ldin(bn1, 128+c, f32), vv = ldin(bn1, 192+c, f32);
        float s = g / sqrtf(vv + 1e-5f);
        ws[O_BN1SC + c] = s; ws[O_BN1SH + c] = be - m*s;
        float g2 = ldin(p1_bn, c, f32), be2 = ldin(p1_bn, 64+c, f32);
        float m2 = ldin(p1_bn, 128+c, f32), vv2 = ldin(p1_bn, 192+c, f32);
        float s2 = g2 / sqrtf(vv2 + 1e-5f);
        ws[O_P1SC + c] = s2; ws[O_P1SH + c] = be2 - m2*s2;
    }
    for (int c = gid; c < 256; c += gsz) {
        float g = ldin(bn2, c, f32), be = ldin(bn2, 256+c, f32);
        float m = ldin(bn2, 512+c, f32), vv = ldin(bn2, 768+c, f32);
        float s = g / sqrtf(vv + 1e-5f);
        ws[O_BN2SC + c] = s; ws[O_BN2SH + c] = be - m*s;
        float g2 = ldin(p2_bn, c, f32), be2 = ldin(p2_bn, 256+c, f32);
        float m2 = ldin(p2_bn, 512+c, f32), vv2 = ldin(p2_bn, 768+c, f32);
        float s2 = g2 / sqrtf(vv2 + 1e-5f);
        ws[O_P2SC + c] = s2; ws[O_P2SH + c] = be2 - m2*s2;
        ws[O_P2B + c] = ldin(p2_b, c, f32);
    }
    // w3 2-split K-interleaved: w3s[o][2c+s] = split_s(w3[o][c])
    {
        ushort16_t* w3s = (ushort16_t*)(ws + O_W3S16);
        for (int i = gid; i < 512*1024; i += gsz) {
            int o = i >> 10, kp = i & 1023;
            int c = kp >> 1, s = kp & 1;
            float v = ldin(w3, o*512 + c, f32);
            ushort16_t h = f2bf(v);
            w3s[i] = (s == 0) ? h : f2bf(v - bfbits2f(h));
        }
    }
    for (int c = gid; c < 512; c += gsz) {
        float g = ldin(bn3, c, f32), be = ldin(bn3, 512+c, f32);
        float m = ldin(bn3, 1024+c, f32), vv = ldin(bn3, 1536+c, f32);
        float s = g / sqrtf(vv + 1e-5f);
        ws[O_BN3SC + c] = s; ws[O_BN3SH + c] = be - m*s;
    }
    for (int i = gid; i < 48; i += gsz) ws[O_LA + i]       = ldin(la_w1, i, f32);
    for (int i = gid; i < 16; i += gsz) ws[O_LA + 48 + i]  = ldin(la_b1, i, f32);
    for (int i = gid; i < 48; i += gsz) ws[O_LA + 64 + i]  = ldin(la_w2, i, f32);
    for (int i = gid; i < 16; i += gsz) ws[O_LA + 112 + i] = ldin(la_b2, i, f32);
    for (int i = gid; i < 16; i += gsz) ws[O_LA + 128 + i] = ldin(la_w3, i, f32);
    if (gid == 0) ws[O_LA + 144] = ldin(la_b3, 0, f32);

    // ---- edge1 decomposition: W1split (3-split interleaved, K side) ----
    ushort16_t* w1s = (ushort16_t*)(ws + O_W1S16);
    for (int i = gid; i < 128*64; i += gsz) {
        int row = i >> 6, kp = i & 63;
        if (kp < 57) {
            int c = kp / 3, s = kp - c*3;
            int o = row & 63;
            float wnb = ldin(w1, o*57 + c, f32);
            float wce = ldin(w1, o*57 + 19 + c, f32);
            float wdf = ldin(w1, o*57 + 38 + c, f32);
            float v = (row < 64) ? (wnb - wdf) : (wce + wdf);
            ushort16_t h = f2bf(v); float r1 = v - bfbits2f(h);
            ushort16_t m = f2bf(r1); ushort16_t l = f2bf(r1 - bfbits2f(m));
            w1s[i] = (s==0) ? h : ((s==1) ? m : l);
        } else w1s[i] = 0;
    }
    ushort16_t* w1a3 = (ushort16_t*)(ws + O_W1A3);
    for (int i = gid; i < 3*64*192; i += gsz) {
        int t = i / (64*192), rem = i - t*64*192;
        int o = rem / 192, kp = rem - o*192;
        int c = kp / 3;
        float v = ldin(p1_w, o*64 + c, f32);
        ushort16_t h = f2bf(v); float r1 = v - bfbits2f(h);
        ushort16_t m = f2bf(r1); ushort16_t l = f2bf(r1 - bfbits2f(m));
        w1a3[i] = (t==0) ? h : ((t==1) ? m : l);
    }

    // edge2 decomposition
    ushort16_t* a2b = (ushort16_t*)(ws + O_W2B16);
    for (int i = gid; i < 256*96; i += gsz) {
        int row = i / 96, c = i - row*96;
        float v = (c < 83) ? (ldin(w2, row*249 + c, f32) - ldin(w2, row*249 + 166 + c, f32)) : 0.f;
        a2b[i] = f2bf(v);
    }
    float* b2fT = ws + O_P2W;
    for (int i = gid; i < 84*256; i += gsz) {
        int c = i >> 8, row = i & 255;
        b2fT[i] = (c < 83) ? (ldin(w2, row*249 + 83 + c, f32) + ldin(w2, row*249 + 166 + c, f32)) : 0.f;
    }
    ushort16_t* pwb = (ushort16_t*)(ws + O_P2W16);
    for (int i = gid; i < 256*256; i += gsz) pwb[i] = f2bf(ldin(p2_w, i, f32));
}

// ================= xconv: x -> fp32 into XMAN rows 0..2 =================
__global__ __launch_bounds__(256) void xconv_kernel(const void* x, float* ws) {
    const int f32 = ((const int*)ws)[O_FLAG];
    int gid = blockIdx.x*256 + threadIdx.x;
    int b = gid / (3*NN), r = gid - b*3*NN;
    ws[O_XMAN + b*19*NN + r] = ldin(x, gid, f32);
}

// ================= xc1copy: xman rows 0..18 -> xc1 rows 0..18 (coalesced) =====
__global__ __launch_bounds__(256) void xc1copy_kernel(float* ws) {
    int gid = blockIdx.x*256 + threadIdx.x;
    int b = gid / (19*NN), r = gid - b*19*NN;
    ws[O_XC1 + (size_t)b*83*NN + r] = ws[O_XMAN + gid];
}

// ====== 3-way bf16 split precompute (batch locked to XCD via blockIdx&7) ======
template<int C, int CS, int KP>
__global__ void hilo_kernel(const float* feat, ushort16_t* out) {
    int b  = blockIdx.x & 7;
    int lb = blockIdx.x >> 3;
    int nb = gridDim.x >> 3;
    const float* fb = feat + (size_t)b*CS*NN;
    ushort16_t* ob = out + (size_t)b*NN*KP;
    for (int i = lb*blockDim.x + threadIdx.x; i < C*NN; i += nb*blockDim.x) {
        int c = i >> 11, n = i & (NN-1);
        float v = fb[(size_t)c*NN + n];
        ushort16_t h = f2bf(v);
        float r1 = v - bfbits2f(h);
        ushort16_t m = f2bf(r1);
        ushort16_t l = f2bf(r1 - bfbits2f(m));
        size_t base = (size_t)n*KP + 3*c;
        ob[base] = h; ob[base+1] = m; ob[base+2] = l;
    }
    constexpr int PAD = KP - 3*C;
    for (int i = lb*blockDim.x + threadIdx.x; i < NN*PAD; i += nb*blockDim.x) {
        int n = i / PAD, p = i - n*PAD;
        ob[(size_t)n*KP + 3*C + p] = 0;
    }
}

// ====== exact fp32 squared norms ======
template<int C, int CS>
__global__ __launch_bounds__(256) void xx_kernel(const float* feat, float* xxg) {
    int gid = blockIdx.x*256 + threadIdx.x;
    int b = gid >> 11, n = gid & (NN-1);
    const float* fb = feat + (size_t)b*CS*NN;
    float s = 0.f;
    #pragma unroll
    for (int c = 0; c < C; ++c) { float v = fb[c*NN + n]; s += v*v; }
    xxg[gid] = s;
}

// ====== fused knn: MFMA distance tile + lazy top-3 + DPP-reduce extraction ======
// 1024 threads (16 waves); wave wv owns row wv in selection.
// Extraction uses VALU-only DPP wave-max (value word) + ballot owner resolution
// (+ rare masked DPP max on index word for exact u64 tie-break semantics).
template<int C, int CS, int KP>
__global__ __launch_bounds__(1024, 4) void knn_fused_kernel(
    const float* feat, const ushort16_t* hilo, const float* xxg, int* idxout)
{
    constexpr int KT = KP / 32;
    constexpr int NCH = (KT > 4) ? 2 : 1;
    constexpr int KTC = KT / NCH;
    constexpr int ST = 2057;
    __shared__ float Dt[16 * ST];
    int tid = threadIdx.x;
    int b  = blockIdx.x & 7;
    int n0 = (blockIdx.x >> 3) << 4;
    int lane = tid & 63, wv = tid >> 6;      // 16 waves
    int quad = lane >> 4, l15 = lane & 15;
    const float* fb = feat + (size_t)b * CS * NN;
    const ushort16_t* hb = hilo + (size_t)b * NN * KP;
    const float* xxb = xxg + b * NN;

    // ---- distance: wave wv covers candidate tiles wv*2, wv*2+1 ----
    floatx4 acc[2][4];
    #pragma unroll
    for (int i = 0; i < 2; ++i)
        #pragma unroll
        for (int st = 0; st < 4; ++st) acc[i][st] = (floatx4){0.f,0.f,0.f,0.f};

    #pragma unroll
    for (int ch = 0; ch < NCH; ++ch) {
        short8 Bh[KTC], Bm[KTC], Bl[KTC];
        #pragma unroll
        for (int ktc = 0; ktc < KTC; ++ktc) {
            #pragma unroll
            for (int e = 0; e < 8; ++e) {
                int kp = (ch*KTC + ktc)*32 + quad*8 + e;
                int c = kp / 3;
                float v = (c < C) ? fb[(size_t)c*NN + n0 + l15] : 0.f;
                ushort16_t h = f2bf(v);
                float r1 = v - bfbits2f(h);
                ushort16_t m = f2bf(r1);
                ushort16_t l = f2bf(r1 - bfbits2f(m));
                Bh[ktc][e] = (short)h; Bm[ktc][e] = (short)m; Bl[ktc][e] = (short)l;
            }
        }
        #pragma unroll
        for (int i = 0; i < 2; ++i) {
            int base = (wv*2 + i) * 64;
            #pragma unroll
            for (int st = 0; st < 4; ++st) {
                #pragma unroll
                for (int ktc = 0; ktc < KTC; ++ktc) {
                    int kt = ch*KTC + ktc;
                    short8 a = *(const short8*)&hb[(size_t)(base + st*16 + l15)*KP + kt*32 + quad*8];
                    acc[i][st] = __builtin_amdgcn_mfma_f32_16x16x32_bf16(a, Bh[ktc], acc[i][st], 0, 0, 0);
                    acc[i][st] = __builtin_amdgcn_mfma_f32_16x16x32_bf16(a, Bm[ktc], acc[i][st], 0, 0, 0);
                    acc[i][st] = __builtin_amdgcn_mfma_f32_16x16x32_bf16(a, Bl[ktc], acc[i][st], 0, 0, 0);
                }
            }
        }
    }
    #pragma unroll
    for (int i = 0; i < 2; ++i) {
        #pragma unroll
        for (int st = 0; st < 4; ++st) {
            #pragma unroll
            for (int r = 0; r < 4; ++r) {
                int cand = (wv*2 + i)*64 + st*16 + quad*4 + r;
                Dt[l15*ST + cand] = 2.f*acc[i][st][r] - xxb[cand];
            }
        }
    }
    __syncthreads();

    // ---- selection: wave wv owns row wv ----
    int r0 = wv;
    unsigned int basei = 2047u - (unsigned int)lane;
    unsigned int a0[32];
    unsigned int dead0 = 0;
    unsigned long long p0 = 0, p1 = 0, p2 = 0;
    #pragma unroll
    for (int j = 0; j < 32; ++j) {
        unsigned int u0 = __float_as_uint(Dt[r0*ST + j*64 + lane]);
        unsigned int o0 = u0 ^ (unsigned int)(((int)u0 >> 31) | 0x80000000);
        a0[j] = o0;
        unsigned long long k0 = ((unsigned long long)o0 << 32) | (basei - j*64);
        bool g00 = k0 > p0, g01 = k0 > p1, g02 = k0 > p2;
        p2 = g01 ? p1 : (g02 ? k0 : p2);
        p1 = g00 ? p0 : (g01 ? k0 : p1);
        p0 = g00 ? k0 : p0;
    }
    int myg0 = 0;
    #pragma unroll 1
    for (int it = 0; it < KK; ++it) {
        unsigned int hi = (unsigned int)(p0 >> 32);
        unsigned int mx = dpp_wavemax(hi);
        unsigned int winv = (unsigned int)__builtin_amdgcn_readlane((int)mx, 63);
        unsigned long long mask = __ballot(hi == winv);
        unsigned int winlow;
        if (__popcll(mask) == 1) {
            int owner = __ffsll((unsigned long long)mask) - 1;
            winlow = (unsigned int)__builtin_amdgcn_readlane((int)(unsigned int)p0, owner);
        } else {
            // rare value-tie: exact u64 semantics via masked DPP max on the index word
            unsigned int lo = (hi == winv) ? (unsigned int)p0 : 0u;
            unsigned int mx2 = dpp_wavemax(lo);
            winlow = (unsigned int)__builtin_amdgcn_readlane((int)mx2, 63);
        }
        if (lane == it) myg0 = (int)(2047u - winlow);
        if (hi == winv && (unsigned int)p0 == winlow) {   // exactly one owner
            dead0 |= 1u << ((int)(basei - winlow) >> 6);
            p0 = p1; p1 = p2; p2 = 0;
        }
        if (__any(p0 == 0ull)) {   // rare: lane popped 3x since build
            if (p0 == 0ull) {
                unsigned long long t0 = 0, t1 = 0, t2 = 0;
                #pragma unroll
                for (int j = 0; j < 32; ++j) {
                    unsigned long long k = ((dead0 >> j) & 1u) ? 0ull
                        : (((unsigned long long)a0[j] << 32) | (basei - j*64));
                    bool g0 = k > t0, g1 = k > t1, g2 = k > t2;
                    t2 = g1 ? t1 : (g2 ? k : t2);
                    t1 = g0 ? t0 : (g1 ? k : t1);
                    t0 = g0 ? k : t0;
                }
                p0 = t0; p1 = t1; p2 = t2;
            }
        }
    }
    if (lane < KK)
        idxout[((size_t)(b*NN + n0 + r0))*KK + lane] = myg0;
}

// ================= lafe attention (post-knn) =================
__global__ __launch_bounds__(256, 1) void lafe_att_kernel(float* ws, const int* idx) {
    __shared__ float xs0[NN], xs1[NN], xs2[NN];
    int tid = threadIdx.x;
    int b = blockIdx.x >> 3;
    int n = ((blockIdx.x & 7) << 8) + tid;
    float* xm = ws + O_XMAN + b*19*NN;
    for (int i = tid; i < NN; i += 256) {
        xs0[i] = xm[i]; xs1[i] = xm[NN + i]; xs2[i] = xm[2*NN + i];
    }
    __syncthreads();
    float a0 = xs0[n], a1 = xs1[n], a2 = xs2[n];
    int ti[KK];
    #pragma unroll
    for (int k = 0; k < KK; ++k) ti[k] = idx[(b*NN + n)*KK + k] & (NN-1);
    const float* wl = ws + O_LA;
    float sa = wl[144];
    #pragma unroll
    for (int o = 0; o < 16; ++o) {
        float nf = wl[o*3+0]*a0 + wl[o*3+1]*a1 + wl[o*3+2]*a2 + wl[48+o];
        sa += wl[128+o]*nf;
    }
    float lg[KK]; float mx = -3.0e38f;
    #pragma unroll
    for (int k = 0; k < KK; ++k) {
        int m = ti[k];
        float d0 = a0 - xs0[m], d1 = a1 - xs1[m], d2 = a2 - xs2[m];
        float na = wl[144];
        #pragma unroll
        for (int o = 0; o < 16; ++o) {
            float ef = wl[64+o*3+0]*d0 + wl[64+o*3+1]*d1 + wl[64+o*3+2]*d2 + wl[112+o];
            na += wl[128+o]*ef;
        }
        float t = sa + na;
        t = t > 0.f ? t : 0.01f*t;
        lg[k] = t; mx = fmaxf(mx, t);
    }
    float ssum = 0.f;
    #pragma unroll
    for (int k = 0; k < KK; ++k) { lg[k] = expf(lg[k] - mx); ssum += lg[k]; }
    float vals[16];
    #pragma unroll
    for (int o = 0; o < 16; ++o) vals[o] = 0.f;
    #pragma unroll
    for (int k = 0; k < KK; ++k) {
        float coef = lg[k] / ssum;
        int m = ti[k];
        float d0 = a0 - xs0[m], d1 = a1 - xs1[m], d2 = a2 - xs2[m];
        #pragma unroll
        for (int o = 0; o < 16; ++o) {
            float ef = wl[64+o*3+0]*d0 + wl[64+o*3+1]*d1 + wl[64+o*3+2]*d2 + wl[112+o];
            vals[o] += coef * ef;
        }
    }
    #pragma unroll
    for (int o = 0; o < 16; ++o) {
        float v = vals[o];
        xm[(3+o)*NN + n] = v > 0.f ? v : expm1f(v);
    }
}

// ================= mlp (batch = blockIdx&7) =================
__global__ void mlp_kernel(float* ws) {
    __shared__ __align__(16) float xv[20];
    int tid = threadIdx.x;
    int b = blockIdx.x & 7, n = blockIdx.x >> 3;
    if (tid < 20) xv[tid] = (tid < 19) ? ws[O_XMAN + b*19*NN + tid*NN + n] : 0.f;
    __syncthreads();
    const float* mw = ws + O_MLPW;
    float acc = 0.f;
    #pragma unroll
    for (int c4 = 0; c4 < 5; ++c4) {
        float4 w = *(const float4*)&mw[tid*20 + c4*4];
        float4 g = *(const float4*)&xv[c4*4];
        acc += w.x*g.x + w.y*g.y + w.z*g.z + w.w*g.w;
    }
    float v = acc * ws[O_MLPSC + tid] + ws[O_MLPSH + tid];
    ws[O_XC2 + b*512*NN + tid*NN + n] = fmaxf(v, 0.f);
}

// ====== uv1: [U1;V1][n][128] = [A1;B1] @ xman via exact 3-split MFMA ======
__global__ __launch_bounds__(256, 2) void uv1_kernel(float* ws) {
    __shared__ float xt[19*64];
    int tid = threadIdx.x;
    int b = blockIdx.x & 7;
    int pn0 = (blockIdx.x >> 3) << 6;
    const float* fb = ws + O_XMAN + (size_t)b*19*NN;
    for (int i = tid; i < 19*64; i += 256) {
        int c = i >> 6, j = i & 63;
        xt[i] = fb[(size_t)c*NN + pn0 + j];
    }
    __syncthreads();
    int lane = tid & 63, wv = tid >> 6;
    int quad = lane >> 4, l15 = lane & 15;

    short8 X[3][4][2];
    #pragma unroll
    for (int nt = 0; nt < 4; ++nt) {
        int pt = nt*16 + l15;
        #pragma unroll
        for (int kt = 0; kt < 2; ++kt) {
            #pragma unroll
            for (int e = 0; e < 8; ++e) {
                int kp = kt*32 + quad*8 + e;
                int c = kp / 3;
                float v = (c < 19) ? xt[c*64 + pt] : 0.f;
                ushort16_t h = f2bf(v); float r1 = v - bfbits2f(h);
                ushort16_t m = f2bf(r1); ushort16_t l = f2bf(r1 - bfbits2f(m));
                X[0][nt][kt][e] = (short)h;
                X[1][nt][kt][e] = (short)m;
                X[2][nt][kt][e] = (short)l;
            }
        }
    }
    const ushort16_t* w1s = (const ushort16_t*)(ws + O_W1S16);
    floatx4 acc[2][4];
    #pragma unroll
    for (int rt = 0; rt < 2; ++rt)
        #pragma unroll
        for (int nt = 0; nt < 4; ++nt) acc[rt][nt] = (floatx4){0.f,0.f,0.f,0.f};
    #pragma unroll
    for (int pass = 0; pass < 3; ++pass) {
        #pragma unroll
        for (int kt = 0; kt < 2; ++kt) {
            int c0 = kt*32 + quad*8;
            short8 a[2];
            a[0] = *(const short8*)&w1s[(wv*32 + l15)*64 + c0];
            a[1] = *(const short8*)&w1s[(wv*32 + 16 + l15)*64 + c0];
            #pragma unroll
            for (int rt = 0; rt < 2; ++rt)
                #pragma unroll
                for (int nt = 0; nt < 4; ++nt)
                    acc[rt][nt] = __builtin_amdgcn_mfma_f32_16x16x32_bf16(a[rt], X[pass][nt][kt], acc[rt][nt], 0, 0, 0);
        }
    }
    float* uv1 = ws + O_UV1 + (size_t)b*NN*128;
    #pragma unroll
    for (int rt = 0; rt < 2; ++rt)
        #pragma unroll
        for (int nt = 0; nt < 4; ++nt) {
            int n = pn0 + nt*16 + l15;
            int r = wv*32 + rt*16 + quad*4;
            *(float4*)&uv1[(size_t)n*128 + r] =
                make_float4(acc[rt][nt][0], acc[rt][nt][1], acc[rt][nt][2], acc[rt][nt][3]);
        }
}

// ================= edge1 v2: U1/V1 gather + exact 3-split att GEMM =================
__global__ __launch_bounds__(256, 2) void edge1_kernel(float* ws, const int* idx) {
    constexpr int SW = 204;
    constexpr int ST = 65;
    __shared__ __align__(16) ushort16_t hrS[80*SW];
    __shared__ __align__(16) float attL[80*ST];
    __shared__ float vL[4*64];
    __shared__ float scalL[256];
    __shared__ float outL[64*5];
    __shared__ int idxL[80];

    int tid = threadIdx.x;
    int b  = blockIdx.x & 7;
    int n0 = (blockIdx.x >> 3) << 2;
    const float* uv1 = ws + O_UV1 + (size_t)b*NN*128;

    {
        int grp = tid >> 6, r6 = tid & 63;
        int off = grp==0 ? O_BN1SC : grp==1 ? O_BN1SH : grp==2 ? O_P1SC : O_P1SH;
        scalL[tid] = ws[off + r6];
        vL[tid] = uv1[(size_t)(n0 + grp)*128 + 64 + r6];
    }
    if (tid < 80) idxL[tid] = idx[(b*NN + n0 + tid/20)*KK + (tid%20)] & (NN-1);
    __syncthreads();

    {
        int rw = tid & 63, cg = tid >> 6;
        float s1 = scalL[rw], sh1 = scalL[64+rw], ps = scalL[128+rw], ph = scalL[192+rw];
        #pragma unroll 5
        for (int it = 0; it < 20; ++it) {
            int col = it*4 + cg;
            int p = col / 20;
            int j = idxL[col];
            float u = uv1[(size_t)j*128 + rw];
            float h1 = (u + vL[p*64+rw])*s1 + sh1;
            h1 = h1 > 0.f ? h1 : 0.2f*h1;
            float hv = h1*ps + ph;
            hv = hv > 0.f ? hv : 0.f;
            ushort16_t h = f2bf(hv); float r1 = hv - bfbits2f(h);
            ushort16_t m = f2bf(r1); ushort16_t l = f2bf(r1 - bfbits2f(m));
            hrS[col*SW + 3*rw + 0] = h;
            hrS[col*SW + 3*rw + 1] = m;
            hrS[col*SW + 3*rw + 2] = l;
        }
    }
    __syncthreads();

    int lane = tid & 63, wv = tid >> 6;
    int quad = lane >> 4, l15 = lane & 15;
    const ushort16_t* w1a3 = (const ushort16_t*)(ws + O_W1A3);
    floatx4 acc[5];
    #pragma unroll
    for (int mt = 0; mt < 5; ++mt) acc[mt] = (floatx4){0.f,0.f,0.f,0.f};
    #pragma unroll
    for (int pass = 0; pass < 3; ++pass) {
        #pragma unroll
        for (int kt = 0; kt < 6; ++kt) {
            int c0 = kt*32 + quad*8;
            short8 bfrag = *(const short8*)&w1a3[((size_t)pass*64 + wv*16 + l15)*192 + c0];
            #pragma unroll
            for (int mt = 0; mt < 5; ++mt) {
                short8 afrag = *(const short8*)&hrS[(mt*16 + l15)*SW + c0];
                acc[mt] = __builtin_amdgcn_mfma_f32_16x16x32_bf16(afrag, bfrag, acc[mt], 0, 0, 0);
            }
        }
    }
    #pragma unroll
    for (int mt = 0; mt < 5; ++mt)
        #pragma unroll
        for (int r = 0; r < 4; ++r)
            attL[(mt*16 + quad*4 + r)*ST + wv*16 + l15] = acc[mt][r];
    __syncthreads();

    {
        int o = tid & 63, p = tid >> 6;
        float av[KK]; float mx = -3.0e38f;
        #pragma unroll
        for (int k = 0; k < KK; ++k) { av[k] = attL[(p*20 + k)*ST + o]; mx = fmaxf(mx, av[k]); }
        float ssum = 0.f;
        #pragma unroll
        for (int k = 0; k < KK; ++k) { av[k] = expf(av[k] - mx); ssum += av[k]; }
        float inv = 1.f / ssum;
        float s1o = scalL[o], sh1o = scalL[64+o], vpo = vL[p*64+o];
        float sacc = 0.f;
        #pragma unroll
        for (int k = 0; k < KK; ++k) {
            int j = idxL[p*20 + k];
            float u = uv1[(size_t)j*128 + o];
            float h1 = (u + vpo)*s1o + sh1o;
            h1 = h1 > 0.f ? h1 : 0.2f*h1;
            sacc += av[k]*inv*h1;
        }
        outL[o*5 + p] = sacc;
    }
    __syncthreads();
    {
        int o = tid >> 2, p = tid & 3;
        ws[O_XC1 + (size_t)b*83*NN + (size_t)(19+o)*NN + n0 + p] = outL[o*5 + p];
    }
}

// ====== uv2: U2[b][n][r] = sum_c A2[r][c] * xc1[b][c][n] (batch = blockIdx&7) ======
__global__ __launch_bounds__(256, 2) void uv2_kernel(float* ws) {
    constexpr int XS = 108;
    __shared__ ushort16_t xt[64*XS];
    int tid = threadIdx.x;
    int b = blockIdx.x & 7;
    int pn0 = (blockIdx.x >> 3) << 6;
    const float* xc1 = ws + O_XC1 + (size_t)b*83*NN;
    for (int i = tid; i < 96*64; i += 256) {
        int c = i >> 6, j = i & 63;
        xt[j*XS + c] = (c < 83) ? f2bf(xc1[c*NN + pn0 + j]) : (ushort16_t)0;
    }
    __syncthreads();
    int lane = tid & 63, wv = tid >> 6;
    int quad = lane >> 4, l15 = lane & 15;
    const ushort16_t* a2b = (const ushort16_t*)(ws + O_W2B16);
    floatx4 acc[4][4];
    #pragma unroll
    for (int rt = 0; rt < 4; ++rt)
        #pragma unroll
        for (int nt = 0; nt < 4; ++nt) acc[rt][nt] = (floatx4){0.f,0.f,0.f,0.f};
    #pragma unroll
    for (int kt = 0; kt < 3; ++kt) {
        int c0 = kt*32 + quad*8;
        short8 bfr[4], a[4];
        #pragma unroll
        for (int nt = 0; nt < 4; ++nt)
            bfr[nt] = *(const short8*)&xt[(nt*16 + l15)*XS + c0];
        #pragma unroll
        for (int rt = 0; rt < 4; ++rt)
            a[rt] = *(const short8*)&a2b[(wv*64 + rt*16 + l15)*96 + c0];
        #pragma unroll
        for (int rt = 0; rt < 4; ++rt)
            #pragma unroll
            for (int nt = 0; nt < 4; ++nt)
                acc[rt][nt] = __builtin_amdgcn_mfma_f32_16x16x32_bf16(a[rt], bfr[nt], acc[rt][nt], 0, 0, 0);
    }
    float* U2 = ws + O_XC2 + (size_t)b*512*NN;
    #pragma unroll
    for (int rt = 0; rt < 4; ++rt)
        #pragma unroll
        for (int nt = 0; nt < 4; ++nt) {
            int n = pn0 + nt*16 + l15;
            int r = wv*64 + rt*16 + quad*4;
            *(float4*)&U2[(size_t)n*256 + r] =
                make_float4(acc[rt][nt][0], acc[rt][nt][1], acc[rt][nt][2], acc[rt][nt][3]);
        }
}

// ====== v2: V2[b][n][r] = sum_c b2fT[c][r] * xc1[b][c][n], exact fp32, point-major ======
__global__ __launch_bounds__(256, 4) void v2_kernel(float* ws) {
    __shared__ float xs[83*16];
    int tid = threadIdx.x;
    int b = blockIdx.x & 7;
    int pn0 = (blockIdx.x >> 3) << 4;
    const float* xc1 = ws + O_XC1 + (size_t)b*83*NN;
    for (int i = tid; i < 83*16; i += 256) {
        int c = i >> 4, j = i & 15;
        xs[i] = xc1[(size_t)c*NN + pn0 + j];
    }
    __syncthreads();
    const float* b2fT = ws + O_P2W;
    float acc[16];
    #pragma unroll
    for (int j = 0; j < 16; ++j) acc[j] = 0.f;
    #pragma unroll 4
    for (int c = 0; c < 83; ++c) {
        float w = b2fT[c*256 + tid];
        #pragma unroll
        for (int j = 0; j < 16; ++j) acc[j] += w * xs[c*16 + j];
    }
    float* V2 = ws + O_XC2 + (size_t)b*512*NN + (size_t)256*NN;
    #pragma unroll
    for (int j = 0; j < 16; ++j) V2[(size_t)(pn0 + j)*256 + tid] = acc[j];
}

// ================= edge2 v3: 2 points/block, V precomputed, h2 reg-cached =================
__global__ __launch_bounds__(256, 2) void edge2_kernel(float* ws, const int* idx) {
    constexpr int HS = 268;
    __shared__ __align__(16) ushort16_t hrb[48*HS];
    __shared__ __align__(16) float attL[256*41];
    __shared__ float p2bL[256];
    __shared__ int idxL[40];

    int tid = threadIdx.x;
    int b  = blockIdx.x & 7;
    int n0 = (blockIdx.x >> 3) << 1;

    const float* U2 = ws + O_XC2 + (size_t)b*512*NN;
    float* V2 = ws + O_XC2 + (size_t)b*512*NN + (size_t)256*NN;

    float sc = ws[O_BN2SC + tid], sh = ws[O_BN2SH + tid];
    float ps = ws[O_P2SC + tid],  ph = ws[O_P2SH + tid];
    p2bL[tid] = ws[O_P2B + tid];
    float v0 = V2[(size_t)n0*256 + tid];
    float v1 = V2[(size_t)(n0+1)*256 + tid];
    if (tid < 40) idxL[tid] = idx[(b*NN + n0 + tid/20)*KK + (tid%20)] & (NN-1);
    __syncthreads();

    float h2r[40];
    #pragma unroll
    for (int col = 0; col < 40; ++col) {
        int j = idxL[col];
        float u = U2[(size_t)j*256 + tid];
        float h2 = (u + (col >= 20 ? v1 : v0))*sc + sh;
        h2 = h2 > 0.f ? h2 : 0.2f*h2;
        h2r[col] = h2;
        float hv = h2*ps + ph;
        hrb[col*HS + tid] = f2bf(fmaxf(hv, 0.f));
    }
    __syncthreads();

    int lane = tid & 63, wv = tid >> 6;
    int quad = lane >> 4, l15 = lane & 15;
    const ushort16_t* p2wb = (const ushort16_t*)(ws + O_P2W16);
    floatx4 acc2[4][3];
    #pragma unroll
    for (int mt = 0; mt < 4; ++mt)
        #pragma unroll
        for (int nt = 0; nt < 3; ++nt) acc2[mt][nt] = (floatx4){0.f,0.f,0.f,0.f};
    for (int kt = 0; kt < 8; ++kt) {
        int c0 = kt*32 + quad*8;
        short8 a[4], bb3[3];
        #pragma unroll
        for (int mt = 0; mt < 4; ++mt)
            a[mt] = *(const short8*)&p2wb[(wv*64 + mt*16 + l15)*256 + c0];
        #pragma unroll
        for (int nt = 0; nt < 3; ++nt)
            bb3[nt] = *(const short8*)&hrb[(nt*16 + l15)*HS + c0];
        #pragma unroll
        for (int mt = 0; mt < 4; ++mt)
            #pragma unroll
            for (int nt = 0; nt < 3; ++nt)
                acc2[mt][nt] = __builtin_amdgcn_mfma_f32_16x16x32_bf16(a[mt], bb3[nt], acc2[mt][nt], 0, 0, 0);
    }
    #pragma unroll
    for (int mt = 0; mt < 4; ++mt) {
        int k0 = wv*64 + mt*16 + quad*4;
        #pragma unroll
        for (int nt = 0; nt < 3; ++nt) {
            int col = nt*16 + l15;
            if (col < 40) {
                #pragma unroll
                for (int r = 0; r < 4; ++r)
                    attL[(k0 + r)*41 + col] = acc2[mt][nt][r] + p2bL[k0 + r];
            }
        }
    }
    __syncthreads();

    #pragma unroll
    for (int p = 0; p < 2; ++p) {
        float av[KK]; float mx = -3.0e38f;
        #pragma unroll
        for (int k = 0; k < KK; ++k) { av[k] = attL[tid*41 + p*20 + k]; mx = fmaxf(mx, av[k]); }
        float ssum = 0.f;
        #pragma unroll
        for (int k = 0; k < KK; ++k) { av[k] = expf(av[k] - mx); ssum += av[k]; }
        float inv = 1.f / ssum;
        float sacc = 0.f;
        #pragma unroll
        for (int k = 0; k < KK; ++k) sacc += av[k] * inv * h2r[p*20 + k];
        V2[(size_t)(n0 + p)*256 + tid] = sacc;
    }
}

// ================= final (MFMA, 2-split x 2-split exact-enough) =================
__global__ __launch_bounds__(512, 1) void final_kernel(const float* ws, float* out) {
    __shared__ __align__(16) uint32 smem[17408];      // 69,632 B union
    __shared__ float s3L[512], q3L[512];
    uint32* xh32 = smem;                              // [64][132]
    uint32* xm32 = smem + 8448;                       // [64][132]
    float*  outF = (float*)smem;                      // [256][68]

    int tid = threadIdx.x;
    int b = blockIdx.x & 7;
    int pn0 = (blockIdx.x >> 3) << 6;
    int lane = tid & 63, wv = tid >> 6;
    int quad = lane >> 4, l15 = lane & 15;
    if (tid < 512) { s3L[tid] = ws[O_BN3SC + tid]; q3L[tid] = ws[O_BN3SH + tid]; }

    const float* xc2 = ws + O_XC2 + (size_t)b*512*NN;
    const float* xp2 = xc2 + (size_t)256*NN;
    const ushort16_t* w3s = (const ushort16_t*)(ws + O_W3S16);
    int r0 = wv*64;

    floatx4 acc[4][4];
    #pragma unroll
    for (int mt = 0; mt < 4; ++mt)
        #pragma unroll
        for (int nt = 0; nt < 4; ++nt) acc[mt][nt] = (floatx4){0.f,0.f,0.f,0.f};

    for (int ch = 0; ch < 4; ++ch) {
        __syncthreads();
        if (ch < 2) {
            int gc0 = ch*128;
            #pragma unroll 4
            for (int it = 0; it < 16; ++it) {
                int idx = it*512 + tid;
                int cl = idx >> 6, n = idx & 63;
                float v = xc2[(size_t)(gc0+cl)*NN + pn0 + n];
                ushort16_t h = f2bf(v);
                ushort16_t m = f2bf(v - bfbits2f(h));
                xh32[n*132 + cl] = (uint32)h * 0x10001u;
                xm32[n*132 + cl] = (uint32)m * 0x10001u;
            }
        } else {
            int gco = (ch-2)*128;
            #pragma unroll 4
            for (int it = 0; it < 16; ++it) {
                int idx = it*512 + tid;
                int n = idx >> 7, cl = idx & 127;
                float v = xp2[(size_t)(pn0+n)*256 + gco + cl];
                ushort16_t h = f2bf(v);
                ushort16_t m = f2bf(v - bfbits2f(h));
                xh32[n*132 + cl] = (uint32)h * 0x10001u;
                xm32[n*132 + cl] = (uint32)m * 0x10001u;
            }
        }
        __syncthreads();
        const ushort16_t* ph = (const ushort16_t*)xh32;
        const ushort16_t* pm = (const ushort16_t*)xm32;
        #pragma unroll
        for (int kt = 0; kt < 8; ++kt) {
            int c0k = kt*32 + quad*8;
            short8 a[4], bh[4], bm[4];
            #pragma unroll
            for (int mt = 0; mt < 4; ++mt)
                a[mt] = *(const short8*)&w3s[(size_t)(r0 + mt*16 + l15)*1024 + ch*256 + c0k];
            #pragma unroll
            for (int nt = 0; nt < 4; ++nt) {
                bh[nt] = *(const short8*)&ph[(nt*16 + l15)*264 + c0k];
                bm[nt] = *(const short8*)&pm[(nt*16 + l15)*264 + c0k];
            }
            #pragma unroll
            for (int mt = 0; mt < 4; ++mt)
                #pragma unroll
                for (int nt = 0; nt < 4; ++nt) {
                    acc[mt][nt] = __builtin_amdgcn_mfma_f32_16x16x32_bf16(a[mt], bh[nt], acc[mt][nt], 0, 0, 0);
                    acc[mt][nt] = __builtin_amdgcn_mfma_f32_16x16x32_bf16(a[mt], bm[nt], acc[mt][nt], 0, 0, 0);
                }
        }
    }

    float* ob = out + (size_t)b*512*NN;
    #pragma unroll
    for (int half = 0; half < 2; ++half) {
        __syncthreads();
        if ((wv >> 2) == half) {
            int rb = r0 - half*256;
            #pragma unroll
            for (int mt = 0; mt < 4; ++mt)
                #pragma unroll
                for (int nt = 0; nt < 4; ++nt)
                    #pragma unroll
                    for (int r = 0; r < 4; ++r) {
                        int row = r0 + mt*16 + quad*4 + r;
                        float v = acc[mt][nt][r]*s3L[row] + q3L[row];
                        v = v > 0.f ? v : 0.2f*v;
                        outF[(rb + mt*16 + quad*4 + r)*68 + nt*16 + l15] = v;
                    }
        }
        __syncthreads();
        #pragma unroll
        for (int it = 0; it < 8; ++it) {
            int idx = it*512 + tid;
            int row = idx >> 4, f4 = idx & 15;
            float4 v = *(const float4*)&outF[row*68 + f4*4];
            *(float4*)&ob[(size_t)(half*256 + row)*NN + pn0 + f4*4] = v;
        }
    }
}

extern "C" void kernel_launch(void* const* d_in, const int* in_sizes, int n_in,
                              void* d_out, int out_size, void* d_ws, size_t ws_size,
                              hipStream_t stream) {
    float* ws = (float*)d_ws;
    float* out = (float*)d_out;
    ushort16_t* hilo = (ushort16_t*)(ws + O_HILO);
    float* xxq = ws + O_XXQ;

    detect_kernel<<<1, 64, 0, stream>>>(d_in[0], (int*)ws + O_FLAG);
    prep_kernel<<<64, 256, 0, stream>>>(d_in[1], d_in[2], d_in[3], d_in[4], d_in[5], d_in[6],
                                        d_in[7], d_in[8], d_in[9], d_in[10], d_in[11], d_in[12],
                                        d_in[13], d_in[14], d_in[15], d_in[16], d_in[17], d_in[18],
                                        d_in[19], d_in[20], d_in[21], ws);
    // lafe = xconv + knn3 (fused MFMA+select) + attention
    xconv_kernel<<<192, 256, 0, stream>>>(d_in[0], ws);
    hilo_kernel<3, 19, 32><<<256, 256, 0, stream>>>(ws + O_XMAN, hilo);
    xx_kernel<3, 19><<<64, 256, 0, stream>>>(ws + O_XMAN, xxq);
    knn_fused_kernel<3, 19, 32><<<1024, 1024, 0, stream>>>(ws + O_XMAN, hilo, xxq, (int*)(ws + O_IDX3));
    lafe_att_kernel<<<64, 256, 0, stream>>>(ws, (const int*)(ws + O_IDX3));
    xc1copy_kernel<<<1216, 256, 0, stream>>>(ws);
    // knn on x_manet (C=19)
    hilo_kernel<19, 19, 64><<<1024, 256, 0, stream>>>(ws + O_XMAN, hilo);
    xx_kernel<19, 19><<<64, 256, 0, stream>>>(ws + O_XMAN, xxq);
    knn_fused_kernel<19, 19, 64><<<1024, 1024, 0, stream>>>(ws + O_XMAN, hilo, xxq, (int*)(ws + O_IDX2));
    // edge1 via exact A/B decomposition
    uv1_kernel<<<256, 256, 0, stream>>>(ws);
    edge1_kernel<<<BB*512, 256, 0, stream>>>(ws, (const int*)(ws + O_IDX2));
    // knn on x_c1 (C=83)
    hilo_kernel<83, 83, 256><<<2048, 256, 0, stream>>>(ws + O_XC1, hilo);
    xx_kernel<83, 83><<<64, 256, 0, stream>>>(ws + O_XC1, xxq);
    knn_fused_kernel<83, 83, 256><<<1024, 1024, 0, stream>>>(ws + O_XC1, hilo, xxq, (int*)(ws + O_IDX3));
    // edge2 via A/B decomposition: U2 (MFMA) + V2 (exact fp32 dense), then fused gather kernel
    uv2_kernel<<<256, 256, 0, stream>>>(ws);
    v2_kernel<<<1024, 256, 0, stream>>>(ws);
    edge2_kernel<<<BB*1024, 256, 0, stream>>>(ws, (const int*)(ws + O_IDX3));
    mlp_kernel<<<BB*NN, 256, 0, stream>>>(ws);
    final_kernel<<<256, 512, 0, stream>>>(ws, out);
}